// Round 5
// baseline (1344.506 us; speedup 1.0000x reference)
//
#include <hip/hip_runtime.h>

#define DEVINLINE __device__ __forceinline__

typedef unsigned short u16;
typedef __attribute__((ext_vector_type(8))) short short8v;
typedef __attribute__((ext_vector_type(4))) float float4v;

constexpr int HID = 128;
constexpr int NSPLIT = 8;     // main-pass column splits
constexpr int BUD = 256;      // candidate buffer budget per query
constexpr int SMP = 1024;     // sample size for tau

// ---------- small helpers ----------
DEVINLINE void gld16(const void* g, void* l) {
    __builtin_amdgcn_global_load_lds((const __attribute__((address_space(1))) unsigned int*)g,
                                     (__attribute__((address_space(3))) unsigned int*)l, 16, 0, 0);
}
DEVINLINE void gld4(const void* g, void* l) {
    __builtin_amdgcn_global_load_lds((const __attribute__((address_space(1))) unsigned int*)g,
                                     (__attribute__((address_space(3))) unsigned int*)l, 4, 0, 0);
}
DEVINLINE u16 f2bf(float x) {
    unsigned u = __float_as_uint(x);
    return (u16)((u + 0x7fffu + ((u >> 16) & 1u)) >> 16);
}
// rigorous bound on |screened_d2 - exact_d2| for any pair involving query q:
// bf16 RNE roundoff u=2^-8 on both operands -> dot err <= 2^-7*1.01*||a||*||b||
// <= 0.00394*(sq_a+sq_b); + fp32 combine/sqnorm slop (<1e-3). 0.00415 + 0.01 covers.
DEVINLINE float maxerr_f(float sqq, float sqm) {
    return 0.00415f * (sqq + sqm) + 0.01f;
}
// ascending value-only top-K list (static indices)
template<int K>
DEVINLINE void topk_insert_v(float (&bd)[K], float d) {
    if (d >= bd[K - 1]) return;
#pragma unroll
    for (int p = 0; p < K; ++p) {
        const float mn = fminf(d, bd[p]);
        const float mx = fmaxf(d, bd[p]);
        bd[p] = mn; d = mx;
    }
}
DEVINLINE bool lexd(double d1, int i1, double d2, int i2) {
    return (d1 < d2) || ((d1 == d2) && (i1 < i2));
}
template<int K>
DEVINLINE void topk_insert_d(double (&bd)[K], int (&bi)[K], double d, int j) {
    if (!lexd(d, j, bd[K - 1], bi[K - 1])) return;
    double cd = d; int ci = j;
#pragma unroll
    for (int p = 0; p < K; ++p) {
        const bool lt = lexd(cd, ci, bd[p], bi[p]);
        const double sd = bd[p]; const int si = bi[p];
        bd[p] = lt ? cd : sd;  bi[p] = lt ? ci : si;
        cd = lt ? sd : cd;     ci = lt ? si : ci;
    }
}

// ---------------- per-layer init: zero cnt, novf, sqmax ----------------
__global__ void zero_misc_kernel(int* __restrict__ cnt, int* __restrict__ novf,
                                 float* __restrict__ sqmax, int n) {
    const int i = blockIdx.x * 256 + threadIdx.x;
    if (i < n) cnt[i] = 0;
    if (i == 0) { novf[0] = 0; *(int*)sqmax = 0; }
}

// ---------------- squared norms (fp32) + global max ----------------
template<int D>
__global__ void sqnorm_kernel(const float* __restrict__ X, float* __restrict__ sq,
                              float* __restrict__ sqmax, int n) {
    const int i = blockIdx.x * 256 + threadIdx.x;
    float s = 0.f;
    if (i < n) {
        const float4* row = (const float4*)(X + (size_t)i * D);
#pragma unroll
        for (int u = 0; u < D / 4; ++u) {
            const float4 v = row[u];
            s += v.x * v.x + v.y * v.y + v.z * v.z + v.w * v.w;
        }
        sq[i] = s;
    }
    float m = s;
#pragma unroll
    for (int off = 32; off >= 1; off >>= 1) m = fmaxf(m, __shfl_xor(m, off, 64));
    if ((threadIdx.x & 63) == 0) atomicMax((int*)sqmax, __float_as_int(m));
}

// ---------------- round fp32 -> bf16 ----------------
__global__ void round_bf16_kernel(const float* __restrict__ X, u16* __restrict__ hi, int total4) {
    const int i = blockIdx.x * 256 + threadIdx.x;
    if (i >= total4) return;
    const float4 v = ((const float4*)X)[i];
    ushort4 h = {f2bf(v.x), f2bf(v.y), f2bf(v.z), f2bf(v.w)};
    ((ushort4*)hi)[i] = h;
}

// ---------------- sample pass: per-lane-group top-K screened distances ----------------
// Grid ceil(n/64). Sample rows j = s*sstr, s in [0,1024).
template<int D, int K>
__global__ __launch_bounds__(256)
void sample_knn_kernel(const u16* __restrict__ Xb, const float* __restrict__ sq,
                       float* __restrict__ smp, int n, int sstr) {
    constexpr int MB = 64, NMI = 4;
    constexpr int KS = D / 32, SLOTS = D / 8;
    constexpr int TS = MB * SLOTS, TB = TS * 16, SI = TS / 256;
    constexpr int BUFB = TB + 256 + 64;
    constexpr int NT = SMP / MB;   // 16
    __shared__ __align__(16) char smem[2 * BUFB];

    const int tid = threadIdx.x, lane = tid & 63, wid = tid >> 6;
    const int lrow = lane & 15, lhalf = lane >> 4;
    const int q0 = blockIdx.x * 64;
    const int q = q0 + wid * 16 + lrow, qc = min(q, n - 1);

    short8v qf[KS];
#pragma unroll
    for (int ks = 0; ks < KS; ++ks)
        qf[ks] = *(const short8v*)(Xb + (size_t)qc * D + (ks * 4 + lhalf) * 8);
    const float sqq = sq[qc];

    int srow[SI], soff[SI];
#pragma unroll
    for (int it = 0; it < SI; ++it) {
        const int gs = (it * 4 + wid) * 64 + lane;
        const int row = gs / SLOTS, psl = gs % SLOTS;
        const int ksl = (psl & ~7) | ((psl ^ row) & 7);
        srow[it] = row; soff[it] = ksl * 8;
    }

    float bd[K];
#pragma unroll
    for (int p = 0; p < K; ++p) bd[p] = __builtin_inff();

    auto stage = [&](int t, int b) {
        char* buf = smem + b * BUFB;
        const int s0 = t * MB;
#pragma unroll
        for (int it = 0; it < SI; ++it) {
            const size_t phys = (size_t)(s0 + srow[it]) * sstr;
            gld16(Xb + phys * D + soff[it], buf + (it * 4 + wid) * 1024);
        }
        if (wid == 0) gld4(sq + (size_t)(s0 + lane) * sstr, buf + TB);
    };
    auto compute = [&](int t, int b) {
        const char* buf = smem + b * BUFB;
        const u16* hp = (const u16*)buf;
        const float* sql = (const float*)(buf + TB);
        const int s0 = t * MB;
        float4v acc[NMI];
#pragma unroll
        for (int mi = 0; mi < NMI; ++mi) acc[mi] = (float4v){0.f, 0.f, 0.f, 0.f};
#pragma unroll
        for (int ks = 0; ks < KS; ++ks) {
#pragma unroll
            for (int mi = 0; mi < NMI; ++mi) {
                const int row = mi * 16 + lrow;
                const int ksl = ks * 4 + lhalf;
                const int pk = (ksl & ~7) | ((ksl ^ row) & 7);
                const short8v ah = *(const short8v*)(hp + (size_t)row * (SLOTS * 8) + pk * 8);
                acc[mi] = __builtin_amdgcn_mfma_f32_16x16x32_bf16(ah, qf[ks], acc[mi], 0, 0, 0);
            }
        }
#pragma unroll
        for (int mi = 0; mi < NMI; ++mi) {
            const float4 s4 = *(const float4*)(sql + mi * 16 + lhalf * 4);
            const float ss[4] = {s4.x, s4.y, s4.z, s4.w};
#pragma unroll
            for (int r = 0; r < 4; ++r) {
                const int sidx = s0 + mi * 16 + lhalf * 4 + r;
                const int j = sidx * sstr;
                const float d2 = sqq + ss[r] - 2.f * acc[mi][r];
                if (j != q) topk_insert_v<K>(bd, d2);
            }
        }
    };

    stage(0, 0);
    __syncthreads();
    for (int t = 0; t < NT; ++t) {
        if (t + 1 < NT) stage(t + 1, (t + 1) & 1);
        compute(t, t & 1);
        __syncthreads();
    }

    if (q < n) {
        const size_t base = ((size_t)q * 4 + lhalf) * K;
#pragma unroll
        for (int p = 0; p < K; ++p) smp[base + p] = bd[p];
    }
}

// ---------------- merge sample lists -> tau (rigorous margin) ----------------
template<int K>
__global__ void tau_merge_kernel(const float* __restrict__ smp, const float* __restrict__ sq,
                                 const float* __restrict__ sqmax, float* __restrict__ tau, int n) {
    const int q = blockIdx.x * 256 + threadIdx.x;
    if (q >= n) return;
    float bd[K];
#pragma unroll
    for (int p = 0; p < K; ++p) bd[p] = __builtin_inff();
    for (int g = 0; g < 4; ++g) {
        const size_t base = ((size_t)q * 4 + g) * K;
#pragma unroll
        for (int p = 0; p < K; ++p) topk_insert_v<K>(bd, smp[base + p]);
    }
    const float me = maxerr_f(sq[q], sqmax[0]);
    tau[q] = bd[K - 1] + 2.f * me + 0.0625f;
}

// ---------------- main pass: MFMA distances + threshold compaction ----------------
template<int D>
__global__ __launch_bounds__(256)
void knn_main_kernel(const u16* __restrict__ Xb, const float* __restrict__ sq,
                     const float* __restrict__ tau, int* __restrict__ cnt,
                     int* __restrict__ cbuf, int n, int cps) {
    constexpr int MB = 96, NMI = 6;
    constexpr int KS = D / 32, SLOTS = D / 8;
    constexpr int TS = MB * SLOTS, TB = TS * 16, SI = TS / 256;
    constexpr int BUFB = TB + 512 + 128;
    __shared__ __align__(16) char smem[2 * BUFB];

    const int tid = threadIdx.x, lane = tid & 63, wid = tid >> 6;
    const int lrow = lane & 15, lhalf = lane >> 4;
    const int q0 = blockIdx.x * 64, sp = blockIdx.y;
    const int rbeg = sp * cps, rend = min(rbeg + cps, n);
    const int nt = (rend - rbeg + MB - 1) / MB;
    const int q = q0 + wid * 16 + lrow, qc = min(q, n - 1);
    const bool qok = q < n;

    short8v qf[KS];
#pragma unroll
    for (int ks = 0; ks < KS; ++ks)
        qf[ks] = *(const short8v*)(Xb + (size_t)qc * D + (ks * 4 + lhalf) * 8);
    const float sqq = sq[qc];
    const float tq = tau[qc];

    int srow[SI], soff[SI];
#pragma unroll
    for (int it = 0; it < SI; ++it) {
        const int gs = (it * 4 + wid) * 64 + lane;
        const int row = gs / SLOTS, psl = gs % SLOTS;
        const int ksl = (psl & ~7) | ((psl ^ row) & 7);
        srow[it] = row; soff[it] = ksl * 8;
    }

    auto stage = [&](int t, int b) {
        char* buf = smem + b * BUFB;
        const int row0 = rbeg + t * MB;
#pragma unroll
        for (int it = 0; it < SI; ++it) {
            const int grow = min(row0 + srow[it], rend - 1);
            gld16(Xb + (size_t)grow * D + soff[it], buf + (it * 4 + wid) * 1024);
        }
        if (tid < MB) {
            const int g2 = min(row0 + tid, rend - 1);
            gld4(sq + g2, buf + TB + wid * 256);
        }
    };
    auto compute = [&](int t, int b) {
        const char* buf = smem + b * BUFB;
        const u16* hp = (const u16*)buf;
        const float* sql = (const float*)(buf + TB);
        const int row0 = rbeg + t * MB;
        const int rl = rend - row0;
        float4v acc[NMI];
#pragma unroll
        for (int mi = 0; mi < NMI; ++mi) acc[mi] = (float4v){0.f, 0.f, 0.f, 0.f};
#pragma unroll
        for (int ks = 0; ks < KS; ++ks) {
#pragma unroll
            for (int mi = 0; mi < NMI; ++mi) {
                const int row = mi * 16 + lrow;
                const int ksl = ks * 4 + lhalf;
                const int pk = (ksl & ~7) | ((ksl ^ row) & 7);
                const short8v ah = *(const short8v*)(hp + (size_t)row * (SLOTS * 8) + pk * 8);
                acc[mi] = __builtin_amdgcn_mfma_f32_16x16x32_bf16(ah, qf[ks], acc[mi], 0, 0, 0);
            }
        }
#pragma unroll
        for (int mi = 0; mi < NMI; ++mi) {
            const float4 s4 = *(const float4*)(sql + mi * 16 + lhalf * 4);
            const float ss[4] = {s4.x, s4.y, s4.z, s4.w};
#pragma unroll
            for (int r = 0; r < 4; ++r) {
                const int dbr = mi * 16 + lhalf * 4 + r;
                const int j = row0 + dbr;
                const float d2 = sqq + ss[r] - 2.f * acc[mi][r];
                if (qok && dbr < rl && d2 <= tq && j != q) {
                    const int slot = atomicAdd(cnt + q, 1);
                    if (slot < BUD) cbuf[(size_t)q * BUD + slot] = j;
                }
            }
        }
    };

    stage(0, 0);
    __syncthreads();
    for (int t = 0; t < nt; ++t) {
        if (t + 1 < nt) stage(t + 1, (t + 1) & 1);
        compute(t, t & 1);
        __syncthreads();
    }
}

// ---------------- fp64-exact top-K over the candidate buffer (+ kth dist) ----------------
template<int D, int K>
__global__ __launch_bounds__(256)
void select_kernel(const float* __restrict__ X, const int* __restrict__ cbuf,
                   const int* __restrict__ cnt, int* __restrict__ idx_out,
                   double* __restrict__ dkth, int n) {
    __shared__ float xish[4][D];
    const int tid = threadIdx.x, lane = tid & 63, w = tid >> 6;
    const int q = blockIdx.x * 4 + w;
    const int qc = min(q, n - 1);

    if (lane < D / 4)
        *(float4*)(&xish[w][lane * 4]) = *(const float4*)(X + (size_t)qc * D + lane * 4);
    __syncthreads();

    const int cq = min(cnt[qc], BUD);
    double dv[4]; int jv[4];
#pragma unroll
    for (int u = 0; u < 4; ++u) {
        const int c = u * 64 + lane;
        int j = 0x7fffffff;
        double s = 1e300;
        if (c < cq) {
            j = cbuf[(size_t)qc * BUD + c];
            const float4* xj = (const float4*)(X + (size_t)j * D);
            double acc = 0.0;
#pragma unroll 8
            for (int t = 0; t < D / 4; ++t) {
                const float4 b = xj[t];
                const float4 a = *(const float4*)(&xish[w][t * 4]);
                double d;
                d = (double)a.x - (double)b.x; acc = fma(d, d, acc);
                d = (double)a.y - (double)b.y; acc = fma(d, d, acc);
                d = (double)a.z - (double)b.z; acc = fma(d, d, acc);
                d = (double)a.w - (double)b.w; acc = fma(d, d, acc);
            }
            s = acc;
        }
        dv[u] = s; jv[u] = j;
    }

#pragma unroll
    for (int p = 0; p < K; ++p) {
        double md = dv[0]; int mj = jv[0];
#pragma unroll
        for (int u = 1; u < 4; ++u)
            if (lexd(dv[u], jv[u], md, mj)) { md = dv[u]; mj = jv[u]; }
#pragma unroll
        for (int off = 32; off >= 1; off >>= 1) {
            const double od = __shfl_xor(md, off, 64);
            const int    oj = __shfl_xor(mj, off, 64);
            if (lexd(od, oj, md, mj)) { md = od; mj = oj; }
        }
        if (lane == 0 && q < n) {
            idx_out[(size_t)q * K + p] = mj;
            if (p == K - 1) dkth[q] = md;
        }
#pragma unroll
        for (int u = 0; u < 4; ++u)
            if (jv[u] == mj) dv[u] = 1e300;
    }
}

// ---------------- certificate check -> flagged-query list ----------------
template<int K>
__global__ void flag_kernel(const int* __restrict__ cnt, const double* __restrict__ dkth,
                            const float* __restrict__ tau, const float* __restrict__ sq,
                            const float* __restrict__ sqmax, int* __restrict__ novf,
                            int* __restrict__ ovf, int n) {
    const int q = blockIdx.x * 256 + threadIdx.x;
    if (q >= n) return;
    const float me = maxerr_f(sq[q], sqmax[0]);
    const int c = cnt[q];
    const bool bad = (c > BUD) || (c < K) || (dkth[q] + (double)me > (double)tau[q]);
    if (bad) { const int s = atomicAdd(novf, 1); ovf[s] = q; }
}

// ---------------- exact fp64 full-scan fallback for flagged queries ----------------
template<int D, int K>
__global__ __launch_bounds__(256)
void fallback_kernel(const float* __restrict__ X, const int* __restrict__ ovf,
                     const int* __restrict__ novf, int* __restrict__ idx_out, int n) {
    __shared__ float xq[4][D];
    const int tid = threadIdx.x, lane = tid & 63, w = tid >> 6;
    const int gw = blockIdx.x * 4 + w;
    const int total = novf[0];
    for (int e = gw; e < total; e += gridDim.x * 4) {
        const int q = ovf[e];
        // per-wave staging (no barrier: waves run independent e's); same-wave
        // DS pipeline is in-order so reads below see these writes.
        if (lane < D / 4)
            *(float4*)(&xq[w][lane * 4]) = *(const float4*)(X + (size_t)q * D + lane * 4);
        double bd[K]; int bi[K];
#pragma unroll
        for (int p = 0; p < K; ++p) { bd[p] = 1e300; bi[p] = 0x7fffffff; }
        for (int r = lane; r < n; r += 64) {
            if (r == q) continue;
            const float4* xr = (const float4*)(X + (size_t)r * D);
            double acc = 0.0;
#pragma unroll 8
            for (int t = 0; t < D / 4; ++t) {
                const float4 b = xr[t];
                const float4 a = *(const float4*)(&xq[w][t * 4]);
                double d;
                d = (double)a.x - (double)b.x; acc = fma(d, d, acc);
                d = (double)a.y - (double)b.y; acc = fma(d, d, acc);
                d = (double)a.z - (double)b.z; acc = fma(d, d, acc);
                d = (double)a.w - (double)b.w; acc = fma(d, d, acc);
            }
            topk_insert_d<K>(bd, bi, acc, r);
        }
#pragma unroll
        for (int p = 0; p < K; ++p) {
            double md = bd[0]; int mj = bi[0];
#pragma unroll
            for (int u = 1; u < K; ++u)
                if (lexd(bd[u], bi[u], md, mj)) { md = bd[u]; mj = bi[u]; }
#pragma unroll
            for (int off = 32; off >= 1; off >>= 1) {
                const double od = __shfl_xor(md, off, 64);
                const int    oj = __shfl_xor(mj, off, 64);
                if (lexd(od, oj, md, mj)) { md = od; mj = oj; }
            }
            if (lane == 0) idx_out[(size_t)q * K + p] = mj;
#pragma unroll
            for (int u = 0; u < K; ++u)
                if (bi[u] == mj) bd[u] = 1e300;
        }
    }
}

// ---------------- T = X @ W^T (bias folded into gather-max) ----------------
template<int D>
__global__ __launch_bounds__(256)
void lin_kernel(const float* __restrict__ X, const float* __restrict__ W,
                float* __restrict__ T, int n) {
    constexpr int PB = 16;
    __shared__ float Wlds[D * HID];
    __shared__ float Xlds[PB * D];
    const int tid = threadIdx.x;
    const int p0 = blockIdx.x * PB;

    {
        const int h = tid & 127;
        const int hf = tid >> 7;
#pragma unroll
        for (int u = 0; u < D / 8; ++u) {
            const int d0 = hf * (D / 2) + u * 4;
            const float4 v = *(const float4*)(W + (size_t)h * D + d0);
            Wlds[(d0 + 0) * HID + h] = v.x;
            Wlds[(d0 + 1) * HID + h] = v.y;
            Wlds[(d0 + 2) * HID + h] = v.z;
            Wlds[(d0 + 3) * HID + h] = v.w;
        }
    }
    {
        const int rr = tid & 15;
        const int g = tid >> 4;
        constexpr int DG = D / 16;
        const int p = p0 + rr;
        const bool ok = p < n;
#pragma unroll
        for (int u = 0; u < DG / 4; ++u) {
            const int d0 = g * DG + u * 4;
            const float4 v = ok ? *(const float4*)(X + (size_t)p * D + d0)
                                : make_float4(0.f, 0.f, 0.f, 0.f);
            *(float4*)(&Xlds[rr * D + d0]) = v;
        }
    }
    __syncthreads();

    const int pp = tid >> 4;
    const int hh = tid & 15;
    float acc[8];
#pragma unroll
    for (int e = 0; e < 8; ++e) acc[e] = 0.f;
#pragma unroll 4
    for (int d = 0; d < D; ++d) {
        const float xa = Xlds[pp * D + d];
#pragma unroll
        for (int e = 0; e < 8; ++e)
            acc[e] = fmaf(xa, Wlds[d * HID + hh + 16 * e], acc[e]);
    }
    const int p = p0 + pp;
    if (p < n) {
#pragma unroll
        for (int e = 0; e < 8; ++e)
            T[(size_t)p * HID + hh + 16 * e] = acc[e];
    }
}

// ---------------- h[i,:] = max_j T[idx_j,:] - T[i,:] + b ----------------
template<int K>
__global__ void gathermax_kernel(const float* __restrict__ T, const int* __restrict__ idx,
                                 const float* __restrict__ b, float* __restrict__ out, int n) {
    const int i = blockIdx.x;
    const int h = threadIdx.x;
    float m = -__builtin_inff();
#pragma unroll
    for (int t = 0; t < K; ++t) {
        const int j = idx[(size_t)i * K + t];
        m = fmaxf(m, T[(size_t)j * HID + h]);
    }
    out[(size_t)i * HID + h] = m - T[(size_t)i * HID + h] + b[h];
}

// ---------------- out = h2 @ Wl^T + bl ----------------
__global__ void final_kernel(const float* __restrict__ h2, const float* __restrict__ Wl,
                             const float* __restrict__ bl, float* __restrict__ out, int n) {
    const int t = blockIdx.x * 256 + threadIdx.x;
    const int i = t >> 4;
    const int c = t & 15;
    if (i >= n || c >= 10) return;
    const float* hr = h2 + (size_t)i * HID;
    const float* wr = Wl + (size_t)c * HID;
    float s = 0.f;
#pragma unroll 4
    for (int d = 0; d < HID; ++d) s = fmaf(hr[d], wr[d], s);
    out[(size_t)i * 10 + c] = s + bl[c];
}

extern "C" void kernel_launch(void* const* d_in, const int* in_sizes, int n_in,
                              void* d_out, int out_size, void* d_ws, size_t ws_size,
                              hipStream_t stream) {
    const float* x  = (const float*)d_in[0];
    const float* W1 = (const float*)d_in[1];
    const float* b1 = (const float*)d_in[2];
    const float* W2 = (const float*)d_in[3];
    const float* b2 = (const float*)d_in[4];
    const float* Wl = (const float*)d_in[5];
    const float* bl = (const float*)d_in[6];
    float* out = (float*)d_out;
    const int n = in_sizes[0] / 64;   // 10000
    constexpr int K1 = 5, K2 = 10;

    char* ws = (char*)d_ws;
    size_t off = 0;
    auto alloc = [&](size_t bytes) -> void* {
        void* p = ws + off;
        off = (off + bytes + 255) & ~(size_t)255;
        return p;
    };
    // union region: T (lin output) aliases cbuf+smp (disjoint lifetimes):
    // knn phase uses cbuf/smp; lin..gathermax uses T; they never overlap in time.
    const size_t cbufB = (size_t)n * BUD * 4;            // 10.24 MB
    const size_t smpB  = (size_t)n * 4 * K2 * 4;         // 1.6 MB
    const size_t TB_   = (size_t)n * HID * 4;            // 5.12 MB
    const size_t regB  = (cbufB + smpB > TB_) ? (cbufB + smpB) : TB_;
    char*  region = (char*)alloc(regB);
    float* T1   = (float*)region;
    int*   cbuf = (int*)region;
    float* smp  = (float*)(region + cbufB);
    float* h1b  = (float*)alloc((size_t)n * HID * 4);
    float* sqx  = (float*)alloc((size_t)n * 4);
    float* sqh  = (float*)alloc((size_t)n * 4);
    int*   idx1 = (int*)alloc((size_t)n * K1 * 4);
    int*   idx2 = (int*)alloc((size_t)n * K2 * 4);
    u16*   Xhi  = (u16*)alloc((size_t)n * 64 * 2);
    u16*   Hhi  = (u16*)alloc((size_t)n * HID * 2);
    float* tau  = (float*)alloc((size_t)n * 4);
    int*   cnt  = (int*)alloc((size_t)n * 4);
    double* dkth = (double*)alloc((size_t)n * 8);
    int*   ovf  = (int*)alloc((size_t)n * 4);
    int*   novf = (int*)alloc(256);
    float* sqmax = (float*)alloc(256);
    float* T2  = T1;
    float* h2b = h1b;

    const int cps  = (n + NSPLIT - 1) / NSPLIT;   // 1250
    const int qbs  = (n + 63) / 64;               // 157
    const int sstr = n / SMP;                     // 9
    const int nb   = (n + 255) / 256;

    // ---- layer 1 (D=64, K=5) ----
    zero_misc_kernel<<<nb, 256, 0, stream>>>(cnt, novf, sqmax, n);
    sqnorm_kernel<64><<<nb, 256, 0, stream>>>(x, sqx, sqmax, n);
    round_bf16_kernel<<<(n * 64 / 4 + 255) / 256, 256, 0, stream>>>(x, Xhi, n * 64 / 4);
    sample_knn_kernel<64, K1><<<qbs, 256, 0, stream>>>(Xhi, sqx, smp, n, sstr);
    tau_merge_kernel<K1><<<nb, 256, 0, stream>>>(smp, sqx, sqmax, tau, n);
    knn_main_kernel<64><<<dim3(qbs, NSPLIT), 256, 0, stream>>>(Xhi, sqx, tau, cnt, cbuf, n, cps);
    select_kernel<64, K1><<<(n + 3) / 4, 256, 0, stream>>>(x, cbuf, cnt, idx1, dkth, n);
    flag_kernel<K1><<<nb, 256, 0, stream>>>(cnt, dkth, tau, sqx, sqmax, novf, ovf, n);
    fallback_kernel<64, K1><<<128, 256, 0, stream>>>(x, ovf, novf, idx1, n);
    lin_kernel<64><<<(n + 15) / 16, 256, 0, stream>>>(x, W1, T1, n);
    gathermax_kernel<K1><<<n, HID, 0, stream>>>(T1, idx1, b1, h1b, n);

    // ---- layer 2 (D=128, K=10) ----
    zero_misc_kernel<<<nb, 256, 0, stream>>>(cnt, novf, sqmax, n);
    sqnorm_kernel<HID><<<nb, 256, 0, stream>>>(h1b, sqh, sqmax, n);
    round_bf16_kernel<<<(n * HID / 4 + 255) / 256, 256, 0, stream>>>(h1b, Hhi, n * HID / 4);
    sample_knn_kernel<HID, K2><<<qbs, 256, 0, stream>>>(Hhi, sqh, smp, n, sstr);
    tau_merge_kernel<K2><<<nb, 256, 0, stream>>>(smp, sqh, sqmax, tau, n);
    knn_main_kernel<HID><<<dim3(qbs, NSPLIT), 256, 0, stream>>>(Hhi, sqh, tau, cnt, cbuf, n, cps);
    select_kernel<HID, K2><<<(n + 3) / 4, 256, 0, stream>>>(h1b, cbuf, cnt, idx2, dkth, n);
    flag_kernel<K2><<<nb, 256, 0, stream>>>(cnt, dkth, tau, sqh, sqmax, novf, ovf, n);
    fallback_kernel<HID, K2><<<128, 256, 0, stream>>>(h1b, ovf, novf, idx2, n);
    lin_kernel<HID><<<(n + 15) / 16, 256, 0, stream>>>(h1b, W2, T2, n);
    gathermax_kernel<K2><<<n, HID, 0, stream>>>(T2, idx2, b2, h2b, n);

    // ---- head ----
    final_kernel<<<(n * 16 + 255) / 256, 256, 0, stream>>>(h2b, Wl, bl, out, n);
}

// Round 6
// 1203.951 us; speedup vs baseline: 1.1167x; 1.1167x over previous
//
#include <hip/hip_runtime.h>

#define DEVINLINE __device__ __forceinline__

typedef unsigned short u16;
typedef __attribute__((ext_vector_type(8))) short short8v;
typedef __attribute__((ext_vector_type(4))) float float4v;

constexpr int HID = 128;
constexpr int NSPLIT = 8;     // main-pass column splits
constexpr int BUD = 256;      // candidate buffer budget per query
constexpr int SMP = 1024;     // sample size for tau

// ---------- small helpers ----------
DEVINLINE void gld16(const void* g, void* l) {
    __builtin_amdgcn_global_load_lds((const __attribute__((address_space(1))) unsigned int*)g,
                                     (__attribute__((address_space(3))) unsigned int*)l, 16, 0, 0);
}
DEVINLINE void gld4(const void* g, void* l) {
    __builtin_amdgcn_global_load_lds((const __attribute__((address_space(1))) unsigned int*)g,
                                     (__attribute__((address_space(3))) unsigned int*)l, 4, 0, 0);
}
DEVINLINE u16 f2bf(float x) {
    unsigned u = __float_as_uint(x);
    return (u16)((u + 0x7fffu + ((u >> 16) & 1u)) >> 16);
}
DEVINLINE float bf2f(u16 h) { return __uint_as_float(((unsigned)h) << 16); }
// rigorous bound on |screened_d2 - exact_d2| for split-bf16 3-term screening:
// missing terms (al*bl + residuals) <= 3*2^-16*||a||*||b||, fp32 MFMA accum
// rounding <= ~2.5e-5*(sqa+sqb); x2 for the -2*dot -> ~1.0e-4*(sqa+sqb).
// 1.5e-4 + 0.05 slop covers sq/combine fp32 errors too.
DEVINLINE float maxerr_f(float sqq, float sqm) {
    return 1.5e-4f * (sqq + sqm) + 0.05f;
}
// ascending value-only top-K list (static indices)
template<int K>
DEVINLINE void topk_insert_v(float (&bd)[K], float d) {
    if (d >= bd[K - 1]) return;
#pragma unroll
    for (int p = 0; p < K; ++p) {
        const float mn = fminf(d, bd[p]);
        const float mx = fmaxf(d, bd[p]);
        bd[p] = mn; d = mx;
    }
}
DEVINLINE bool lexd(double d1, int i1, double d2, int i2) {
    return (d1 < d2) || ((d1 == d2) && (i1 < i2));
}
template<int K>
DEVINLINE void topk_insert_d(double (&bd)[K], int (&bi)[K], double d, int j) {
    if (!lexd(d, j, bd[K - 1], bi[K - 1])) return;
    double cd = d; int ci = j;
#pragma unroll
    for (int p = 0; p < K; ++p) {
        const bool lt = lexd(cd, ci, bd[p], bi[p]);
        const double sd = bd[p]; const int si = bi[p];
        bd[p] = lt ? cd : sd;  bi[p] = lt ? ci : si;
        cd = lt ? sd : cd;     ci = lt ? si : ci;
    }
}

// ---------------- per-layer init: zero cnt, novf, sqmax ----------------
__global__ void zero_misc_kernel(int* __restrict__ cnt, int* __restrict__ novf,
                                 float* __restrict__ sqmax, int n) {
    const int i = blockIdx.x * 256 + threadIdx.x;
    if (i < n) cnt[i] = 0;
    if (i == 0) { novf[0] = 0; *(int*)sqmax = 0; }
}

// ---------------- squared norms (fp32) + global max ----------------
template<int D>
__global__ void sqnorm_kernel(const float* __restrict__ X, float* __restrict__ sq,
                              float* __restrict__ sqmax, int n) {
    const int i = blockIdx.x * 256 + threadIdx.x;
    float s = 0.f;
    if (i < n) {
        const float4* row = (const float4*)(X + (size_t)i * D);
#pragma unroll
        for (int u = 0; u < D / 4; ++u) {
            const float4 v = row[u];
            s += v.x * v.x + v.y * v.y + v.z * v.z + v.w * v.w;
        }
        sq[i] = s;
    }
    float m = s;
#pragma unroll
    for (int off = 32; off >= 1; off >>= 1) m = fmaxf(m, __shfl_xor(m, off, 64));
    if ((threadIdx.x & 63) == 0) atomicMax((int*)sqmax, __float_as_int(m));
}

// ---------------- split fp32 -> bf16 hi + lo ----------------
__global__ void split_bf16_kernel(const float* __restrict__ X, u16* __restrict__ hi,
                                  u16* __restrict__ lo, int total4) {
    const int i = blockIdx.x * 256 + threadIdx.x;
    if (i >= total4) return;
    const float4 v = ((const float4*)X)[i];
    float xs[4] = {v.x, v.y, v.z, v.w};
    u16 h4[4], l4[4];
#pragma unroll
    for (int e = 0; e < 4; ++e) {
        const u16 h = f2bf(xs[e]);
        h4[e] = h;
        l4[e] = f2bf(xs[e] - bf2f(h));
    }
    ushort4 hv = {h4[0], h4[1], h4[2], h4[3]};
    ushort4 lv = {l4[0], l4[1], l4[2], l4[3]};
    ((ushort4*)hi)[i] = hv;
    ((ushort4*)lo)[i] = lv;
}

// ---------------- sample pass: per-lane-group top-K screened distances ----------------
// Grid ceil(n/64). Sample rows j = s*sstr, s in [0,1024). Split-bf16 3-MFMA.
template<int D, int K>
__global__ __launch_bounds__(256)
void sample_knn_kernel(const u16* __restrict__ Xhi, const u16* __restrict__ Xlo,
                       const float* __restrict__ sq, float* __restrict__ smp,
                       int n, int sstr) {
    constexpr int MB = 64, NMI = 4;
    constexpr int KS = D / 32, SLOTS = D / 8;
    constexpr int TS = MB * SLOTS, TB = TS * 16, SI = 2 * TS / 256;
    constexpr int BUFB = 2 * TB + 384;
    constexpr int NT = SMP / MB;   // 16
    __shared__ __align__(16) char smem[2 * BUFB];

    const int tid = threadIdx.x, lane = tid & 63, wid = tid >> 6;
    const int lrow = lane & 15, lhalf = lane >> 4;
    const int q0 = blockIdx.x * 64;
    const int q = q0 + wid * 16 + lrow, qc = min(q, n - 1);

    short8v qhi[KS], qlo[KS];
#pragma unroll
    for (int ks = 0; ks < KS; ++ks) {
        qhi[ks] = *(const short8v*)(Xhi + (size_t)qc * D + (ks * 4 + lhalf) * 8);
        qlo[ks] = *(const short8v*)(Xlo + (size_t)qc * D + (ks * 4 + lhalf) * 8);
    }
    const float sqq = sq[qc];

    int srow[SI], soff[SI]; bool sislo[SI];
#pragma unroll
    for (int it = 0; it < SI; ++it) {
        const int gs = (it * 4 + wid) * 64 + lane;
        const bool islo = gs >= TS;
        const int s = islo ? gs - TS : gs;
        const int row = s / SLOTS, psl = s % SLOTS;
        const int ksl = (psl & ~7) | ((psl ^ row) & 7);
        srow[it] = row; soff[it] = ksl * 8; sislo[it] = islo;
    }

    float bd[K];
#pragma unroll
    for (int p = 0; p < K; ++p) bd[p] = __builtin_inff();

    auto stage = [&](int t, int b) {
        char* buf = smem + b * BUFB;
        const int s0 = t * MB;
#pragma unroll
        for (int it = 0; it < SI; ++it) {
            const size_t phys = (size_t)(s0 + srow[it]) * sstr;
            const u16* src = (sislo[it] ? Xlo : Xhi) + phys * D + soff[it];
            gld16(src, buf + (it * 4 + wid) * 1024);
        }
        if (wid == 0) gld4(sq + (size_t)(s0 + lane) * sstr, buf + 2 * TB);
    };
    auto compute = [&](int t, int b) {
        const char* buf = smem + b * BUFB;
        const u16* hp = (const u16*)buf;
        const u16* lp = (const u16*)(buf + TB);
        const float* sql = (const float*)(buf + 2 * TB);
        const int s0 = t * MB;
        float4v acc[NMI];
#pragma unroll
        for (int mi = 0; mi < NMI; ++mi) acc[mi] = (float4v){0.f, 0.f, 0.f, 0.f};
#pragma unroll
        for (int ks = 0; ks < KS; ++ks) {
#pragma unroll
            for (int mi = 0; mi < NMI; ++mi) {
                const int row = mi * 16 + lrow;
                const int ksl = ks * 4 + lhalf;
                const int pk = (ksl & ~7) | ((ksl ^ row) & 7);
                const size_t off = (size_t)row * (SLOTS * 8) + pk * 8;
                const short8v ah = *(const short8v*)(hp + off);
                const short8v al = *(const short8v*)(lp + off);
                acc[mi] = __builtin_amdgcn_mfma_f32_16x16x32_bf16(ah, qhi[ks], acc[mi], 0, 0, 0);
                acc[mi] = __builtin_amdgcn_mfma_f32_16x16x32_bf16(ah, qlo[ks], acc[mi], 0, 0, 0);
                acc[mi] = __builtin_amdgcn_mfma_f32_16x16x32_bf16(al, qhi[ks], acc[mi], 0, 0, 0);
            }
        }
#pragma unroll
        for (int mi = 0; mi < NMI; ++mi) {
            const float4 s4 = *(const float4*)(sql + mi * 16 + lhalf * 4);
            const float ss[4] = {s4.x, s4.y, s4.z, s4.w};
#pragma unroll
            for (int r = 0; r < 4; ++r) {
                const int sidx = s0 + mi * 16 + lhalf * 4 + r;
                const int j = sidx * sstr;
                const float d2 = sqq + ss[r] - 2.f * acc[mi][r];
                if (j != q) topk_insert_v<K>(bd, d2);
            }
        }
    };

    stage(0, 0);
    __syncthreads();
    for (int t = 0; t < NT; ++t) {
        if (t + 1 < NT) stage(t + 1, (t + 1) & 1);
        compute(t, t & 1);
        __syncthreads();
    }

    if (q < n) {
        const size_t base = ((size_t)q * 4 + lhalf) * K;
#pragma unroll
        for (int p = 0; p < K; ++p) smp[base + p] = bd[p];
    }
}

// ---------------- merge sample lists -> tau ----------------
template<int K>
__global__ void tau_merge_kernel(const float* __restrict__ smp, const float* __restrict__ sq,
                                 const float* __restrict__ sqmax, float* __restrict__ tau, int n) {
    const int q = blockIdx.x * 256 + threadIdx.x;
    if (q >= n) return;
    float bd[K];
#pragma unroll
    for (int p = 0; p < K; ++p) bd[p] = __builtin_inff();
    for (int g = 0; g < 4; ++g) {
        const size_t base = ((size_t)q * 4 + g) * K;
#pragma unroll
        for (int p = 0; p < K; ++p) topk_insert_v<K>(bd, smp[base + p]);
    }
    const float me = maxerr_f(sq[q], sqmax[0]);
    tau[q] = bd[K - 1] + 2.f * me + 0.0625f;
}

// ---------------- main pass: split-bf16 3-MFMA + threshold compaction ----------------
template<int D>
__global__ __launch_bounds__(256)
void knn_main_kernel(const u16* __restrict__ Xhi, const u16* __restrict__ Xlo,
                     const float* __restrict__ sq, const float* __restrict__ tau,
                     int* __restrict__ cnt, int* __restrict__ cbuf, int n, int cps) {
    constexpr int MB = 64, NMI = 4;
    constexpr int KS = D / 32, SLOTS = D / 8;
    constexpr int TS = MB * SLOTS, TB = TS * 16, SI = 2 * TS / 256;
    constexpr int BUFB = 2 * TB + 384;
    __shared__ __align__(16) char smem[2 * BUFB];

    const int tid = threadIdx.x, lane = tid & 63, wid = tid >> 6;
    const int lrow = lane & 15, lhalf = lane >> 4;
    const int q0 = blockIdx.x * 64, sp = blockIdx.y;
    const int rbeg = sp * cps, rend = min(rbeg + cps, n);
    const int nt = (rend - rbeg + MB - 1) / MB;
    const int q = q0 + wid * 16 + lrow, qc = min(q, n - 1);
    const bool qok = q < n;

    short8v qhi[KS], qlo[KS];
#pragma unroll
    for (int ks = 0; ks < KS; ++ks) {
        qhi[ks] = *(const short8v*)(Xhi + (size_t)qc * D + (ks * 4 + lhalf) * 8);
        qlo[ks] = *(const short8v*)(Xlo + (size_t)qc * D + (ks * 4 + lhalf) * 8);
    }
    const float sqq = sq[qc];
    const float tq = tau[qc];

    int srow[SI], soff[SI]; bool sislo[SI];
#pragma unroll
    for (int it = 0; it < SI; ++it) {
        const int gs = (it * 4 + wid) * 64 + lane;
        const bool islo = gs >= TS;
        const int s = islo ? gs - TS : gs;
        const int row = s / SLOTS, psl = s % SLOTS;
        const int ksl = (psl & ~7) | ((psl ^ row) & 7);
        srow[it] = row; soff[it] = ksl * 8; sislo[it] = islo;
    }

    auto stage = [&](int t, int b) {
        char* buf = smem + b * BUFB;
        const int row0 = rbeg + t * MB;
#pragma unroll
        for (int it = 0; it < SI; ++it) {
            const int grow = min(row0 + srow[it], rend - 1);
            const u16* src = (sislo[it] ? Xlo : Xhi) + (size_t)grow * D + soff[it];
            gld16(src, buf + (it * 4 + wid) * 1024);
        }
        if (tid < MB) gld4(sq + min(row0 + tid, rend - 1), buf + 2 * TB);
    };
    auto compute = [&](int t, int b) {
        const char* buf = smem + b * BUFB;
        const u16* hp = (const u16*)buf;
        const u16* lp = (const u16*)(buf + TB);
        const float* sql = (const float*)(buf + 2 * TB);
        const int row0 = rbeg + t * MB;
        const int rl = rend - row0;
        float4v acc[NMI];
#pragma unroll
        for (int mi = 0; mi < NMI; ++mi) acc[mi] = (float4v){0.f, 0.f, 0.f, 0.f};
#pragma unroll
        for (int ks = 0; ks < KS; ++ks) {
#pragma unroll
            for (int mi = 0; mi < NMI; ++mi) {
                const int row = mi * 16 + lrow;
                const int ksl = ks * 4 + lhalf;
                const int pk = (ksl & ~7) | ((ksl ^ row) & 7);
                const size_t off = (size_t)row * (SLOTS * 8) + pk * 8;
                const short8v ah = *(const short8v*)(hp + off);
                const short8v al = *(const short8v*)(lp + off);
                acc[mi] = __builtin_amdgcn_mfma_f32_16x16x32_bf16(ah, qhi[ks], acc[mi], 0, 0, 0);
                acc[mi] = __builtin_amdgcn_mfma_f32_16x16x32_bf16(ah, qlo[ks], acc[mi], 0, 0, 0);
                acc[mi] = __builtin_amdgcn_mfma_f32_16x16x32_bf16(al, qhi[ks], acc[mi], 0, 0, 0);
            }
        }
#pragma unroll
        for (int mi = 0; mi < NMI; ++mi) {
            const float4 s4 = *(const float4*)(sql + mi * 16 + lhalf * 4);
            const float ss[4] = {s4.x, s4.y, s4.z, s4.w};
#pragma unroll
            for (int r = 0; r < 4; ++r) {
                const int dbr = mi * 16 + lhalf * 4 + r;
                const int j = row0 + dbr;
                const float d2 = sqq + ss[r] - 2.f * acc[mi][r];
                if (qok && dbr < rl && d2 <= tq && j != q) {
                    const int slot = atomicAdd(cnt + q, 1);
                    if (slot < BUD) cbuf[(size_t)q * BUD + slot] = j;
                }
            }
        }
    };

    stage(0, 0);
    __syncthreads();
    for (int t = 0; t < nt; ++t) {
        if (t + 1 < nt) stage(t + 1, (t + 1) & 1);
        compute(t, t & 1);
        __syncthreads();
    }
}

// ---------------- fp64-exact top-K over the candidate buffer (+ kth dist) ----------------
template<int D, int K>
__global__ __launch_bounds__(256)
void select_kernel(const float* __restrict__ X, const int* __restrict__ cbuf,
                   const int* __restrict__ cnt, int* __restrict__ idx_out,
                   double* __restrict__ dkth, int n) {
    __shared__ float xish[4][D];
    const int tid = threadIdx.x, lane = tid & 63, w = tid >> 6;
    const int q = blockIdx.x * 4 + w;
    const int qc = min(q, n - 1);

    if (lane < D / 4)
        *(float4*)(&xish[w][lane * 4]) = *(const float4*)(X + (size_t)qc * D + lane * 4);
    __syncthreads();

    const int cq = min(cnt[qc], BUD);
    double dv[4]; int jv[4];
#pragma unroll
    for (int u = 0; u < 4; ++u) {
        const int c = u * 64 + lane;
        int j = 0x7fffffff;
        double s = 1e300;
        if (c < cq) {
            j = cbuf[(size_t)qc * BUD + c];
            const float4* xj = (const float4*)(X + (size_t)j * D);
            double acc = 0.0;
#pragma unroll 8
            for (int t = 0; t < D / 4; ++t) {
                const float4 b = xj[t];
                const float4 a = *(const float4*)(&xish[w][t * 4]);
                double d;
                d = (double)a.x - (double)b.x; acc = fma(d, d, acc);
                d = (double)a.y - (double)b.y; acc = fma(d, d, acc);
                d = (double)a.z - (double)b.z; acc = fma(d, d, acc);
                d = (double)a.w - (double)b.w; acc = fma(d, d, acc);
            }
            s = acc;
        }
        dv[u] = s; jv[u] = j;
    }

#pragma unroll
    for (int p = 0; p < K; ++p) {
        double md = dv[0]; int mj = jv[0];
#pragma unroll
        for (int u = 1; u < 4; ++u)
            if (lexd(dv[u], jv[u], md, mj)) { md = dv[u]; mj = jv[u]; }
#pragma unroll
        for (int off = 32; off >= 1; off >>= 1) {
            const double od = __shfl_xor(md, off, 64);
            const int    oj = __shfl_xor(mj, off, 64);
            if (lexd(od, oj, md, mj)) { md = od; mj = oj; }
        }
        if (lane == 0 && q < n) {
            idx_out[(size_t)q * K + p] = mj;
            if (p == K - 1) dkth[q] = md;
        }
#pragma unroll
        for (int u = 0; u < 4; ++u)
            if (jv[u] == mj) dv[u] = 1e300;
    }
}

// ---------------- certificate check -> flagged-query list ----------------
template<int K>
__global__ void flag_kernel(const int* __restrict__ cnt, const double* __restrict__ dkth,
                            const float* __restrict__ tau, const float* __restrict__ sq,
                            const float* __restrict__ sqmax, int* __restrict__ novf,
                            int* __restrict__ ovf, int n) {
    const int q = blockIdx.x * 256 + threadIdx.x;
    if (q >= n) return;
    const float me = maxerr_f(sq[q], sqmax[0]);
    const int c = cnt[q];
    const bool bad = (c > BUD) || (c < K) || (dkth[q] + (double)me > (double)tau[q]);
    if (bad) { const int s = atomicAdd(novf, 1); ovf[s] = q; }
}

// ---------------- exact fp64 full-scan fallback for flagged queries ----------------
template<int D, int K>
__global__ __launch_bounds__(256)
void fallback_kernel(const float* __restrict__ X, const int* __restrict__ ovf,
                     const int* __restrict__ novf, int* __restrict__ idx_out, int n) {
    __shared__ float xq[4][D];
    const int tid = threadIdx.x, lane = tid & 63, w = tid >> 6;
    const int gw = blockIdx.x * 4 + w;
    const int total = novf[0];
    for (int e = gw; e < total; e += gridDim.x * 4) {
        const int q = ovf[e];
        if (lane < D / 4)
            *(float4*)(&xq[w][lane * 4]) = *(const float4*)(X + (size_t)q * D + lane * 4);
        double bd[K]; int bi[K];
#pragma unroll
        for (int p = 0; p < K; ++p) { bd[p] = 1e300; bi[p] = 0x7fffffff; }
        for (int r = lane; r < n; r += 64) {
            if (r == q) continue;
            const float4* xr = (const float4*)(X + (size_t)r * D);
            double a0 = 0.0, a1 = 0.0;   // 2 chains for ILP
#pragma unroll
            for (int t = 0; t < D / 8; ++t) {
                const float4 b0 = xr[2 * t], b1 = xr[2 * t + 1];
                const float4 c0 = *(const float4*)(&xq[w][8 * t]);
                const float4 c1 = *(const float4*)(&xq[w][8 * t + 4]);
                double d;
                d = (double)c0.x - (double)b0.x; a0 = fma(d, d, a0);
                d = (double)c0.y - (double)b0.y; a0 = fma(d, d, a0);
                d = (double)c0.z - (double)b0.z; a0 = fma(d, d, a0);
                d = (double)c0.w - (double)b0.w; a0 = fma(d, d, a0);
                d = (double)c1.x - (double)b1.x; a1 = fma(d, d, a1);
                d = (double)c1.y - (double)b1.y; a1 = fma(d, d, a1);
                d = (double)c1.z - (double)b1.z; a1 = fma(d, d, a1);
                d = (double)c1.w - (double)b1.w; a1 = fma(d, d, a1);
            }
            topk_insert_d<K>(bd, bi, a0 + a1, r);
        }
#pragma unroll
        for (int p = 0; p < K; ++p) {
            double md = bd[0]; int mj = bi[0];
#pragma unroll
            for (int u = 1; u < K; ++u)
                if (lexd(bd[u], bi[u], md, mj)) { md = bd[u]; mj = bi[u]; }
#pragma unroll
            for (int off = 32; off >= 1; off >>= 1) {
                const double od = __shfl_xor(md, off, 64);
                const int    oj = __shfl_xor(mj, off, 64);
                if (lexd(od, oj, md, mj)) { md = od; mj = oj; }
            }
            if (lane == 0) idx_out[(size_t)q * K + p] = mj;
#pragma unroll
            for (int u = 0; u < K; ++u)
                if (bi[u] == mj) bd[u] = 1e300;
        }
    }
}

// ---------------- T = X @ W^T (bias folded into gather-max) ----------------
template<int D>
__global__ __launch_bounds__(256)
void lin_kernel(const float* __restrict__ X, const float* __restrict__ W,
                float* __restrict__ T, int n) {
    constexpr int PB = 16;
    __shared__ float Wlds[D * HID];
    __shared__ float Xlds[PB * D];
    const int tid = threadIdx.x;
    const int p0 = blockIdx.x * PB;

    {
        const int h = tid & 127;
        const int hf = tid >> 7;
#pragma unroll
        for (int u = 0; u < D / 8; ++u) {
            const int d0 = hf * (D / 2) + u * 4;
            const float4 v = *(const float4*)(W + (size_t)h * D + d0);
            Wlds[(d0 + 0) * HID + h] = v.x;
            Wlds[(d0 + 1) * HID + h] = v.y;
            Wlds[(d0 + 2) * HID + h] = v.z;
            Wlds[(d0 + 3) * HID + h] = v.w;
        }
    }
    {
        const int rr = tid & 15;
        const int g = tid >> 4;
        constexpr int DG = D / 16;
        const int p = p0 + rr;
        const bool ok = p < n;
#pragma unroll
        for (int u = 0; u < DG / 4; ++u) {
            const int d0 = g * DG + u * 4;
            const float4 v = ok ? *(const float4*)(X + (size_t)p * D + d0)
                                : make_float4(0.f, 0.f, 0.f, 0.f);
            *(float4*)(&Xlds[rr * D + d0]) = v;
        }
    }
    __syncthreads();

    const int pp = tid >> 4;
    const int hh = tid & 15;
    float acc[8];
#pragma unroll
    for (int e = 0; e < 8; ++e) acc[e] = 0.f;
#pragma unroll 4
    for (int d = 0; d < D; ++d) {
        const float xa = Xlds[pp * D + d];
#pragma unroll
        for (int e = 0; e < 8; ++e)
            acc[e] = fmaf(xa, Wlds[d * HID + hh + 16 * e], acc[e]);
    }
    const int p = p0 + pp;
    if (p < n) {
#pragma unroll
        for (int e = 0; e < 8; ++e)
            T[(size_t)p * HID + hh + 16 * e] = acc[e];
    }
}

// ---------------- h[i,:] = max_j T[idx_j,:] - T[i,:] + b ----------------
template<int K>
__global__ void gathermax_kernel(const float* __restrict__ T, const int* __restrict__ idx,
                                 const float* __restrict__ b, float* __restrict__ out, int n) {
    const int i = blockIdx.x;
    const int h = threadIdx.x;
    float m = -__builtin_inff();
#pragma unroll
    for (int t = 0; t < K; ++t) {
        const int j = idx[(size_t)i * K + t];
        m = fmaxf(m, T[(size_t)j * HID + h]);
    }
    out[(size_t)i * HID + h] = m - T[(size_t)i * HID + h] + b[h];
}

// ---------------- out = h2 @ Wl^T + bl ----------------
__global__ void final_kernel(const float* __restrict__ h2, const float* __restrict__ Wl,
                             const float* __restrict__ bl, float* __restrict__ out, int n) {
    const int t = blockIdx.x * 256 + threadIdx.x;
    const int i = t >> 4;
    const int c = t & 15;
    if (i >= n || c >= 10) return;
    const float* hr = h2 + (size_t)i * HID;
    const float* wr = Wl + (size_t)c * HID;
    float s = 0.f;
#pragma unroll 4
    for (int d = 0; d < HID; ++d) s = fmaf(hr[d], wr[d], s);
    out[(size_t)i * 10 + c] = s + bl[c];
}

extern "C" void kernel_launch(void* const* d_in, const int* in_sizes, int n_in,
                              void* d_out, int out_size, void* d_ws, size_t ws_size,
                              hipStream_t stream) {
    const float* x  = (const float*)d_in[0];
    const float* W1 = (const float*)d_in[1];
    const float* b1 = (const float*)d_in[2];
    const float* W2 = (const float*)d_in[3];
    const float* b2 = (const float*)d_in[4];
    const float* Wl = (const float*)d_in[5];
    const float* bl = (const float*)d_in[6];
    float* out = (float*)d_out;
    const int n = in_sizes[0] / 64;   // 10000
    constexpr int K1 = 5, K2 = 10;

    char* ws = (char*)d_ws;
    size_t off = 0;
    auto alloc = [&](size_t bytes) -> void* {
        void* p = ws + off;
        off = (off + bytes + 255) & ~(size_t)255;
        return p;
    };
    // union region: T (lin output) aliases cbuf+smp (disjoint lifetimes).
    const size_t cbufB = (size_t)n * BUD * 4;            // 10.24 MB
    const size_t smpB  = (size_t)n * 4 * K2 * 4;         // 1.6 MB
    const size_t TB_   = (size_t)n * HID * 4;            // 5.12 MB
    const size_t regB  = (cbufB + smpB > TB_) ? (cbufB + smpB) : TB_;
    char*  region = (char*)alloc(regB);
    float* T1   = (float*)region;
    int*   cbuf = (int*)region;
    float* smp  = (float*)(region + cbufB);
    float* h1b  = (float*)alloc((size_t)n * HID * 4);
    float* sqx  = (float*)alloc((size_t)n * 4);
    float* sqh  = (float*)alloc((size_t)n * 4);
    int*   idx1 = (int*)alloc((size_t)n * K1 * 4);
    int*   idx2 = (int*)alloc((size_t)n * K2 * 4);
    u16*   Xhi  = (u16*)alloc((size_t)n * 64 * 2);
    u16*   Xlo  = (u16*)alloc((size_t)n * 64 * 2);
    u16*   Hhi  = (u16*)alloc((size_t)n * HID * 2);
    u16*   Hlo  = (u16*)alloc((size_t)n * HID * 2);
    float* tau  = (float*)alloc((size_t)n * 4);
    int*   cnt  = (int*)alloc((size_t)n * 4);
    double* dkth = (double*)alloc((size_t)n * 8);
    int*   ovf  = (int*)alloc((size_t)n * 4);
    int*   novf = (int*)alloc(256);
    float* sqmax = (float*)alloc(256);
    float* T2  = T1;
    float* h2b = h1b;

    const int cps  = (n + NSPLIT - 1) / NSPLIT;   // 1250
    const int qbs  = (n + 63) / 64;               // 157
    const int sstr = n / SMP;                     // 9
    const int nb   = (n + 255) / 256;

    // ---- layer 1 (D=64, K=5) ----
    zero_misc_kernel<<<nb, 256, 0, stream>>>(cnt, novf, sqmax, n);
    sqnorm_kernel<64><<<nb, 256, 0, stream>>>(x, sqx, sqmax, n);
    split_bf16_kernel<<<(n * 64 / 4 + 255) / 256, 256, 0, stream>>>(x, Xhi, Xlo, n * 64 / 4);
    sample_knn_kernel<64, K1><<<qbs, 256, 0, stream>>>(Xhi, Xlo, sqx, smp, n, sstr);
    tau_merge_kernel<K1><<<nb, 256, 0, stream>>>(smp, sqx, sqmax, tau, n);
    knn_main_kernel<64><<<dim3(qbs, NSPLIT), 256, 0, stream>>>(Xhi, Xlo, sqx, tau, cnt, cbuf, n, cps);
    select_kernel<64, K1><<<(n + 3) / 4, 256, 0, stream>>>(x, cbuf, cnt, idx1, dkth, n);
    flag_kernel<K1><<<nb, 256, 0, stream>>>(cnt, dkth, tau, sqx, sqmax, novf, ovf, n);
    fallback_kernel<64, K1><<<256, 256, 0, stream>>>(x, ovf, novf, idx1, n);
    lin_kernel<64><<<(n + 15) / 16, 256, 0, stream>>>(x, W1, T1, n);
    gathermax_kernel<K1><<<n, HID, 0, stream>>>(T1, idx1, b1, h1b, n);

    // ---- layer 2 (D=128, K=10) ----
    zero_misc_kernel<<<nb, 256, 0, stream>>>(cnt, novf, sqmax, n);
    sqnorm_kernel<HID><<<nb, 256, 0, stream>>>(h1b, sqh, sqmax, n);
    split_bf16_kernel<<<(n * HID / 4 + 255) / 256, 256, 0, stream>>>(h1b, Hhi, Hlo, n * HID / 4);
    sample_knn_kernel<HID, K2><<<qbs, 256, 0, stream>>>(Hhi, Hlo, sqh, smp, n, sstr);
    tau_merge_kernel<K2><<<nb, 256, 0, stream>>>(smp, sqh, sqmax, tau, n);
    knn_main_kernel<HID><<<dim3(qbs, NSPLIT), 256, 0, stream>>>(Hhi, Hlo, sqh, tau, cnt, cbuf, n, cps);
    select_kernel<HID, K2><<<(n + 3) / 4, 256, 0, stream>>>(h1b, cbuf, cnt, idx2, dkth, n);
    flag_kernel<K2><<<nb, 256, 0, stream>>>(cnt, dkth, tau, sqh, sqmax, novf, ovf, n);
    fallback_kernel<HID, K2><<<256, 256, 0, stream>>>(h1b, ovf, novf, idx2, n);
    lin_kernel<HID><<<(n + 15) / 16, 256, 0, stream>>>(h1b, W2, T2, n);
    gathermax_kernel<K2><<<n, HID, 0, stream>>>(T2, idx2, b2, h2b, n);

    // ---- head ----
    final_kernel<<<(n * 16 + 255) / 256, 256, 0, stream>>>(h2b, Wl, bl, out, n);
}

// Round 7
// 775.558 us; speedup vs baseline: 1.7336x; 1.5524x over previous
//
#include <hip/hip_runtime.h>

#define DEVINLINE __device__ __forceinline__

typedef unsigned short u16;
typedef __attribute__((ext_vector_type(8))) short short8v;
typedef __attribute__((ext_vector_type(4))) float float4v;

constexpr int HID = 128;
constexpr int NSPLIT = 8;     // main-pass column splits
constexpr int BUD = 256;      // candidate buffer budget per query
constexpr int SMP = 1024;     // sample size for tau
constexpr int SEGS = 32;      // fallback scan segments per query
constexpr int MAXF = 2048;    // fast-fallback capacity (scratch-sized)

// ---------- small helpers ----------
DEVINLINE void gld16(const void* g, void* l) {
    __builtin_amdgcn_global_load_lds((const __attribute__((address_space(1))) unsigned int*)g,
                                     (__attribute__((address_space(3))) unsigned int*)l, 16, 0, 0);
}
DEVINLINE void gld4(const void* g, void* l) {
    __builtin_amdgcn_global_load_lds((const __attribute__((address_space(1))) unsigned int*)g,
                                     (__attribute__((address_space(3))) unsigned int*)l, 4, 0, 0);
}
DEVINLINE u16 f2bf(float x) {
    unsigned u = __float_as_uint(x);
    return (u16)((u + 0x7fffu + ((u >> 16) & 1u)) >> 16);
}
DEVINLINE float bf2f(u16 h) { return __uint_as_float(((unsigned)h) << 16); }
// rigorous bound on |screened_d2 - exact_d2| for split-bf16 3-term screening.
DEVINLINE float maxerr_f(float sqq, float sqm) {
    return 1.5e-4f * (sqq + sqm) + 0.05f;
}
// ascending value-only top-K list (static indices)
template<int K>
DEVINLINE void topk_insert_v(float (&bd)[K], float d) {
    if (d >= bd[K - 1]) return;
#pragma unroll
    for (int p = 0; p < K; ++p) {
        const float mn = fminf(d, bd[p]);
        const float mx = fmaxf(d, bd[p]);
        bd[p] = mn; d = mx;
    }
}
DEVINLINE bool lexd(double d1, int i1, double d2, int i2) {
    return (d1 < d2) || ((d1 == d2) && (i1 < i2));
}
template<int K>
DEVINLINE void topk_insert_d(double (&bd)[K], int (&bi)[K], double d, int j) {
    if (!lexd(d, j, bd[K - 1], bi[K - 1])) return;
    double cd = d; int ci = j;
#pragma unroll
    for (int p = 0; p < K; ++p) {
        const bool lt = lexd(cd, ci, bd[p], bi[p]);
        const double sd = bd[p]; const int si = bi[p];
        bd[p] = lt ? cd : sd;  bi[p] = lt ? ci : si;
        cd = lt ? sd : cd;     ci = lt ? si : ci;
    }
}

// ---------------- per-layer init ----------------
__global__ void zero_misc_kernel(int* __restrict__ cnt, int* __restrict__ novf,
                                 float* __restrict__ sqmax, int n) {
    const int i = blockIdx.x * 256 + threadIdx.x;
    if (i < n) cnt[i] = 0;
    if (i == 0) { novf[0] = 0; *(int*)sqmax = 0; }
}

// ---------------- squared norms (fp32) + global max ----------------
template<int D>
__global__ void sqnorm_kernel(const float* __restrict__ X, float* __restrict__ sq,
                              float* __restrict__ sqmax, int n) {
    const int i = blockIdx.x * 256 + threadIdx.x;
    float s = 0.f;
    if (i < n) {
        const float4* row = (const float4*)(X + (size_t)i * D);
#pragma unroll
        for (int u = 0; u < D / 4; ++u) {
            const float4 v = row[u];
            s += v.x * v.x + v.y * v.y + v.z * v.z + v.w * v.w;
        }
        sq[i] = s;
    }
    float m = s;
#pragma unroll
    for (int off = 32; off >= 1; off >>= 1) m = fmaxf(m, __shfl_xor(m, off, 64));
    if ((threadIdx.x & 63) == 0) atomicMax((int*)sqmax, __float_as_int(m));
}

// ---------------- split fp32 -> bf16 hi + lo ----------------
__global__ void split_bf16_kernel(const float* __restrict__ X, u16* __restrict__ hi,
                                  u16* __restrict__ lo, int total4) {
    const int i = blockIdx.x * 256 + threadIdx.x;
    if (i >= total4) return;
    const float4 v = ((const float4*)X)[i];
    float xs[4] = {v.x, v.y, v.z, v.w};
    u16 h4[4], l4[4];
#pragma unroll
    for (int e = 0; e < 4; ++e) {
        const u16 h = f2bf(xs[e]);
        h4[e] = h;
        l4[e] = f2bf(xs[e] - bf2f(h));
    }
    ushort4 hv = {h4[0], h4[1], h4[2], h4[3]};
    ushort4 lv = {l4[0], l4[1], l4[2], l4[3]};
    ((ushort4*)hi)[i] = hv;
    ((ushort4*)lo)[i] = lv;
}

// ---------------- sample pass ----------------
template<int D, int K>
__global__ __launch_bounds__(256)
void sample_knn_kernel(const u16* __restrict__ Xhi, const u16* __restrict__ Xlo,
                       const float* __restrict__ sq, float* __restrict__ smp,
                       int n, int sstr) {
    constexpr int MB = 64, NMI = 4;
    constexpr int KS = D / 32, SLOTS = D / 8;
    constexpr int TS = MB * SLOTS, TB = TS * 16, SI = 2 * TS / 256;
    constexpr int BUFB = 2 * TB + 384;
    constexpr int NT = SMP / MB;   // 16
    __shared__ __align__(16) char smem[2 * BUFB];

    const int tid = threadIdx.x, lane = tid & 63, wid = tid >> 6;
    const int lrow = lane & 15, lhalf = lane >> 4;
    const int q0 = blockIdx.x * 64;
    const int q = q0 + wid * 16 + lrow, qc = min(q, n - 1);

    short8v qhi[KS], qlo[KS];
#pragma unroll
    for (int ks = 0; ks < KS; ++ks) {
        qhi[ks] = *(const short8v*)(Xhi + (size_t)qc * D + (ks * 4 + lhalf) * 8);
        qlo[ks] = *(const short8v*)(Xlo + (size_t)qc * D + (ks * 4 + lhalf) * 8);
    }
    const float sqq = sq[qc];

    int srow[SI], soff[SI]; bool sislo[SI];
#pragma unroll
    for (int it = 0; it < SI; ++it) {
        const int gs = (it * 4 + wid) * 64 + lane;
        const bool islo = gs >= TS;
        const int s = islo ? gs - TS : gs;
        const int row = s / SLOTS, psl = s % SLOTS;
        const int ksl = (psl & ~7) | ((psl ^ row) & 7);
        srow[it] = row; soff[it] = ksl * 8; sislo[it] = islo;
    }

    float bd[K];
#pragma unroll
    for (int p = 0; p < K; ++p) bd[p] = __builtin_inff();

    auto stage = [&](int t, int b) {
        char* buf = smem + b * BUFB;
        const int s0 = t * MB;
#pragma unroll
        for (int it = 0; it < SI; ++it) {
            const size_t phys = (size_t)(s0 + srow[it]) * sstr;
            const u16* src = (sislo[it] ? Xlo : Xhi) + phys * D + soff[it];
            gld16(src, buf + (it * 4 + wid) * 1024);
        }
        if (wid == 0) gld4(sq + (size_t)(s0 + lane) * sstr, buf + 2 * TB);
    };
    auto compute = [&](int t, int b) {
        const char* buf = smem + b * BUFB;
        const u16* hp = (const u16*)buf;
        const u16* lp = (const u16*)(buf + TB);
        const float* sql = (const float*)(buf + 2 * TB);
        const int s0 = t * MB;
        float4v acc[NMI];
#pragma unroll
        for (int mi = 0; mi < NMI; ++mi) acc[mi] = (float4v){0.f, 0.f, 0.f, 0.f};
#pragma unroll
        for (int ks = 0; ks < KS; ++ks) {
#pragma unroll
            for (int mi = 0; mi < NMI; ++mi) {
                const int row = mi * 16 + lrow;
                const int ksl = ks * 4 + lhalf;
                const int pk = (ksl & ~7) | ((ksl ^ row) & 7);
                const size_t off = (size_t)row * (SLOTS * 8) + pk * 8;
                const short8v ah = *(const short8v*)(hp + off);
                const short8v al = *(const short8v*)(lp + off);
                acc[mi] = __builtin_amdgcn_mfma_f32_16x16x32_bf16(ah, qhi[ks], acc[mi], 0, 0, 0);
                acc[mi] = __builtin_amdgcn_mfma_f32_16x16x32_bf16(ah, qlo[ks], acc[mi], 0, 0, 0);
                acc[mi] = __builtin_amdgcn_mfma_f32_16x16x32_bf16(al, qhi[ks], acc[mi], 0, 0, 0);
            }
        }
#pragma unroll
        for (int mi = 0; mi < NMI; ++mi) {
            const float4 s4 = *(const float4*)(sql + mi * 16 + lhalf * 4);
            const float ss[4] = {s4.x, s4.y, s4.z, s4.w};
#pragma unroll
            for (int r = 0; r < 4; ++r) {
                const int sidx = s0 + mi * 16 + lhalf * 4 + r;
                const int j = sidx * sstr;
                const float d2 = sqq + ss[r] - 2.f * acc[mi][r];
                if (j != q) topk_insert_v<K>(bd, d2);
            }
        }
    };

    stage(0, 0);
    __syncthreads();
    for (int t = 0; t < NT; ++t) {
        if (t + 1 < NT) stage(t + 1, (t + 1) & 1);
        compute(t, t & 1);
        __syncthreads();
    }

    if (q < n) {
        const size_t base = ((size_t)q * 4 + lhalf) * K;
#pragma unroll
        for (int p = 0; p < K; ++p) smp[base + p] = bd[p];
    }
}

// ---------------- merge sample lists -> tau ----------------
template<int K>
__global__ void tau_merge_kernel(const float* __restrict__ smp, const float* __restrict__ sq,
                                 const float* __restrict__ sqmax, float* __restrict__ tau, int n) {
    const int q = blockIdx.x * 256 + threadIdx.x;
    if (q >= n) return;
    float bd[K];
#pragma unroll
    for (int p = 0; p < K; ++p) bd[p] = __builtin_inff();
    for (int g = 0; g < 4; ++g) {
        const size_t base = ((size_t)q * 4 + g) * K;
#pragma unroll
        for (int p = 0; p < K; ++p) topk_insert_v<K>(bd, smp[base + p]);
    }
    const float me = maxerr_f(sq[q], sqmax[0]);
    tau[q] = bd[K - 1] + 2.f * me + 0.0625f;
}

// ---------------- main pass: split-bf16 3-MFMA + threshold compaction ----------------
template<int D>
__global__ __launch_bounds__(256)
void knn_main_kernel(const u16* __restrict__ Xhi, const u16* __restrict__ Xlo,
                     const float* __restrict__ sq, const float* __restrict__ tau,
                     int* __restrict__ cnt, int* __restrict__ cbuf, int n, int cps) {
    constexpr int MB = 64, NMI = 4;
    constexpr int KS = D / 32, SLOTS = D / 8;
    constexpr int TS = MB * SLOTS, TB = TS * 16, SI = 2 * TS / 256;
    constexpr int BUFB = 2 * TB + 384;
    __shared__ __align__(16) char smem[2 * BUFB];

    const int tid = threadIdx.x, lane = tid & 63, wid = tid >> 6;
    const int lrow = lane & 15, lhalf = lane >> 4;
    const int q0 = blockIdx.x * 64, sp = blockIdx.y;
    const int rbeg = sp * cps, rend = min(rbeg + cps, n);
    const int nt = (rend - rbeg + MB - 1) / MB;
    const int q = q0 + wid * 16 + lrow, qc = min(q, n - 1);
    const bool qok = q < n;

    short8v qhi[KS], qlo[KS];
#pragma unroll
    for (int ks = 0; ks < KS; ++ks) {
        qhi[ks] = *(const short8v*)(Xhi + (size_t)qc * D + (ks * 4 + lhalf) * 8);
        qlo[ks] = *(const short8v*)(Xlo + (size_t)qc * D + (ks * 4 + lhalf) * 8);
    }
    const float sqq = sq[qc];
    const float tq = tau[qc];

    int srow[SI], soff[SI]; bool sislo[SI];
#pragma unroll
    for (int it = 0; it < SI; ++it) {
        const int gs = (it * 4 + wid) * 64 + lane;
        const bool islo = gs >= TS;
        const int s = islo ? gs - TS : gs;
        const int row = s / SLOTS, psl = s % SLOTS;
        const int ksl = (psl & ~7) | ((psl ^ row) & 7);
        srow[it] = row; soff[it] = ksl * 8; sislo[it] = islo;
    }

    auto stage = [&](int t, int b) {
        char* buf = smem + b * BUFB;
        const int row0 = rbeg + t * MB;
#pragma unroll
        for (int it = 0; it < SI; ++it) {
            const int grow = min(row0 + srow[it], rend - 1);
            const u16* src = (sislo[it] ? Xlo : Xhi) + (size_t)grow * D + soff[it];
            gld16(src, buf + (it * 4 + wid) * 1024);
        }
        if (tid < MB) gld4(sq + min(row0 + tid, rend - 1), buf + 2 * TB);
    };
    auto compute = [&](int t, int b) {
        const char* buf = smem + b * BUFB;
        const u16* hp = (const u16*)buf;
        const u16* lp = (const u16*)(buf + TB);
        const float* sql = (const float*)(buf + 2 * TB);
        const int row0 = rbeg + t * MB;
        const int rl = rend - row0;
        float4v acc[NMI];
#pragma unroll
        for (int mi = 0; mi < NMI; ++mi) acc[mi] = (float4v){0.f, 0.f, 0.f, 0.f};
#pragma unroll
        for (int ks = 0; ks < KS; ++ks) {
#pragma unroll
            for (int mi = 0; mi < NMI; ++mi) {
                const int row = mi * 16 + lrow;
                const int ksl = ks * 4 + lhalf;
                const int pk = (ksl & ~7) | ((ksl ^ row) & 7);
                const size_t off = (size_t)row * (SLOTS * 8) + pk * 8;
                const short8v ah = *(const short8v*)(hp + off);
                const short8v al = *(const short8v*)(lp + off);
                acc[mi] = __builtin_amdgcn_mfma_f32_16x16x32_bf16(ah, qhi[ks], acc[mi], 0, 0, 0);
                acc[mi] = __builtin_amdgcn_mfma_f32_16x16x32_bf16(ah, qlo[ks], acc[mi], 0, 0, 0);
                acc[mi] = __builtin_amdgcn_mfma_f32_16x16x32_bf16(al, qhi[ks], acc[mi], 0, 0, 0);
            }
        }
#pragma unroll
        for (int mi = 0; mi < NMI; ++mi) {
            const float4 s4 = *(const float4*)(sql + mi * 16 + lhalf * 4);
            const float ss[4] = {s4.x, s4.y, s4.z, s4.w};
#pragma unroll
            for (int r = 0; r < 4; ++r) {
                const int dbr = mi * 16 + lhalf * 4 + r;
                const int j = row0 + dbr;
                const float d2 = sqq + ss[r] - 2.f * acc[mi][r];
                if (qok && dbr < rl && d2 <= tq && j != q) {
                    const int slot = atomicAdd(cnt + q, 1);
                    if (slot < BUD) cbuf[(size_t)q * BUD + slot] = j;
                }
            }
        }
    };

    stage(0, 0);
    __syncthreads();
    for (int t = 0; t < nt; ++t) {
        if (t + 1 < nt) stage(t + 1, (t + 1) & 1);
        compute(t, t & 1);
        __syncthreads();
    }
}

// ---------------- fp64-exact top-K over the candidate buffer (+ kth dist) ----------------
template<int D, int K>
__global__ __launch_bounds__(256)
void select_kernel(const float* __restrict__ X, const int* __restrict__ cbuf,
                   const int* __restrict__ cnt, int* __restrict__ idx_out,
                   double* __restrict__ dkth, int n) {
    __shared__ float xish[4][D];
    const int tid = threadIdx.x, lane = tid & 63, w = tid >> 6;
    const int q = blockIdx.x * 4 + w;
    const int qc = min(q, n - 1);

    if (lane < D / 4)
        *(float4*)(&xish[w][lane * 4]) = *(const float4*)(X + (size_t)qc * D + lane * 4);
    __syncthreads();

    const int cq = min(cnt[qc], BUD);
    double dv[4]; int jv[4];
#pragma unroll
    for (int u = 0; u < 4; ++u) {
        const int c = u * 64 + lane;
        int j = 0x7fffffff;
        double s = 1e300;
        if (c < cq) {
            j = cbuf[(size_t)qc * BUD + c];
            const float4* xj = (const float4*)(X + (size_t)j * D);
            double acc = 0.0;
#pragma unroll 8
            for (int t = 0; t < D / 4; ++t) {
                const float4 b = xj[t];
                const float4 a = *(const float4*)(&xish[w][t * 4]);
                double d;
                d = (double)a.x - (double)b.x; acc = fma(d, d, acc);
                d = (double)a.y - (double)b.y; acc = fma(d, d, acc);
                d = (double)a.z - (double)b.z; acc = fma(d, d, acc);
                d = (double)a.w - (double)b.w; acc = fma(d, d, acc);
            }
            s = acc;
        }
        dv[u] = s; jv[u] = j;
    }

#pragma unroll
    for (int p = 0; p < K; ++p) {
        double md = dv[0]; int mj = jv[0];
#pragma unroll
        for (int u = 1; u < 4; ++u)
            if (lexd(dv[u], jv[u], md, mj)) { md = dv[u]; mj = jv[u]; }
#pragma unroll
        for (int off = 32; off >= 1; off >>= 1) {
            const double od = __shfl_xor(md, off, 64);
            const int    oj = __shfl_xor(mj, off, 64);
            if (lexd(od, oj, md, mj)) { md = od; mj = oj; }
        }
        if (lane == 0 && q < n) {
            idx_out[(size_t)q * K + p] = mj;
            if (p == K - 1) dkth[q] = md;
        }
#pragma unroll
        for (int u = 0; u < 4; ++u)
            if (jv[u] == mj) dv[u] = 1e300;
    }
}

// ---------------- certificate check -> flagged-query list ----------------
template<int K>
__global__ void flag_kernel(const int* __restrict__ cnt, const double* __restrict__ dkth,
                            const float* __restrict__ tau, const float* __restrict__ sq,
                            const float* __restrict__ sqmax, int* __restrict__ novf,
                            int* __restrict__ ovf, int n) {
    const int q = blockIdx.x * 256 + threadIdx.x;
    if (q >= n) return;
    const float me = maxerr_f(sq[q], sqmax[0]);
    const int c = cnt[q];
    const bool bad = (c > BUD) || (c < K) || (dkth[q] + (double)me > (double)tau[q]);
    if (bad) { const int s = atomicAdd(novf, 1); ovf[s] = q; }
}

// ---------------- parallel exact fallback: per-(query,segment) wave scan ----------------
template<int D, int K>
__global__ __launch_bounds__(256)
void fallback_seg_kernel(const float* __restrict__ X, const int* __restrict__ ovf,
                         const int* __restrict__ novf, double* __restrict__ fbd,
                         int* __restrict__ fbi, int n) {
    __shared__ float xq[4][D];
    const int tid = threadIdx.x, lane = tid & 63, w = tid >> 6;
    const int nwave = gridDim.x * 4;
    const int total = min(novf[0], MAXF);
    const int items = total * SEGS;
    const int segsz = (n + SEGS - 1) / SEGS;
    for (int item = blockIdx.x * 4 + w; item < items; item += nwave) {
        const int e = item / SEGS, s = item % SEGS;
        const int q = ovf[e];
        if (lane < D / 4)
            *(float4*)(&xq[w][lane * 4]) = *(const float4*)(X + (size_t)q * D + lane * 4);
        double bd[K]; int bi[K];
#pragma unroll
        for (int p = 0; p < K; ++p) { bd[p] = 1e300; bi[p] = 0x7fffffff; }
        const int rs = s * segsz, re = min(rs + segsz, n);
        for (int r = rs + lane; r < re; r += 64) {
            if (r == q) continue;
            const float4* xr = (const float4*)(X + (size_t)r * D);
            double a0 = 0.0, a1 = 0.0;
#pragma unroll
            for (int t = 0; t < D / 8; ++t) {
                const float4 b0 = xr[2 * t], b1 = xr[2 * t + 1];
                const float4 c0 = *(const float4*)(&xq[w][8 * t]);
                const float4 c1 = *(const float4*)(&xq[w][8 * t + 4]);
                double d;
                d = (double)c0.x - (double)b0.x; a0 = fma(d, d, a0);
                d = (double)c0.y - (double)b0.y; a0 = fma(d, d, a0);
                d = (double)c0.z - (double)b0.z; a0 = fma(d, d, a0);
                d = (double)c0.w - (double)b0.w; a0 = fma(d, d, a0);
                d = (double)c1.x - (double)b1.x; a1 = fma(d, d, a1);
                d = (double)c1.y - (double)b1.y; a1 = fma(d, d, a1);
                d = (double)c1.z - (double)b1.z; a1 = fma(d, d, a1);
                d = (double)c1.w - (double)b1.w; a1 = fma(d, d, a1);
            }
            topk_insert_d<K>(bd, bi, a0 + a1, r);
        }
#pragma unroll
        for (int p = 0; p < K; ++p) {
            double md = bd[0]; int mj = bi[0];
#pragma unroll
            for (int u = 1; u < K; ++u)
                if (lexd(bd[u], bi[u], md, mj)) { md = bd[u]; mj = bi[u]; }
#pragma unroll
            for (int off = 32; off >= 1; off >>= 1) {
                const double od = __shfl_xor(md, off, 64);
                const int    oj = __shfl_xor(mj, off, 64);
                if (lexd(od, oj, md, mj)) { md = od; mj = oj; }
            }
            if (lane == 0) {
                fbd[(size_t)item * K + p] = md;
                fbi[(size_t)item * K + p] = mj;
            }
#pragma unroll
            for (int u = 0; u < K; ++u)
                if (bi[u] == mj) bd[u] = 1e300;
        }
    }
}

// ---------------- merge per-segment partial top-Ks -> final indices ----------------
template<int K>
__global__ __launch_bounds__(256)
void fallback_merge_kernel(const double* __restrict__ fbd, const int* __restrict__ fbi,
                           const int* __restrict__ ovf, const int* __restrict__ novf,
                           int* __restrict__ idx_out, int n) {
    const int tid = threadIdx.x, lane = tid & 63, w = tid >> 6;
    const int nwave = gridDim.x * 4;
    const int total = min(novf[0], MAXF);
    constexpr int E = SEGS * K;
    constexpr int PL = (E + 63) / 64;
    for (int e = blockIdx.x * 4 + w; e < total; e += nwave) {
        const int q = ovf[e];
        double dv[PL]; int jv[PL];
#pragma unroll
        for (int u = 0; u < PL; ++u) {
            const int c = u * 64 + lane;
            if (c < E) { dv[u] = fbd[(size_t)e * E + c]; jv[u] = fbi[(size_t)e * E + c]; }
            else       { dv[u] = 1e300;                  jv[u] = 0x7fffffff; }
        }
#pragma unroll
        for (int p = 0; p < K; ++p) {
            double md = dv[0]; int mj = jv[0];
#pragma unroll
            for (int u = 1; u < PL; ++u)
                if (lexd(dv[u], jv[u], md, mj)) { md = dv[u]; mj = jv[u]; }
#pragma unroll
            for (int off = 32; off >= 1; off >>= 1) {
                const double od = __shfl_xor(md, off, 64);
                const int    oj = __shfl_xor(mj, off, 64);
                if (lexd(od, oj, md, mj)) { md = od; mj = oj; }
            }
            if (lane == 0) idx_out[(size_t)q * K + p] = mj;
#pragma unroll
            for (int u = 0; u < PL; ++u)
                if (jv[u] == mj) dv[u] = 1e300;
        }
    }
}

// ---------------- serial fallback (only for e >= MAXF; never expected) ----------------
template<int D, int K>
__global__ __launch_bounds__(256)
void fallback_kernel(const float* __restrict__ X, const int* __restrict__ ovf,
                     const int* __restrict__ novf, int* __restrict__ idx_out, int n) {
    __shared__ float xq[4][D];
    const int tid = threadIdx.x, lane = tid & 63, w = tid >> 6;
    const int gw = blockIdx.x * 4 + w;
    const int total = novf[0];
    for (int e = MAXF + gw; e < total; e += gridDim.x * 4) {
        const int q = ovf[e];
        if (lane < D / 4)
            *(float4*)(&xq[w][lane * 4]) = *(const float4*)(X + (size_t)q * D + lane * 4);
        double bd[K]; int bi[K];
#pragma unroll
        for (int p = 0; p < K; ++p) { bd[p] = 1e300; bi[p] = 0x7fffffff; }
        for (int r = lane; r < n; r += 64) {
            if (r == q) continue;
            const float4* xr = (const float4*)(X + (size_t)r * D);
            double a0 = 0.0, a1 = 0.0;
#pragma unroll
            for (int t = 0; t < D / 8; ++t) {
                const float4 b0 = xr[2 * t], b1 = xr[2 * t + 1];
                const float4 c0 = *(const float4*)(&xq[w][8 * t]);
                const float4 c1 = *(const float4*)(&xq[w][8 * t + 4]);
                double d;
                d = (double)c0.x - (double)b0.x; a0 = fma(d, d, a0);
                d = (double)c0.y - (double)b0.y; a0 = fma(d, d, a0);
                d = (double)c0.z - (double)b0.z; a0 = fma(d, d, a0);
                d = (double)c0.w - (double)b0.w; a0 = fma(d, d, a0);
                d = (double)c1.x - (double)b1.x; a1 = fma(d, d, a1);
                d = (double)c1.y - (double)b1.y; a1 = fma(d, d, a1);
                d = (double)c1.z - (double)b1.z; a1 = fma(d, d, a1);
                d = (double)c1.w - (double)b1.w; a1 = fma(d, d, a1);
            }
            topk_insert_d<K>(bd, bi, a0 + a1, r);
        }
#pragma unroll
        for (int p = 0; p < K; ++p) {
            double md = bd[0]; int mj = bi[0];
#pragma unroll
            for (int u = 1; u < K; ++u)
                if (lexd(bd[u], bi[u], md, mj)) { md = bd[u]; mj = bi[u]; }
#pragma unroll
            for (int off = 32; off >= 1; off >>= 1) {
                const double od = __shfl_xor(md, off, 64);
                const int    oj = __shfl_xor(mj, off, 64);
                if (lexd(od, oj, md, mj)) { md = od; mj = oj; }
            }
            if (lane == 0) idx_out[(size_t)q * K + p] = mj;
#pragma unroll
            for (int u = 0; u < K; ++u)
                if (bi[u] == mj) bd[u] = 1e300;
        }
    }
}

// ---------------- T = X @ W^T (bias folded into gather-max) ----------------
template<int D>
__global__ __launch_bounds__(256)
void lin_kernel(const float* __restrict__ X, const float* __restrict__ W,
                float* __restrict__ T, int n) {
    constexpr int PB = 16;
    __shared__ float Wlds[D * HID];
    __shared__ float Xlds[PB * D];
    const int tid = threadIdx.x;
    const int p0 = blockIdx.x * PB;

    {
        const int h = tid & 127;
        const int hf = tid >> 7;
#pragma unroll
        for (int u = 0; u < D / 8; ++u) {
            const int d0 = hf * (D / 2) + u * 4;
            const float4 v = *(const float4*)(W + (size_t)h * D + d0);
            Wlds[(d0 + 0) * HID + h] = v.x;
            Wlds[(d0 + 1) * HID + h] = v.y;
            Wlds[(d0 + 2) * HID + h] = v.z;
            Wlds[(d0 + 3) * HID + h] = v.w;
        }
    }
    {
        const int rr = tid & 15;
        const int g = tid >> 4;
        constexpr int DG = D / 16;
        const int p = p0 + rr;
        const bool ok = p < n;
#pragma unroll
        for (int u = 0; u < DG / 4; ++u) {
            const int d0 = g * DG + u * 4;
            const float4 v = ok ? *(const float4*)(X + (size_t)p * D + d0)
                                : make_float4(0.f, 0.f, 0.f, 0.f);
            *(float4*)(&Xlds[rr * D + d0]) = v;
        }
    }
    __syncthreads();

    const int pp = tid >> 4;
    const int hh = tid & 15;
    float acc[8];
#pragma unroll
    for (int e = 0; e < 8; ++e) acc[e] = 0.f;
#pragma unroll 4
    for (int d = 0; d < D; ++d) {
        const float xa = Xlds[pp * D + d];
#pragma unroll
        for (int e = 0; e < 8; ++e)
            acc[e] = fmaf(xa, Wlds[d * HID + hh + 16 * e], acc[e]);
    }
    const int p = p0 + pp;
    if (p < n) {
#pragma unroll
        for (int e = 0; e < 8; ++e)
            T[(size_t)p * HID + hh + 16 * e] = acc[e];
    }
}

// ---------------- h[i,:] = max_j T[idx_j,:] - T[i,:] + b ----------------
template<int K>
__global__ void gathermax_kernel(const float* __restrict__ T, const int* __restrict__ idx,
                                 const float* __restrict__ b, float* __restrict__ out, int n) {
    const int i = blockIdx.x;
    const int h = threadIdx.x;
    float m = -__builtin_inff();
#pragma unroll
    for (int t = 0; t < K; ++t) {
        const int j = idx[(size_t)i * K + t];
        m = fmaxf(m, T[(size_t)j * HID + h]);
    }
    out[(size_t)i * HID + h] = m - T[(size_t)i * HID + h] + b[h];
}

// ---------------- out = h2 @ Wl^T + bl ----------------
__global__ void final_kernel(const float* __restrict__ h2, const float* __restrict__ Wl,
                             const float* __restrict__ bl, float* __restrict__ out, int n) {
    const int t = blockIdx.x * 256 + threadIdx.x;
    const int i = t >> 4;
    const int c = t & 15;
    if (i >= n || c >= 10) return;
    const float* hr = h2 + (size_t)i * HID;
    const float* wr = Wl + (size_t)c * HID;
    float s = 0.f;
#pragma unroll 4
    for (int d = 0; d < HID; ++d) s = fmaf(hr[d], wr[d], s);
    out[(size_t)i * 10 + c] = s + bl[c];
}

extern "C" void kernel_launch(void* const* d_in, const int* in_sizes, int n_in,
                              void* d_out, int out_size, void* d_ws, size_t ws_size,
                              hipStream_t stream) {
    const float* x  = (const float*)d_in[0];
    const float* W1 = (const float*)d_in[1];
    const float* b1 = (const float*)d_in[2];
    const float* W2 = (const float*)d_in[3];
    const float* b2 = (const float*)d_in[4];
    const float* Wl = (const float*)d_in[5];
    const float* bl = (const float*)d_in[6];
    float* out = (float*)d_out;
    const int n = in_sizes[0] / 64;   // 10000
    constexpr int K1 = 5, K2 = 10;

    char* ws = (char*)d_ws;
    size_t off = 0;
    auto alloc = [&](size_t bytes) -> void* {
        void* p = ws + off;
        off = (off + bytes + 255) & ~(size_t)255;
        return p;
    };
    // union region with disjoint lifetimes:
    //   phase A (knn):      cbuf (BUD ints/query) + smp
    //   phase B (fallback): fbd/fbi  (aliases cbuf, dead after select)
    //   phase C (lin/gm):   T (lin output)
    const size_t cbufB = (size_t)n * BUD * 4;                    // 10.24 MB
    const size_t smpB  = (size_t)n * 4 * K2 * 4;                 // 1.6 MB
    const size_t fbdB  = (size_t)MAXF * SEGS * K2 * 8;           // 5.24 MB
    const size_t fbiB  = (size_t)MAXF * SEGS * K2 * 4;           // 2.62 MB
    const size_t TB_   = (size_t)n * HID * 4;                    // 5.12 MB
    size_t regB = cbufB + smpB;
    if (fbdB + fbiB > regB) regB = fbdB + fbiB;
    if (TB_ > regB) regB = TB_;
    char*  region = (char*)alloc(regB);
    float* T1   = (float*)region;
    int*   cbuf = (int*)region;
    float* smp  = (float*)(region + cbufB);
    double* fbd = (double*)region;
    int*   fbi  = (int*)(region + fbdB);
    float* h1b  = (float*)alloc((size_t)n * HID * 4);
    float* sqx  = (float*)alloc((size_t)n * 4);
    float* sqh  = (float*)alloc((size_t)n * 4);
    int*   idx1 = (int*)alloc((size_t)n * K1 * 4);
    int*   idx2 = (int*)alloc((size_t)n * K2 * 4);
    u16*   Xhi  = (u16*)alloc((size_t)n * 64 * 2);
    u16*   Xlo  = (u16*)alloc((size_t)n * 64 * 2);
    u16*   Hhi  = (u16*)alloc((size_t)n * HID * 2);
    u16*   Hlo  = (u16*)alloc((size_t)n * HID * 2);
    float* tau  = (float*)alloc((size_t)n * 4);
    int*   cnt  = (int*)alloc((size_t)n * 4);
    double* dkth = (double*)alloc((size_t)n * 8);
    int*   ovf  = (int*)alloc((size_t)n * 4);
    int*   novf = (int*)alloc(256);
    float* sqmax = (float*)alloc(256);
    float* T2  = T1;
    float* h2b = h1b;

    const int cps  = (n + NSPLIT - 1) / NSPLIT;   // 1250
    const int qbs  = (n + 63) / 64;               // 157
    const int sstr = n / SMP;                     // 9
    const int nb   = (n + 255) / 256;

    // ---- layer 1 (D=64, K=5) ----
    zero_misc_kernel<<<nb, 256, 0, stream>>>(cnt, novf, sqmax, n);
    sqnorm_kernel<64><<<nb, 256, 0, stream>>>(x, sqx, sqmax, n);
    split_bf16_kernel<<<(n * 64 / 4 + 255) / 256, 256, 0, stream>>>(x, Xhi, Xlo, n * 64 / 4);
    sample_knn_kernel<64, K1><<<qbs, 256, 0, stream>>>(Xhi, Xlo, sqx, smp, n, sstr);
    tau_merge_kernel<K1><<<nb, 256, 0, stream>>>(smp, sqx, sqmax, tau, n);
    knn_main_kernel<64><<<dim3(qbs, NSPLIT), 256, 0, stream>>>(Xhi, Xlo, sqx, tau, cnt, cbuf, n, cps);
    select_kernel<64, K1><<<(n + 3) / 4, 256, 0, stream>>>(x, cbuf, cnt, idx1, dkth, n);
    flag_kernel<K1><<<nb, 256, 0, stream>>>(cnt, dkth, tau, sqx, sqmax, novf, ovf, n);
    fallback_seg_kernel<64, K1><<<1024, 256, 0, stream>>>(x, ovf, novf, fbd, fbi, n);
    fallback_merge_kernel<K1><<<256, 256, 0, stream>>>(fbd, fbi, ovf, novf, idx1, n);
    fallback_kernel<64, K1><<<256, 256, 0, stream>>>(x, ovf, novf, idx1, n);
    lin_kernel<64><<<(n + 15) / 16, 256, 0, stream>>>(x, W1, T1, n);
    gathermax_kernel<K1><<<n, HID, 0, stream>>>(T1, idx1, b1, h1b, n);

    // ---- layer 2 (D=128, K=10) ----
    zero_misc_kernel<<<nb, 256, 0, stream>>>(cnt, novf, sqmax, n);
    sqnorm_kernel<HID><<<nb, 256, 0, stream>>>(h1b, sqh, sqmax, n);
    split_bf16_kernel<<<(n * HID / 4 + 255) / 256, 256, 0, stream>>>(h1b, Hhi, Hlo, n * HID / 4);
    sample_knn_kernel<HID, K2><<<qbs, 256, 0, stream>>>(Hhi, Hlo, sqh, smp, n, sstr);
    tau_merge_kernel<K2><<<nb, 256, 0, stream>>>(smp, sqh, sqmax, tau, n);
    knn_main_kernel<HID><<<dim3(qbs, NSPLIT), 256, 0, stream>>>(Hhi, Hlo, sqh, tau, cnt, cbuf, n, cps);
    select_kernel<HID, K2><<<(n + 3) / 4, 256, 0, stream>>>(h1b, cbuf, cnt, idx2, dkth, n);
    flag_kernel<K2><<<nb, 256, 0, stream>>>(cnt, dkth, tau, sqh, sqmax, novf, ovf, n);
    fallback_seg_kernel<HID, K2><<<1024, 256, 0, stream>>>(h1b, ovf, novf, fbd, fbi, n);
    fallback_merge_kernel<K2><<<256, 256, 0, stream>>>(fbd, fbi, ovf, novf, idx2, n);
    fallback_kernel<HID, K2><<<256, 256, 0, stream>>>(h1b, ovf, novf, idx2, n);
    lin_kernel<HID><<<(n + 15) / 16, 256, 0, stream>>>(h1b, W2, T2, n);
    gathermax_kernel<K2><<<n, HID, 0, stream>>>(T2, idx2, b2, h2b, n);

    // ---- head ----
    final_kernel<<<(n * 16 + 255) / 256, 256, 0, stream>>>(h2b, Wl, bl, out, n);
}

// Round 8
// 628.118 us; speedup vs baseline: 2.1405x; 1.2347x over previous
//
#include <hip/hip_runtime.h>

#define DEVINLINE __device__ __forceinline__

typedef unsigned short u16;
typedef __attribute__((ext_vector_type(8))) short short8v;
typedef __attribute__((ext_vector_type(4))) float float4v;

constexpr int HID = 128;
constexpr int NSPLIT = 8;     // main-pass column splits
constexpr int BUDS = 32;      // candidate budget per (split, query)
constexpr int BUD = NSPLIT * BUDS;   // 256 total select capacity
constexpr int SMP = 1024;     // sample size for tau
constexpr int SEGS = 32;      // fallback scan segments per query
constexpr int MAXF = 2048;    // fast-fallback capacity (scratch-sized)

// ---------- small helpers ----------
DEVINLINE void gld16(const void* g, void* l) {
    __builtin_amdgcn_global_load_lds((const __attribute__((address_space(1))) unsigned int*)g,
                                     (__attribute__((address_space(3))) unsigned int*)l, 16, 0, 0);
}
DEVINLINE void gld4(const void* g, void* l) {
    __builtin_amdgcn_global_load_lds((const __attribute__((address_space(1))) unsigned int*)g,
                                     (__attribute__((address_space(3))) unsigned int*)l, 4, 0, 0);
}
DEVINLINE u16 f2bf(float x) {
    unsigned u = __float_as_uint(x);
    return (u16)((u + 0x7fffu + ((u >> 16) & 1u)) >> 16);
}
DEVINLINE float bf2f(u16 h) { return __uint_as_float(((unsigned)h) << 16); }
// rigorous bound on |screened_d2 - exact_d2| for split-bf16 3-term screening.
DEVINLINE float maxerr_f(float sqq, float sqm) {
    return 1.5e-4f * (sqq + sqm) + 0.05f;
}
// ascending value-only top-K list (static indices)
template<int K>
DEVINLINE void topk_insert_v(float (&bd)[K], float d) {
    if (d >= bd[K - 1]) return;
#pragma unroll
    for (int p = 0; p < K; ++p) {
        const float mn = fminf(d, bd[p]);
        const float mx = fmaxf(d, bd[p]);
        bd[p] = mn; d = mx;
    }
}
DEVINLINE bool lexd(double d1, int i1, double d2, int i2) {
    return (d1 < d2) || ((d1 == d2) && (i1 < i2));
}
template<int K>
DEVINLINE void topk_insert_d(double (&bd)[K], int (&bi)[K], double d, int j) {
    if (!lexd(d, j, bd[K - 1], bi[K - 1])) return;
    double cd = d; int ci = j;
#pragma unroll
    for (int p = 0; p < K; ++p) {
        const bool lt = lexd(cd, ci, bd[p], bi[p]);
        const double sd = bd[p]; const int si = bi[p];
        bd[p] = lt ? cd : sd;  bi[p] = lt ? ci : si;
        cd = lt ? sd : cd;     ci = lt ? si : ci;
    }
}

// ---------------- per-layer init (novf + sqmax only; cnt8 fully overwritten) ----------------
__global__ void zero_misc_kernel(int* __restrict__ novf, float* __restrict__ sqmax) {
    if (blockIdx.x == 0 && threadIdx.x == 0) { novf[0] = 0; *(int*)sqmax = 0; }
}

// ---------------- squared norms (fp32) + global max ----------------
template<int D>
__global__ void sqnorm_kernel(const float* __restrict__ X, float* __restrict__ sq,
                              float* __restrict__ sqmax, int n) {
    const int i = blockIdx.x * 256 + threadIdx.x;
    float s = 0.f;
    if (i < n) {
        const float4* row = (const float4*)(X + (size_t)i * D);
#pragma unroll
        for (int u = 0; u < D / 4; ++u) {
            const float4 v = row[u];
            s += v.x * v.x + v.y * v.y + v.z * v.z + v.w * v.w;
        }
        sq[i] = s;
    }
    float m = s;
#pragma unroll
    for (int off = 32; off >= 1; off >>= 1) m = fmaxf(m, __shfl_xor(m, off, 64));
    if ((threadIdx.x & 63) == 0) atomicMax((int*)sqmax, __float_as_int(m));
}

// ---------------- split fp32 -> bf16 hi + lo ----------------
__global__ void split_bf16_kernel(const float* __restrict__ X, u16* __restrict__ hi,
                                  u16* __restrict__ lo, int total4) {
    const int i = blockIdx.x * 256 + threadIdx.x;
    if (i >= total4) return;
    const float4 v = ((const float4*)X)[i];
    float xs[4] = {v.x, v.y, v.z, v.w};
    u16 h4[4], l4[4];
#pragma unroll
    for (int e = 0; e < 4; ++e) {
        const u16 h = f2bf(xs[e]);
        h4[e] = h;
        l4[e] = f2bf(xs[e] - bf2f(h));
    }
    ushort4 hv = {h4[0], h4[1], h4[2], h4[3]};
    ushort4 lv = {l4[0], l4[1], l4[2], l4[3]};
    ((ushort4*)hi)[i] = hv;
    ((ushort4*)lo)[i] = lv;
}

// ---------------- sample pass ----------------
template<int D, int K>
__global__ __launch_bounds__(256)
void sample_knn_kernel(const u16* __restrict__ Xhi, const u16* __restrict__ Xlo,
                       const float* __restrict__ sq, float* __restrict__ smp,
                       int n, int sstr) {
    constexpr int MB = 64, NMI = 4;
    constexpr int KS = D / 32, SLOTS = D / 8;
    constexpr int TS = MB * SLOTS, TB = TS * 16, SI = 2 * TS / 256;
    constexpr int BUFB = 2 * TB + 384;
    constexpr int NT = SMP / MB;   // 16
    __shared__ __align__(16) char smem[2 * BUFB];

    const int tid = threadIdx.x, lane = tid & 63, wid = tid >> 6;
    const int lrow = lane & 15, lhalf = lane >> 4;
    const int q0 = blockIdx.x * 64;
    const int q = q0 + wid * 16 + lrow, qc = min(q, n - 1);

    short8v qhi[KS], qlo[KS];
#pragma unroll
    for (int ks = 0; ks < KS; ++ks) {
        qhi[ks] = *(const short8v*)(Xhi + (size_t)qc * D + (ks * 4 + lhalf) * 8);
        qlo[ks] = *(const short8v*)(Xlo + (size_t)qc * D + (ks * 4 + lhalf) * 8);
    }
    const float sqq = sq[qc];

    int srow[SI], soff[SI]; bool sislo[SI];
#pragma unroll
    for (int it = 0; it < SI; ++it) {
        const int gs = (it * 4 + wid) * 64 + lane;
        const bool islo = gs >= TS;
        const int s = islo ? gs - TS : gs;
        const int row = s / SLOTS, psl = s % SLOTS;
        const int ksl = (psl & ~7) | ((psl ^ row) & 7);
        srow[it] = row; soff[it] = ksl * 8; sislo[it] = islo;
    }

    float bd[K];
#pragma unroll
    for (int p = 0; p < K; ++p) bd[p] = __builtin_inff();

    auto stage = [&](int t, int b) {
        char* buf = smem + b * BUFB;
        const int s0 = t * MB;
#pragma unroll
        for (int it = 0; it < SI; ++it) {
            const size_t phys = (size_t)(s0 + srow[it]) * sstr;
            const u16* src = (sislo[it] ? Xlo : Xhi) + phys * D + soff[it];
            gld16(src, buf + (it * 4 + wid) * 1024);
        }
        if (wid == 0) gld4(sq + (size_t)(s0 + lane) * sstr, buf + 2 * TB);
    };
    auto compute = [&](int t, int b) {
        const char* buf = smem + b * BUFB;
        const u16* hp = (const u16*)buf;
        const u16* lp = (const u16*)(buf + TB);
        const float* sql = (const float*)(buf + 2 * TB);
        const int s0 = t * MB;
        float4v acc[NMI];
#pragma unroll
        for (int mi = 0; mi < NMI; ++mi) acc[mi] = (float4v){0.f, 0.f, 0.f, 0.f};
#pragma unroll
        for (int ks = 0; ks < KS; ++ks) {
#pragma unroll
            for (int mi = 0; mi < NMI; ++mi) {
                const int row = mi * 16 + lrow;
                const int ksl = ks * 4 + lhalf;
                const int pk = (ksl & ~7) | ((ksl ^ row) & 7);
                const size_t off = (size_t)row * (SLOTS * 8) + pk * 8;
                const short8v ah = *(const short8v*)(hp + off);
                const short8v al = *(const short8v*)(lp + off);
                acc[mi] = __builtin_amdgcn_mfma_f32_16x16x32_bf16(ah, qhi[ks], acc[mi], 0, 0, 0);
                acc[mi] = __builtin_amdgcn_mfma_f32_16x16x32_bf16(ah, qlo[ks], acc[mi], 0, 0, 0);
                acc[mi] = __builtin_amdgcn_mfma_f32_16x16x32_bf16(al, qhi[ks], acc[mi], 0, 0, 0);
            }
        }
#pragma unroll
        for (int mi = 0; mi < NMI; ++mi) {
            const float4 s4 = *(const float4*)(sql + mi * 16 + lhalf * 4);
            const float ss[4] = {s4.x, s4.y, s4.z, s4.w};
#pragma unroll
            for (int r = 0; r < 4; ++r) {
                const int sidx = s0 + mi * 16 + lhalf * 4 + r;
                const int j = sidx * sstr;
                const float d2 = sqq + ss[r] - 2.f * acc[mi][r];
                if (j != q) topk_insert_v<K>(bd, d2);
            }
        }
    };

    stage(0, 0);
    __syncthreads();
    for (int t = 0; t < NT; ++t) {
        if (t + 1 < NT) stage(t + 1, (t + 1) & 1);
        compute(t, t & 1);
        __syncthreads();
    }

    if (q < n) {
        const size_t base = ((size_t)q * 4 + lhalf) * K;
#pragma unroll
        for (int p = 0; p < K; ++p) smp[base + p] = bd[p];
    }
}

// ---------------- merge sample lists -> tau ----------------
template<int K>
__global__ void tau_merge_kernel(const float* __restrict__ smp, const float* __restrict__ sq,
                                 const float* __restrict__ sqmax, float* __restrict__ tau, int n) {
    const int q = blockIdx.x * 256 + threadIdx.x;
    if (q >= n) return;
    float bd[K];
#pragma unroll
    for (int p = 0; p < K; ++p) bd[p] = __builtin_inff();
    for (int g = 0; g < 4; ++g) {
        const size_t base = ((size_t)q * 4 + g) * K;
#pragma unroll
        for (int p = 0; p < K; ++p) topk_insert_v<K>(bd, smp[base + p]);
    }
    const float me = maxerr_f(sq[q], sqmax[0]);
    tau[q] = bd[K - 1] + 2.f * me + 0.0625f;
}

// ---------------- main pass: split-bf16 3-MFMA + LDS-counter compaction ----------------
// Block = (query-block, split) uniquely owns cnt8[sp][q0..q0+63]: counts live in
// LDS (atomicAdd is LDS-local, no L2 round-trip), candidate stores are plain
// global stores into the block's private strip cbuf[(sp*n+q)*BUDS ...].
template<int D>
__global__ __launch_bounds__(256)
void knn_main_kernel(const u16* __restrict__ Xhi, const u16* __restrict__ Xlo,
                     const float* __restrict__ sq, const float* __restrict__ tau,
                     int* __restrict__ cnt8, int* __restrict__ cbuf, int n, int cps) {
    constexpr int MB = 64, NMI = 4;
    constexpr int KS = D / 32, SLOTS = D / 8;
    constexpr int TS = MB * SLOTS, TB = TS * 16, SI = 2 * TS / 256;
    constexpr int BUFB = 2 * TB + 384;
    __shared__ __align__(16) char smem[2 * BUFB];
    __shared__ int scnt[64];

    const int tid = threadIdx.x, lane = tid & 63, wid = tid >> 6;
    const int lrow = lane & 15, lhalf = lane >> 4;
    const int q0 = blockIdx.x * 64, sp = blockIdx.y;
    const int rbeg = sp * cps, rend = min(rbeg + cps, n);
    const int nt = (rend - rbeg + MB - 1) / MB;
    const int q = q0 + wid * 16 + lrow, qc = min(q, n - 1);
    const bool qok = q < n;
    const int qloc = wid * 16 + lrow;

    short8v qhi[KS], qlo[KS];
#pragma unroll
    for (int ks = 0; ks < KS; ++ks) {
        qhi[ks] = *(const short8v*)(Xhi + (size_t)qc * D + (ks * 4 + lhalf) * 8);
        qlo[ks] = *(const short8v*)(Xlo + (size_t)qc * D + (ks * 4 + lhalf) * 8);
    }
    const float sqq = sq[qc];
    const float tq = tau[qc];

    int srow[SI], soff[SI]; bool sislo[SI];
#pragma unroll
    for (int it = 0; it < SI; ++it) {
        const int gs = (it * 4 + wid) * 64 + lane;
        const bool islo = gs >= TS;
        const int s = islo ? gs - TS : gs;
        const int row = s / SLOTS, psl = s % SLOTS;
        const int ksl = (psl & ~7) | ((psl ^ row) & 7);
        srow[it] = row; soff[it] = ksl * 8; sislo[it] = islo;
    }

    auto stage = [&](int t, int b) {
        char* buf = smem + b * BUFB;
        const int row0 = rbeg + t * MB;
#pragma unroll
        for (int it = 0; it < SI; ++it) {
            const int grow = min(row0 + srow[it], rend - 1);
            const u16* src = (sislo[it] ? Xlo : Xhi) + (size_t)grow * D + soff[it];
            gld16(src, buf + (it * 4 + wid) * 1024);
        }
        if (tid < MB) gld4(sq + min(row0 + tid, rend - 1), buf + 2 * TB);
    };
    auto compute = [&](int t, int b) {
        const char* buf = smem + b * BUFB;
        const u16* hp = (const u16*)buf;
        const u16* lp = (const u16*)(buf + TB);
        const float* sql = (const float*)(buf + 2 * TB);
        const int row0 = rbeg + t * MB;
        const int rl = rend - row0;
        float4v acc[NMI];
#pragma unroll
        for (int mi = 0; mi < NMI; ++mi) acc[mi] = (float4v){0.f, 0.f, 0.f, 0.f};
#pragma unroll
        for (int ks = 0; ks < KS; ++ks) {
#pragma unroll
            for (int mi = 0; mi < NMI; ++mi) {
                const int row = mi * 16 + lrow;
                const int ksl = ks * 4 + lhalf;
                const int pk = (ksl & ~7) | ((ksl ^ row) & 7);
                const size_t off = (size_t)row * (SLOTS * 8) + pk * 8;
                const short8v ah = *(const short8v*)(hp + off);
                const short8v al = *(const short8v*)(lp + off);
                acc[mi] = __builtin_amdgcn_mfma_f32_16x16x32_bf16(ah, qhi[ks], acc[mi], 0, 0, 0);
                acc[mi] = __builtin_amdgcn_mfma_f32_16x16x32_bf16(ah, qlo[ks], acc[mi], 0, 0, 0);
                acc[mi] = __builtin_amdgcn_mfma_f32_16x16x32_bf16(al, qhi[ks], acc[mi], 0, 0, 0);
            }
        }
#pragma unroll
        for (int mi = 0; mi < NMI; ++mi) {
            const float4 s4 = *(const float4*)(sql + mi * 16 + lhalf * 4);
            const float ss[4] = {s4.x, s4.y, s4.z, s4.w};
#pragma unroll
            for (int r = 0; r < 4; ++r) {
                const int dbr = mi * 16 + lhalf * 4 + r;
                const int j = row0 + dbr;
                const float d2 = sqq + ss[r] - 2.f * acc[mi][r];
                if (qok && dbr < rl && d2 <= tq && j != q) {
                    const int slot = atomicAdd(&scnt[qloc], 1);   // LDS atomic
                    if (slot < BUDS) cbuf[((size_t)sp * n + q) * BUDS + slot] = j;
                }
            }
        }
    };

    if (tid < 64) scnt[tid] = 0;
    stage(0, 0);
    __syncthreads();
    for (int t = 0; t < nt; ++t) {
        if (t + 1 < nt) stage(t + 1, (t + 1) & 1);
        compute(t, t & 1);
        __syncthreads();
    }
    if (tid < 64) {
        const int qq = q0 + tid;
        if (qq < n) cnt8[(size_t)sp * n + qq] = scnt[tid];
    }
}

// ---------------- fp64-exact top-K over the 8x32 candidate strips ----------------
template<int D, int K>
__global__ __launch_bounds__(256)
void select_kernel(const float* __restrict__ X, const int* __restrict__ cbuf,
                   const int* __restrict__ cnt8, int* __restrict__ idx_out,
                   double* __restrict__ dkth, int n) {
    __shared__ float xish[4][D];
    const int tid = threadIdx.x, lane = tid & 63, w = tid >> 6;
    const int q = blockIdx.x * 4 + w;
    const int qc = min(q, n - 1);

    if (lane < D / 4)
        *(float4*)(&xish[w][lane * 4]) = *(const float4*)(X + (size_t)qc * D + lane * 4);
    __syncthreads();

    double dv[4]; int jv[4];
#pragma unroll
    for (int u = 0; u < 4; ++u) {
        const int c = u * 64 + lane;        // 0..255
        const int spc = c >> 5, slot = c & 31;
        int j = 0x7fffffff;
        double s = 1e300;
        const int cc = min(cnt8[(size_t)spc * n + qc], BUDS);
        if (slot < cc) {
            j = cbuf[((size_t)spc * n + qc) * BUDS + slot];
            const float4* xj = (const float4*)(X + (size_t)j * D);
            double acc = 0.0;
#pragma unroll 8
            for (int t = 0; t < D / 4; ++t) {
                const float4 b = xj[t];
                const float4 a = *(const float4*)(&xish[w][t * 4]);
                double d;
                d = (double)a.x - (double)b.x; acc = fma(d, d, acc);
                d = (double)a.y - (double)b.y; acc = fma(d, d, acc);
                d = (double)a.z - (double)b.z; acc = fma(d, d, acc);
                d = (double)a.w - (double)b.w; acc = fma(d, d, acc);
            }
            s = acc;
        }
        dv[u] = s; jv[u] = j;
    }

#pragma unroll
    for (int p = 0; p < K; ++p) {
        double md = dv[0]; int mj = jv[0];
#pragma unroll
        for (int u = 1; u < 4; ++u)
            if (lexd(dv[u], jv[u], md, mj)) { md = dv[u]; mj = jv[u]; }
#pragma unroll
        for (int off = 32; off >= 1; off >>= 1) {
            const double od = __shfl_xor(md, off, 64);
            const int    oj = __shfl_xor(mj, off, 64);
            if (lexd(od, oj, md, mj)) { md = od; mj = oj; }
        }
        if (lane == 0 && q < n) {
            idx_out[(size_t)q * K + p] = mj;
            if (p == K - 1) dkth[q] = md;
        }
#pragma unroll
        for (int u = 0; u < 4; ++u)
            if (jv[u] == mj) dv[u] = 1e300;
    }
}

// ---------------- certificate check -> flagged-query list ----------------
template<int K>
__global__ void flag_kernel(const int* __restrict__ cnt8, const double* __restrict__ dkth,
                            const float* __restrict__ tau, const float* __restrict__ sq,
                            const float* __restrict__ sqmax, int* __restrict__ novf,
                            int* __restrict__ ovf, int n) {
    const int q = blockIdx.x * 256 + threadIdx.x;
    if (q >= n) return;
    const float me = maxerr_f(sq[q], sqmax[0]);
    int tot = 0; bool ov = false;
#pragma unroll
    for (int spc = 0; spc < NSPLIT; ++spc) {
        const int c = cnt8[(size_t)spc * n + q];
        tot += c; ov |= (c > BUDS);
    }
    const bool bad = ov || (tot < K) || (dkth[q] + (double)me > (double)tau[q]);
    if (bad) { const int s = atomicAdd(novf, 1); ovf[s] = q; }
}

// ---------------- parallel exact fallback: per-(query,segment) wave scan ----------------
template<int D, int K>
__global__ __launch_bounds__(256)
void fallback_seg_kernel(const float* __restrict__ X, const int* __restrict__ ovf,
                         const int* __restrict__ novf, double* __restrict__ fbd,
                         int* __restrict__ fbi, int n) {
    __shared__ float xq[4][D];
    const int tid = threadIdx.x, lane = tid & 63, w = tid >> 6;
    const int nwave = gridDim.x * 4;
    const int total = min(novf[0], MAXF);
    const int items = total * SEGS;
    const int segsz = (n + SEGS - 1) / SEGS;
    for (int item = blockIdx.x * 4 + w; item < items; item += nwave) {
        const int e = item / SEGS, s = item % SEGS;
        const int q = ovf[e];
        if (lane < D / 4)
            *(float4*)(&xq[w][lane * 4]) = *(const float4*)(X + (size_t)q * D + lane * 4);
        double bd[K]; int bi[K];
#pragma unroll
        for (int p = 0; p < K; ++p) { bd[p] = 1e300; bi[p] = 0x7fffffff; }
        const int rs = s * segsz, re = min(rs + segsz, n);
        for (int r = rs + lane; r < re; r += 64) {
            if (r == q) continue;
            const float4* xr = (const float4*)(X + (size_t)r * D);
            double a0 = 0.0, a1 = 0.0;
#pragma unroll
            for (int t = 0; t < D / 8; ++t) {
                const float4 b0 = xr[2 * t], b1 = xr[2 * t + 1];
                const float4 c0 = *(const float4*)(&xq[w][8 * t]);
                const float4 c1 = *(const float4*)(&xq[w][8 * t + 4]);
                double d;
                d = (double)c0.x - (double)b0.x; a0 = fma(d, d, a0);
                d = (double)c0.y - (double)b0.y; a0 = fma(d, d, a0);
                d = (double)c0.z - (double)b0.z; a0 = fma(d, d, a0);
                d = (double)c0.w - (double)b0.w; a0 = fma(d, d, a0);
                d = (double)c1.x - (double)b1.x; a1 = fma(d, d, a1);
                d = (double)c1.y - (double)b1.y; a1 = fma(d, d, a1);
                d = (double)c1.z - (double)b1.z; a1 = fma(d, d, a1);
                d = (double)c1.w - (double)b1.w; a1 = fma(d, d, a1);
            }
            topk_insert_d<K>(bd, bi, a0 + a1, r);
        }
#pragma unroll
        for (int p = 0; p < K; ++p) {
            double md = bd[0]; int mj = bi[0];
#pragma unroll
            for (int u = 1; u < K; ++u)
                if (lexd(bd[u], bi[u], md, mj)) { md = bd[u]; mj = bi[u]; }
#pragma unroll
            for (int off = 32; off >= 1; off >>= 1) {
                const double od = __shfl_xor(md, off, 64);
                const int    oj = __shfl_xor(mj, off, 64);
                if (lexd(od, oj, md, mj)) { md = od; mj = oj; }
            }
            if (lane == 0) {
                fbd[(size_t)item * K + p] = md;
                fbi[(size_t)item * K + p] = mj;
            }
#pragma unroll
            for (int u = 0; u < K; ++u)
                if (bi[u] == mj) bd[u] = 1e300;
        }
    }
}

// ---------------- merge per-segment partial top-Ks -> final indices ----------------
template<int K>
__global__ __launch_bounds__(256)
void fallback_merge_kernel(const double* __restrict__ fbd, const int* __restrict__ fbi,
                           const int* __restrict__ ovf, const int* __restrict__ novf,
                           int* __restrict__ idx_out, int n) {
    const int tid = threadIdx.x, lane = tid & 63, w = tid >> 6;
    const int nwave = gridDim.x * 4;
    const int total = min(novf[0], MAXF);
    constexpr int E = SEGS * K;
    constexpr int PL = (E + 63) / 64;
    for (int e = blockIdx.x * 4 + w; e < total; e += nwave) {
        const int q = ovf[e];
        double dv[PL]; int jv[PL];
#pragma unroll
        for (int u = 0; u < PL; ++u) {
            const int c = u * 64 + lane;
            if (c < E) { dv[u] = fbd[(size_t)e * E + c]; jv[u] = fbi[(size_t)e * E + c]; }
            else       { dv[u] = 1e300;                  jv[u] = 0x7fffffff; }
        }
#pragma unroll
        for (int p = 0; p < K; ++p) {
            double md = dv[0]; int mj = jv[0];
#pragma unroll
            for (int u = 1; u < PL; ++u)
                if (lexd(dv[u], jv[u], md, mj)) { md = dv[u]; mj = jv[u]; }
#pragma unroll
            for (int off = 32; off >= 1; off >>= 1) {
                const double od = __shfl_xor(md, off, 64);
                const int    oj = __shfl_xor(mj, off, 64);
                if (lexd(od, oj, md, mj)) { md = od; mj = oj; }
            }
            if (lane == 0) idx_out[(size_t)q * K + p] = mj;
#pragma unroll
            for (int u = 0; u < PL; ++u)
                if (jv[u] == mj) dv[u] = 1e300;
        }
    }
}

// ---------------- serial fallback (only for e >= MAXF; never expected) ----------------
template<int D, int K>
__global__ __launch_bounds__(256)
void fallback_kernel(const float* __restrict__ X, const int* __restrict__ ovf,
                     const int* __restrict__ novf, int* __restrict__ idx_out, int n) {
    __shared__ float xq[4][D];
    const int tid = threadIdx.x, lane = tid & 63, w = tid >> 6;
    const int gw = blockIdx.x * 4 + w;
    const int total = novf[0];
    for (int e = MAXF + gw; e < total; e += gridDim.x * 4) {
        const int q = ovf[e];
        if (lane < D / 4)
            *(float4*)(&xq[w][lane * 4]) = *(const float4*)(X + (size_t)q * D + lane * 4);
        double bd[K]; int bi[K];
#pragma unroll
        for (int p = 0; p < K; ++p) { bd[p] = 1e300; bi[p] = 0x7fffffff; }
        for (int r = lane; r < n; r += 64) {
            if (r == q) continue;
            const float4* xr = (const float4*)(X + (size_t)r * D);
            double a0 = 0.0, a1 = 0.0;
#pragma unroll
            for (int t = 0; t < D / 8; ++t) {
                const float4 b0 = xr[2 * t], b1 = xr[2 * t + 1];
                const float4 c0 = *(const float4*)(&xq[w][8 * t]);
                const float4 c1 = *(const float4*)(&xq[w][8 * t + 4]);
                double d;
                d = (double)c0.x - (double)b0.x; a0 = fma(d, d, a0);
                d = (double)c0.y - (double)b0.y; a0 = fma(d, d, a0);
                d = (double)c0.z - (double)b0.z; a0 = fma(d, d, a0);
                d = (double)c0.w - (double)b0.w; a0 = fma(d, d, a0);
                d = (double)c1.x - (double)b1.x; a1 = fma(d, d, a1);
                d = (double)c1.y - (double)b1.y; a1 = fma(d, d, a1);
                d = (double)c1.z - (double)b1.z; a1 = fma(d, d, a1);
                d = (double)c1.w - (double)b1.w; a1 = fma(d, d, a1);
            }
            topk_insert_d<K>(bd, bi, a0 + a1, r);
        }
#pragma unroll
        for (int p = 0; p < K; ++p) {
            double md = bd[0]; int mj = bi[0];
#pragma unroll
            for (int u = 1; u < K; ++u)
                if (lexd(bd[u], bi[u], md, mj)) { md = bd[u]; mj = bi[u]; }
#pragma unroll
            for (int off = 32; off >= 1; off >>= 1) {
                const double od = __shfl_xor(md, off, 64);
                const int    oj = __shfl_xor(mj, off, 64);
                if (lexd(od, oj, md, mj)) { md = od; mj = oj; }
            }
            if (lane == 0) idx_out[(size_t)q * K + p] = mj;
#pragma unroll
            for (int u = 0; u < K; ++u)
                if (bi[u] == mj) bd[u] = 1e300;
        }
    }
}

// ---------------- T = X @ W^T (bias folded into gather-max) ----------------
template<int D>
__global__ __launch_bounds__(256)
void lin_kernel(const float* __restrict__ X, const float* __restrict__ W,
                float* __restrict__ T, int n) {
    constexpr int PB = 16;
    __shared__ float Wlds[D * HID];
    __shared__ float Xlds[PB * D];
    const int tid = threadIdx.x;
    const int p0 = blockIdx.x * PB;

    {
        const int h = tid & 127;
        const int hf = tid >> 7;
#pragma unroll
        for (int u = 0; u < D / 8; ++u) {
            const int d0 = hf * (D / 2) + u * 4;
            const float4 v = *(const float4*)(W + (size_t)h * D + d0);
            Wlds[(d0 + 0) * HID + h] = v.x;
            Wlds[(d0 + 1) * HID + h] = v.y;
            Wlds[(d0 + 2) * HID + h] = v.z;
            Wlds[(d0 + 3) * HID + h] = v.w;
        }
    }
    {
        const int rr = tid & 15;
        const int g = tid >> 4;
        constexpr int DG = D / 16;
        const int p = p0 + rr;
        const bool ok = p < n;
#pragma unroll
        for (int u = 0; u < DG / 4; ++u) {
            const int d0 = g * DG + u * 4;
            const float4 v = ok ? *(const float4*)(X + (size_t)p * D + d0)
                                : make_float4(0.f, 0.f, 0.f, 0.f);
            *(float4*)(&Xlds[rr * D + d0]) = v;
        }
    }
    __syncthreads();

    const int pp = tid >> 4;
    const int hh = tid & 15;
    float acc[8];
#pragma unroll
    for (int e = 0; e < 8; ++e) acc[e] = 0.f;
#pragma unroll 4
    for (int d = 0; d < D; ++d) {
        const float xa = Xlds[pp * D + d];
#pragma unroll
        for (int e = 0; e < 8; ++e)
            acc[e] = fmaf(xa, Wlds[d * HID + hh + 16 * e], acc[e]);
    }
    const int p = p0 + pp;
    if (p < n) {
#pragma unroll
        for (int e = 0; e < 8; ++e)
            T[(size_t)p * HID + hh + 16 * e] = acc[e];
    }
}

// ---------------- h[i,:] = max_j T[idx_j,:] - T[i,:] + b ----------------
template<int K>
__global__ void gathermax_kernel(const float* __restrict__ T, const int* __restrict__ idx,
                                 const float* __restrict__ b, float* __restrict__ out, int n) {
    const int i = blockIdx.x;
    const int h = threadIdx.x;
    float m = -__builtin_inff();
#pragma unroll
    for (int t = 0; t < K; ++t) {
        const int j = idx[(size_t)i * K + t];
        m = fmaxf(m, T[(size_t)j * HID + h]);
    }
    out[(size_t)i * HID + h] = m - T[(size_t)i * HID + h] + b[h];
}

// ---------------- out = h2 @ Wl^T + bl ----------------
__global__ void final_kernel(const float* __restrict__ h2, const float* __restrict__ Wl,
                             const float* __restrict__ bl, float* __restrict__ out, int n) {
    const int t = blockIdx.x * 256 + threadIdx.x;
    const int i = t >> 4;
    const int c = t & 15;
    if (i >= n || c >= 10) return;
    const float* hr = h2 + (size_t)i * HID;
    const float* wr = Wl + (size_t)c * HID;
    float s = 0.f;
#pragma unroll 4
    for (int d = 0; d < HID; ++d) s = fmaf(hr[d], wr[d], s);
    out[(size_t)i * 10 + c] = s + bl[c];
}

extern "C" void kernel_launch(void* const* d_in, const int* in_sizes, int n_in,
                              void* d_out, int out_size, void* d_ws, size_t ws_size,
                              hipStream_t stream) {
    const float* x  = (const float*)d_in[0];
    const float* W1 = (const float*)d_in[1];
    const float* b1 = (const float*)d_in[2];
    const float* W2 = (const float*)d_in[3];
    const float* b2 = (const float*)d_in[4];
    const float* Wl = (const float*)d_in[5];
    const float* bl = (const float*)d_in[6];
    float* out = (float*)d_out;
    const int n = in_sizes[0] / 64;   // 10000
    constexpr int K1 = 5, K2 = 10;

    char* ws = (char*)d_ws;
    size_t off = 0;
    auto alloc = [&](size_t bytes) -> void* {
        void* p = ws + off;
        off = (off + bytes + 255) & ~(size_t)255;
        return p;
    };
    // union region with disjoint lifetimes:
    //   phase A (knn):      cbuf (NSPLIT strips of BUDS ints/query) + smp
    //   phase B (fallback): fbd/fbi  (aliases cbuf, dead after select)
    //   phase C (lin/gm):   T (lin output)
    const size_t cbufB = (size_t)NSPLIT * n * BUDS * 4;          // 10.24 MB
    const size_t smpB  = (size_t)n * 4 * K2 * 4;                 // 1.6 MB
    const size_t fbdB  = (size_t)MAXF * SEGS * K2 * 8;           // 5.24 MB
    const size_t fbiB  = (size_t)MAXF * SEGS * K2 * 4;           // 2.62 MB
    const size_t TB_   = (size_t)n * HID * 4;                    // 5.12 MB
    size_t regB = cbufB + smpB;
    if (fbdB + fbiB > regB) regB = fbdB + fbiB;
    if (TB_ > regB) regB = TB_;
    char*  region = (char*)alloc(regB);
    float* T1   = (float*)region;
    int*   cbuf = (int*)region;
    float* smp  = (float*)(region + cbufB);
    double* fbd = (double*)region;
    int*   fbi  = (int*)(region + fbdB);
    float* h1b  = (float*)alloc((size_t)n * HID * 4);
    float* sqx  = (float*)alloc((size_t)n * 4);
    float* sqh  = (float*)alloc((size_t)n * 4);
    int*   idx1 = (int*)alloc((size_t)n * K1 * 4);
    int*   idx2 = (int*)alloc((size_t)n * K2 * 4);
    u16*   Xhi  = (u16*)alloc((size_t)n * 64 * 2);
    u16*   Xlo  = (u16*)alloc((size_t)n * 64 * 2);
    u16*   Hhi  = (u16*)alloc((size_t)n * HID * 2);
    u16*   Hlo  = (u16*)alloc((size_t)n * HID * 2);
    float* tau  = (float*)alloc((size_t)n * 4);
    int*   cnt8 = (int*)alloc((size_t)NSPLIT * n * 4);
    double* dkth = (double*)alloc((size_t)n * 8);
    int*   ovf  = (int*)alloc((size_t)n * 4);
    int*   novf = (int*)alloc(256);
    float* sqmax = (float*)alloc(256);
    float* T2  = T1;
    float* h2b = h1b;

    const int cps  = (n + NSPLIT - 1) / NSPLIT;   // 1250
    const int qbs  = (n + 63) / 64;               // 157
    const int sstr = n / SMP;                     // 9
    const int nb   = (n + 255) / 256;

    // ---- layer 1 (D=64, K=5) ----
    zero_misc_kernel<<<1, 64, 0, stream>>>(novf, sqmax);
    sqnorm_kernel<64><<<nb, 256, 0, stream>>>(x, sqx, sqmax, n);
    split_bf16_kernel<<<(n * 64 / 4 + 255) / 256, 256, 0, stream>>>(x, Xhi, Xlo, n * 64 / 4);
    sample_knn_kernel<64, K1><<<qbs, 256, 0, stream>>>(Xhi, Xlo, sqx, smp, n, sstr);
    tau_merge_kernel<K1><<<nb, 256, 0, stream>>>(smp, sqx, sqmax, tau, n);
    knn_main_kernel<64><<<dim3(qbs, NSPLIT), 256, 0, stream>>>(Xhi, Xlo, sqx, tau, cnt8, cbuf, n, cps);
    select_kernel<64, K1><<<(n + 3) / 4, 256, 0, stream>>>(x, cbuf, cnt8, idx1, dkth, n);
    flag_kernel<K1><<<nb, 256, 0, stream>>>(cnt8, dkth, tau, sqx, sqmax, novf, ovf, n);
    fallback_seg_kernel<64, K1><<<1024, 256, 0, stream>>>(x, ovf, novf, fbd, fbi, n);
    fallback_merge_kernel<K1><<<256, 256, 0, stream>>>(fbd, fbi, ovf, novf, idx1, n);
    fallback_kernel<64, K1><<<256, 256, 0, stream>>>(x, ovf, novf, idx1, n);
    lin_kernel<64><<<(n + 15) / 16, 256, 0, stream>>>(x, W1, T1, n);
    gathermax_kernel<K1><<<n, HID, 0, stream>>>(T1, idx1, b1, h1b, n);

    // ---- layer 2 (D=128, K=10) ----
    zero_misc_kernel<<<1, 64, 0, stream>>>(novf, sqmax);
    sqnorm_kernel<HID><<<nb, 256, 0, stream>>>(h1b, sqh, sqmax, n);
    split_bf16_kernel<<<(n * HID / 4 + 255) / 256, 256, 0, stream>>>(h1b, Hhi, Hlo, n * HID / 4);
    sample_knn_kernel<HID, K2><<<qbs, 256, 0, stream>>>(Hhi, Hlo, sqh, smp, n, sstr);
    tau_merge_kernel<K2><<<nb, 256, 0, stream>>>(smp, sqh, sqmax, tau, n);
    knn_main_kernel<HID><<<dim3(qbs, NSPLIT), 256, 0, stream>>>(Hhi, Hlo, sqh, tau, cnt8, cbuf, n, cps);
    select_kernel<HID, K2><<<(n + 3) / 4, 256, 0, stream>>>(h1b, cbuf, cnt8, idx2, dkth, n);
    flag_kernel<K2><<<nb, 256, 0, stream>>>(cnt8, dkth, tau, sqh, sqmax, novf, ovf, n);
    fallback_seg_kernel<HID, K2><<<1024, 256, 0, stream>>>(h1b, ovf, novf, fbd, fbi, n);
    fallback_merge_kernel<K2><<<256, 256, 0, stream>>>(fbd, fbi, ovf, novf, idx2, n);
    fallback_kernel<HID, K2><<<256, 256, 0, stream>>>(h1b, ovf, novf, idx2, n);
    lin_kernel<HID><<<(n + 15) / 16, 256, 0, stream>>>(h1b, W2, T2, n);
    gathermax_kernel<K2><<<n, HID, 0, stream>>>(T2, idx2, b2, h2b, n);

    // ---- head ----
    final_kernel<<<(n * 16 + 255) / 256, 256, 0, stream>>>(h2b, Wl, bl, out, n);
}

// Round 9
// 619.101 us; speedup vs baseline: 2.1717x; 1.0146x over previous
//
#include <hip/hip_runtime.h>

#define DEVINLINE __device__ __forceinline__

typedef unsigned short u16;
typedef __attribute__((ext_vector_type(8))) short short8v;
typedef __attribute__((ext_vector_type(4))) float float4v;

constexpr int HID = 128;
constexpr int NSPLIT = 8;     // main-pass column splits
constexpr int BUDS = 32;      // candidate budget per (split, query)
constexpr int BUD = NSPLIT * BUDS;   // 256 total select capacity
constexpr int SMP = 1024;     // sample size for tau
constexpr int SEGS = 32;      // fallback scan segments per query
constexpr int MAXF = 2048;    // fast-fallback capacity (scratch-sized)

// ---------- small helpers ----------
DEVINLINE void gld16(const void* g, void* l) {
    __builtin_amdgcn_global_load_lds((const __attribute__((address_space(1))) unsigned int*)g,
                                     (__attribute__((address_space(3))) unsigned int*)l, 16, 0, 0);
}
DEVINLINE void gld4(const void* g, void* l) {
    __builtin_amdgcn_global_load_lds((const __attribute__((address_space(1))) unsigned int*)g,
                                     (__attribute__((address_space(3))) unsigned int*)l, 4, 0, 0);
}
DEVINLINE u16 f2bf(float x) {
    unsigned u = __float_as_uint(x);
    return (u16)((u + 0x7fffu + ((u >> 16) & 1u)) >> 16);
}
DEVINLINE float bf2f(u16 h) { return __uint_as_float(((unsigned)h) << 16); }
// rigorous bound on |screened_d2 - exact_d2| for split-bf16 3-term screening.
DEVINLINE float maxerr_f(float sqq, float sqm) {
    return 1.5e-4f * (sqq + sqm) + 0.05f;
}
// ascending value-only top-K list (static indices)
template<int K>
DEVINLINE void topk_insert_v(float (&bd)[K], float d) {
    if (d >= bd[K - 1]) return;
#pragma unroll
    for (int p = 0; p < K; ++p) {
        const float mn = fminf(d, bd[p]);
        const float mx = fmaxf(d, bd[p]);
        bd[p] = mn; d = mx;
    }
}
DEVINLINE bool lexd(double d1, int i1, double d2, int i2) {
    return (d1 < d2) || ((d1 == d2) && (i1 < i2));
}
template<int K>
DEVINLINE void topk_insert_d(double (&bd)[K], int (&bi)[K], double d, int j) {
    if (!lexd(d, j, bd[K - 1], bi[K - 1])) return;
    double cd = d; int ci = j;
#pragma unroll
    for (int p = 0; p < K; ++p) {
        const bool lt = lexd(cd, ci, bd[p], bi[p]);
        const double sd = bd[p]; const int si = bi[p];
        bd[p] = lt ? cd : sd;  bi[p] = lt ? ci : si;
        cd = lt ? sd : cd;     ci = lt ? si : ci;
    }
}

// ---------------- per-layer init (novf + sqmax only; cnt8 fully overwritten) ----------------
__global__ void zero_misc_kernel(int* __restrict__ novf, float* __restrict__ sqmax) {
    if (blockIdx.x == 0 && threadIdx.x == 0) { novf[0] = 0; *(int*)sqmax = 0; }
}

// ---------------- squared norms (fp32) + global max ----------------
template<int D>
__global__ void sqnorm_kernel(const float* __restrict__ X, float* __restrict__ sq,
                              float* __restrict__ sqmax, int n) {
    const int i = blockIdx.x * 256 + threadIdx.x;
    float s = 0.f;
    if (i < n) {
        const float4* row = (const float4*)(X + (size_t)i * D);
#pragma unroll
        for (int u = 0; u < D / 4; ++u) {
            const float4 v = row[u];
            s += v.x * v.x + v.y * v.y + v.z * v.z + v.w * v.w;
        }
        sq[i] = s;
    }
    float m = s;
#pragma unroll
    for (int off = 32; off >= 1; off >>= 1) m = fmaxf(m, __shfl_xor(m, off, 64));
    if ((threadIdx.x & 63) == 0) atomicMax((int*)sqmax, __float_as_int(m));
}

// ---------------- split fp32 -> bf16 hi + lo ----------------
__global__ void split_bf16_kernel(const float* __restrict__ X, u16* __restrict__ hi,
                                  u16* __restrict__ lo, int total4) {
    const int i = blockIdx.x * 256 + threadIdx.x;
    if (i >= total4) return;
    const float4 v = ((const float4*)X)[i];
    float xs[4] = {v.x, v.y, v.z, v.w};
    u16 h4[4], l4[4];
#pragma unroll
    for (int e = 0; e < 4; ++e) {
        const u16 h = f2bf(xs[e]);
        h4[e] = h;
        l4[e] = f2bf(xs[e] - bf2f(h));
    }
    ushort4 hv = {h4[0], h4[1], h4[2], h4[3]};
    ushort4 lv = {l4[0], l4[1], l4[2], l4[3]};
    ((ushort4*)hi)[i] = hv;
    ((ushort4*)lo)[i] = lv;
}

// ---------------- sample pass ----------------
template<int D, int K>
__global__ __launch_bounds__(256)
void sample_knn_kernel(const u16* __restrict__ Xhi, const u16* __restrict__ Xlo,
                       const float* __restrict__ sq, float* __restrict__ smp,
                       int n, int sstr) {
    constexpr int MB = 64, NMI = 4;
    constexpr int KS = D / 32, SLOTS = D / 8;
    constexpr int TS = MB * SLOTS, TB = TS * 16, SI = 2 * TS / 256;
    constexpr int BUFB = 2 * TB + 384;
    constexpr int NT = SMP / MB;   // 16
    __shared__ __align__(16) char smem[2 * BUFB];

    const int tid = threadIdx.x, lane = tid & 63, wid = tid >> 6;
    const int lrow = lane & 15, lhalf = lane >> 4;
    const int q0 = blockIdx.x * 64;
    const int q = q0 + wid * 16 + lrow, qc = min(q, n - 1);

    short8v qhi[KS], qlo[KS];
#pragma unroll
    for (int ks = 0; ks < KS; ++ks) {
        qhi[ks] = *(const short8v*)(Xhi + (size_t)qc * D + (ks * 4 + lhalf) * 8);
        qlo[ks] = *(const short8v*)(Xlo + (size_t)qc * D + (ks * 4 + lhalf) * 8);
    }
    const float sqq = sq[qc];

    int srow[SI], soff[SI]; bool sislo[SI];
#pragma unroll
    for (int it = 0; it < SI; ++it) {
        const int gs = (it * 4 + wid) * 64 + lane;
        const bool islo = gs >= TS;
        const int s = islo ? gs - TS : gs;
        const int row = s / SLOTS, psl = s % SLOTS;
        const int ksl = (psl & ~7) | ((psl ^ row) & 7);
        srow[it] = row; soff[it] = ksl * 8; sislo[it] = islo;
    }

    float bd[K];
#pragma unroll
    for (int p = 0; p < K; ++p) bd[p] = __builtin_inff();

    auto stage = [&](int t, int b) {
        char* buf = smem + b * BUFB;
        const int s0 = t * MB;
#pragma unroll
        for (int it = 0; it < SI; ++it) {
            const size_t phys = (size_t)(s0 + srow[it]) * sstr;
            const u16* src = (sislo[it] ? Xlo : Xhi) + phys * D + soff[it];
            gld16(src, buf + (it * 4 + wid) * 1024);
        }
        if (wid == 0) gld4(sq + (size_t)(s0 + lane) * sstr, buf + 2 * TB);
    };
    auto compute = [&](int t, int b) {
        const char* buf = smem + b * BUFB;
        const u16* hp = (const u16*)buf;
        const u16* lp = (const u16*)(buf + TB);
        const float* sql = (const float*)(buf + 2 * TB);
        const int s0 = t * MB;
        float4v acc[NMI];
#pragma unroll
        for (int mi = 0; mi < NMI; ++mi) acc[mi] = (float4v){0.f, 0.f, 0.f, 0.f};
#pragma unroll
        for (int ks = 0; ks < KS; ++ks) {
#pragma unroll
            for (int mi = 0; mi < NMI; ++mi) {
                const int row = mi * 16 + lrow;
                const int ksl = ks * 4 + lhalf;
                const int pk = (ksl & ~7) | ((ksl ^ row) & 7);
                const size_t off = (size_t)row * (SLOTS * 8) + pk * 8;
                const short8v ah = *(const short8v*)(hp + off);
                const short8v al = *(const short8v*)(lp + off);
                acc[mi] = __builtin_amdgcn_mfma_f32_16x16x32_bf16(ah, qhi[ks], acc[mi], 0, 0, 0);
                acc[mi] = __builtin_amdgcn_mfma_f32_16x16x32_bf16(ah, qlo[ks], acc[mi], 0, 0, 0);
                acc[mi] = __builtin_amdgcn_mfma_f32_16x16x32_bf16(al, qhi[ks], acc[mi], 0, 0, 0);
            }
        }
#pragma unroll
        for (int mi = 0; mi < NMI; ++mi) {
            const float4 s4 = *(const float4*)(sql + mi * 16 + lhalf * 4);
            const float ss[4] = {s4.x, s4.y, s4.z, s4.w};
#pragma unroll
            for (int r = 0; r < 4; ++r) {
                const int sidx = s0 + mi * 16 + lhalf * 4 + r;
                const int j = sidx * sstr;
                const float d2 = sqq + ss[r] - 2.f * acc[mi][r];
                if (j != q) topk_insert_v<K>(bd, d2);
            }
        }
    };

    stage(0, 0);
    __syncthreads();
    for (int t = 0; t < NT; ++t) {
        if (t + 1 < NT) stage(t + 1, (t + 1) & 1);
        compute(t, t & 1);
        __syncthreads();
    }

    if (q < n) {
        const size_t base = ((size_t)q * 4 + lhalf) * K;
#pragma unroll
        for (int p = 0; p < K; ++p) smp[base + p] = bd[p];
    }
}

// ---------------- merge sample lists -> tau ----------------
template<int K>
__global__ void tau_merge_kernel(const float* __restrict__ smp, const float* __restrict__ sq,
                                 const float* __restrict__ sqmax, float* __restrict__ tau, int n) {
    const int q = blockIdx.x * 256 + threadIdx.x;
    if (q >= n) return;
    float bd[K];
#pragma unroll
    for (int p = 0; p < K; ++p) bd[p] = __builtin_inff();
    for (int g = 0; g < 4; ++g) {
        const size_t base = ((size_t)q * 4 + g) * K;
#pragma unroll
        for (int p = 0; p < K; ++p) topk_insert_v<K>(bd, smp[base + p]);
    }
    const float me = maxerr_f(sq[q], sqmax[0]);
    tau[q] = bd[K - 1] + 2.f * me + 0.0625f;
}

// ---------------- main pass: split-bf16 3-MFMA, 2 query-sets/wave, LDS compaction ----------
// QB=128 queries/block (4 waves x 2 sets of 16): each staged (ah,al) pair read
// once feeds 6 MFMAs -> LDS-read per MFMA halved. MB=48 -> ~50KB LDS -> 3 blocks/CU.
template<int D>
__global__ __launch_bounds__(256)
void knn_main_kernel(const u16* __restrict__ Xhi, const u16* __restrict__ Xlo,
                     const float* __restrict__ sq, const float* __restrict__ tau,
                     int* __restrict__ cnt8, int* __restrict__ cbuf, int n, int cps) {
    constexpr int QB = 128;
    constexpr int MB = 48, NMI = 3;
    constexpr int KS = D / 32, SLOTS = D / 8;
    constexpr int TS = MB * SLOTS, TB = TS * 16, SI = 2 * TS / 256;
    constexpr int BUFB = 2 * TB + 256;
    __shared__ __align__(16) char smem[2 * BUFB];
    __shared__ int scnt[QB];

    const int tid = threadIdx.x, lane = tid & 63, wid = tid >> 6;
    const int lrow = lane & 15, lhalf = lane >> 4;
    const int q0 = blockIdx.x * QB, sp = blockIdx.y;
    const int rbeg = sp * cps, rend = min(rbeg + cps, n);
    const int nt = (rend - rbeg + MB - 1) / MB;

    const int qA = q0 + wid * 32 + lrow, qB = qA + 16;
    const int qcA = min(qA, n - 1),     qcB = min(qB, n - 1);
    const bool okA = qA < n,            okB = qB < n;
    const int qlocA = wid * 32 + lrow,  qlocB = qlocA + 16;

    short8v qhiA[KS], qloA[KS], qhiB[KS], qloB[KS];
#pragma unroll
    for (int ks = 0; ks < KS; ++ks) {
        const int o = (ks * 4 + lhalf) * 8;
        qhiA[ks] = *(const short8v*)(Xhi + (size_t)qcA * D + o);
        qloA[ks] = *(const short8v*)(Xlo + (size_t)qcA * D + o);
        qhiB[ks] = *(const short8v*)(Xhi + (size_t)qcB * D + o);
        qloB[ks] = *(const short8v*)(Xlo + (size_t)qcB * D + o);
    }
    const float sqqA = sq[qcA], sqqB = sq[qcB];
    const float tqA = tau[qcA], tqB = tau[qcB];

    int srow[SI], soff[SI]; bool sislo[SI];
#pragma unroll
    for (int it = 0; it < SI; ++it) {
        const int gs = (it * 4 + wid) * 64 + lane;
        const bool islo = gs >= TS;
        const int s = islo ? gs - TS : gs;
        const int row = s / SLOTS, psl = s % SLOTS;
        const int ksl = (psl & ~7) | ((psl ^ row) & 7);
        srow[it] = row; soff[it] = ksl * 8; sislo[it] = islo;
    }

    auto stage = [&](int t, int b) {
        char* buf = smem + b * BUFB;
        const int row0 = rbeg + t * MB;
#pragma unroll
        for (int it = 0; it < SI; ++it) {
            const int grow = min(row0 + srow[it], rend - 1);
            const u16* src = (sislo[it] ? Xlo : Xhi) + (size_t)grow * D + soff[it];
            gld16(src, buf + (it * 4 + wid) * 1024);
        }
        if (tid < MB) gld4(sq + min(row0 + tid, rend - 1), buf + 2 * TB);
    };
    auto compute = [&](int t, int b) {
        const char* buf = smem + b * BUFB;
        const u16* hp = (const u16*)buf;
        const u16* lp = (const u16*)(buf + TB);
        const float* sql = (const float*)(buf + 2 * TB);
        const int row0 = rbeg + t * MB;
        const int rl = rend - row0;
        float4v accA[NMI], accB[NMI];
#pragma unroll
        for (int mi = 0; mi < NMI; ++mi) {
            accA[mi] = (float4v){0.f, 0.f, 0.f, 0.f};
            accB[mi] = (float4v){0.f, 0.f, 0.f, 0.f};
        }
#pragma unroll
        for (int ks = 0; ks < KS; ++ks) {
#pragma unroll
            for (int mi = 0; mi < NMI; ++mi) {
                const int row = mi * 16 + lrow;
                const int ksl = ks * 4 + lhalf;
                const int pk = (ksl & ~7) | ((ksl ^ row) & 7);
                const size_t off = (size_t)row * (SLOTS * 8) + pk * 8;
                const short8v ah = *(const short8v*)(hp + off);
                const short8v al = *(const short8v*)(lp + off);
                accA[mi] = __builtin_amdgcn_mfma_f32_16x16x32_bf16(ah, qhiA[ks], accA[mi], 0, 0, 0);
                accA[mi] = __builtin_amdgcn_mfma_f32_16x16x32_bf16(ah, qloA[ks], accA[mi], 0, 0, 0);
                accA[mi] = __builtin_amdgcn_mfma_f32_16x16x32_bf16(al, qhiA[ks], accA[mi], 0, 0, 0);
                accB[mi] = __builtin_amdgcn_mfma_f32_16x16x32_bf16(ah, qhiB[ks], accB[mi], 0, 0, 0);
                accB[mi] = __builtin_amdgcn_mfma_f32_16x16x32_bf16(ah, qloB[ks], accB[mi], 0, 0, 0);
                accB[mi] = __builtin_amdgcn_mfma_f32_16x16x32_bf16(al, qhiB[ks], accB[mi], 0, 0, 0);
            }
        }
#pragma unroll
        for (int mi = 0; mi < NMI; ++mi) {
            const float4 s4 = *(const float4*)(sql + mi * 16 + lhalf * 4);
            const float ss[4] = {s4.x, s4.y, s4.z, s4.w};
#pragma unroll
            for (int r = 0; r < 4; ++r) {
                const int dbr = mi * 16 + lhalf * 4 + r;
                const int j = row0 + dbr;
                const bool jok = dbr < rl;
                const float d2A = sqqA + ss[r] - 2.f * accA[mi][r];
                const float d2B = sqqB + ss[r] - 2.f * accB[mi][r];
                if (okA && jok && d2A <= tqA && j != qA) {
                    const int slot = atomicAdd(&scnt[qlocA], 1);   // LDS atomic
                    if (slot < BUDS) cbuf[((size_t)sp * n + qA) * BUDS + slot] = j;
                }
                if (okB && jok && d2B <= tqB && j != qB) {
                    const int slot = atomicAdd(&scnt[qlocB], 1);
                    if (slot < BUDS) cbuf[((size_t)sp * n + qB) * BUDS + slot] = j;
                }
            }
        }
    };

    if (tid < QB) scnt[tid] = 0;
    stage(0, 0);
    __syncthreads();
    for (int t = 0; t < nt; ++t) {
        if (t + 1 < nt) stage(t + 1, (t + 1) & 1);
        compute(t, t & 1);
        __syncthreads();
    }
    if (tid < QB) {
        const int qq = q0 + tid;
        if (qq < n) cnt8[(size_t)sp * n + qq] = scnt[tid];
    }
}

// ---------------- fp64-exact top-K over the 8x32 candidate strips ----------------
template<int D, int K>
__global__ __launch_bounds__(256)
void select_kernel(const float* __restrict__ X, const int* __restrict__ cbuf,
                   const int* __restrict__ cnt8, int* __restrict__ idx_out,
                   double* __restrict__ dkth, int n) {
    __shared__ float xish[4][D];
    const int tid = threadIdx.x, lane = tid & 63, w = tid >> 6;
    const int q = blockIdx.x * 4 + w;
    const int qc = min(q, n - 1);

    if (lane < D / 4)
        *(float4*)(&xish[w][lane * 4]) = *(const float4*)(X + (size_t)qc * D + lane * 4);
    __syncthreads();

    double dv[4]; int jv[4];
#pragma unroll
    for (int u = 0; u < 4; ++u) {
        const int c = u * 64 + lane;        // 0..255
        const int spc = c >> 5, slot = c & 31;
        int j = 0x7fffffff;
        double s = 1e300;
        const int cc = min(cnt8[(size_t)spc * n + qc], BUDS);
        if (slot < cc) {
            j = cbuf[((size_t)spc * n + qc) * BUDS + slot];
            const float4* xj = (const float4*)(X + (size_t)j * D);
            double acc = 0.0;
#pragma unroll 8
            for (int t = 0; t < D / 4; ++t) {
                const float4 b = xj[t];
                const float4 a = *(const float4*)(&xish[w][t * 4]);
                double d;
                d = (double)a.x - (double)b.x; acc = fma(d, d, acc);
                d = (double)a.y - (double)b.y; acc = fma(d, d, acc);
                d = (double)a.z - (double)b.z; acc = fma(d, d, acc);
                d = (double)a.w - (double)b.w; acc = fma(d, d, acc);
            }
            s = acc;
        }
        dv[u] = s; jv[u] = j;
    }

#pragma unroll
    for (int p = 0; p < K; ++p) {
        double md = dv[0]; int mj = jv[0];
#pragma unroll
        for (int u = 1; u < 4; ++u)
            if (lexd(dv[u], jv[u], md, mj)) { md = dv[u]; mj = jv[u]; }
#pragma unroll
        for (int off = 32; off >= 1; off >>= 1) {
            const double od = __shfl_xor(md, off, 64);
            const int    oj = __shfl_xor(mj, off, 64);
            if (lexd(od, oj, md, mj)) { md = od; mj = oj; }
        }
        if (lane == 0 && q < n) {
            idx_out[(size_t)q * K + p] = mj;
            if (p == K - 1) dkth[q] = md;
        }
#pragma unroll
        for (int u = 0; u < 4; ++u)
            if (jv[u] == mj) dv[u] = 1e300;
    }
}

// ---------------- certificate check -> flagged-query list ----------------
template<int K>
__global__ void flag_kernel(const int* __restrict__ cnt8, const double* __restrict__ dkth,
                            const float* __restrict__ tau, const float* __restrict__ sq,
                            const float* __restrict__ sqmax, int* __restrict__ novf,
                            int* __restrict__ ovf, int n) {
    const int q = blockIdx.x * 256 + threadIdx.x;
    if (q >= n) return;
    const float me = maxerr_f(sq[q], sqmax[0]);
    int tot = 0; bool ov = false;
#pragma unroll
    for (int spc = 0; spc < NSPLIT; ++spc) {
        const int c = cnt8[(size_t)spc * n + q];
        tot += c; ov |= (c > BUDS);
    }
    const bool bad = ov || (tot < K) || (dkth[q] + (double)me > (double)tau[q]);
    if (bad) { const int s = atomicAdd(novf, 1); ovf[s] = q; }
}

// ---------------- parallel exact fallback: per-(query,segment) wave scan ----------------
template<int D, int K>
__global__ __launch_bounds__(256)
void fallback_seg_kernel(const float* __restrict__ X, const int* __restrict__ ovf,
                         const int* __restrict__ novf, double* __restrict__ fbd,
                         int* __restrict__ fbi, int n) {
    __shared__ float xq[4][D];
    const int tid = threadIdx.x, lane = tid & 63, w = tid >> 6;
    const int nwave = gridDim.x * 4;
    const int total = min(novf[0], MAXF);
    const int items = total * SEGS;
    const int segsz = (n + SEGS - 1) / SEGS;
    for (int item = blockIdx.x * 4 + w; item < items; item += nwave) {
        const int e = item / SEGS, s = item % SEGS;
        const int q = ovf[e];
        if (lane < D / 4)
            *(float4*)(&xq[w][lane * 4]) = *(const float4*)(X + (size_t)q * D + lane * 4);
        double bd[K]; int bi[K];
#pragma unroll
        for (int p = 0; p < K; ++p) { bd[p] = 1e300; bi[p] = 0x7fffffff; }
        const int rs = s * segsz, re = min(rs + segsz, n);
        for (int r = rs + lane; r < re; r += 64) {
            if (r == q) continue;
            const float4* xr = (const float4*)(X + (size_t)r * D);
            double a0 = 0.0, a1 = 0.0;
#pragma unroll
            for (int t = 0; t < D / 8; ++t) {
                const float4 b0 = xr[2 * t], b1 = xr[2 * t + 1];
                const float4 c0 = *(const float4*)(&xq[w][8 * t]);
                const float4 c1 = *(const float4*)(&xq[w][8 * t + 4]);
                double d;
                d = (double)c0.x - (double)b0.x; a0 = fma(d, d, a0);
                d = (double)c0.y - (double)b0.y; a0 = fma(d, d, a0);
                d = (double)c0.z - (double)b0.z; a0 = fma(d, d, a0);
                d = (double)c0.w - (double)b0.w; a0 = fma(d, d, a0);
                d = (double)c1.x - (double)b1.x; a1 = fma(d, d, a1);
                d = (double)c1.y - (double)b1.y; a1 = fma(d, d, a1);
                d = (double)c1.z - (double)b1.z; a1 = fma(d, d, a1);
                d = (double)c1.w - (double)b1.w; a1 = fma(d, d, a1);
            }
            topk_insert_d<K>(bd, bi, a0 + a1, r);
        }
#pragma unroll
        for (int p = 0; p < K; ++p) {
            double md = bd[0]; int mj = bi[0];
#pragma unroll
            for (int u = 1; u < K; ++u)
                if (lexd(bd[u], bi[u], md, mj)) { md = bd[u]; mj = bi[u]; }
#pragma unroll
            for (int off = 32; off >= 1; off >>= 1) {
                const double od = __shfl_xor(md, off, 64);
                const int    oj = __shfl_xor(mj, off, 64);
                if (lexd(od, oj, md, mj)) { md = od; mj = oj; }
            }
            if (lane == 0) {
                fbd[(size_t)item * K + p] = md;
                fbi[(size_t)item * K + p] = mj;
            }
#pragma unroll
            for (int u = 0; u < K; ++u)
                if (bi[u] == mj) bd[u] = 1e300;
        }
    }
}

// ---------------- merge per-segment partial top-Ks -> final indices ----------------
template<int K>
__global__ __launch_bounds__(256)
void fallback_merge_kernel(const double* __restrict__ fbd, const int* __restrict__ fbi,
                           const int* __restrict__ ovf, const int* __restrict__ novf,
                           int* __restrict__ idx_out, int n) {
    const int tid = threadIdx.x, lane = tid & 63, w = tid >> 6;
    const int nwave = gridDim.x * 4;
    const int total = min(novf[0], MAXF);
    constexpr int E = SEGS * K;
    constexpr int PL = (E + 63) / 64;
    for (int e = blockIdx.x * 4 + w; e < total; e += nwave) {
        const int q = ovf[e];
        double dv[PL]; int jv[PL];
#pragma unroll
        for (int u = 0; u < PL; ++u) {
            const int c = u * 64 + lane;
            if (c < E) { dv[u] = fbd[(size_t)e * E + c]; jv[u] = fbi[(size_t)e * E + c]; }
            else       { dv[u] = 1e300;                  jv[u] = 0x7fffffff; }
        }
#pragma unroll
        for (int p = 0; p < K; ++p) {
            double md = dv[0]; int mj = jv[0];
#pragma unroll
            for (int u = 1; u < PL; ++u)
                if (lexd(dv[u], jv[u], md, mj)) { md = dv[u]; mj = jv[u]; }
#pragma unroll
            for (int off = 32; off >= 1; off >>= 1) {
                const double od = __shfl_xor(md, off, 64);
                const int    oj = __shfl_xor(mj, off, 64);
                if (lexd(od, oj, md, mj)) { md = od; mj = oj; }
            }
            if (lane == 0) idx_out[(size_t)q * K + p] = mj;
#pragma unroll
            for (int u = 0; u < PL; ++u)
                if (jv[u] == mj) dv[u] = 1e300;
        }
    }
}

// ---------------- serial fallback (only for e >= MAXF; never expected) ----------------
template<int D, int K>
__global__ __launch_bounds__(256)
void fallback_kernel(const float* __restrict__ X, const int* __restrict__ ovf,
                     const int* __restrict__ novf, int* __restrict__ idx_out, int n) {
    __shared__ float xq[4][D];
    const int tid = threadIdx.x, lane = tid & 63, w = tid >> 6;
    const int gw = blockIdx.x * 4 + w;
    const int total = novf[0];
    for (int e = MAXF + gw; e < total; e += gridDim.x * 4) {
        const int q = ovf[e];
        if (lane < D / 4)
            *(float4*)(&xq[w][lane * 4]) = *(const float4*)(X + (size_t)q * D + lane * 4);
        double bd[K]; int bi[K];
#pragma unroll
        for (int p = 0; p < K; ++p) { bd[p] = 1e300; bi[p] = 0x7fffffff; }
        for (int r = lane; r < n; r += 64) {
            if (r == q) continue;
            const float4* xr = (const float4*)(X + (size_t)r * D);
            double a0 = 0.0, a1 = 0.0;
#pragma unroll
            for (int t = 0; t < D / 8; ++t) {
                const float4 b0 = xr[2 * t], b1 = xr[2 * t + 1];
                const float4 c0 = *(const float4*)(&xq[w][8 * t]);
                const float4 c1 = *(const float4*)(&xq[w][8 * t + 4]);
                double d;
                d = (double)c0.x - (double)b0.x; a0 = fma(d, d, a0);
                d = (double)c0.y - (double)b0.y; a0 = fma(d, d, a0);
                d = (double)c0.z - (double)b0.z; a0 = fma(d, d, a0);
                d = (double)c0.w - (double)b0.w; a0 = fma(d, d, a0);
                d = (double)c1.x - (double)b1.x; a1 = fma(d, d, a1);
                d = (double)c1.y - (double)b1.y; a1 = fma(d, d, a1);
                d = (double)c1.z - (double)b1.z; a1 = fma(d, d, a1);
                d = (double)c1.w - (double)b1.w; a1 = fma(d, d, a1);
            }
            topk_insert_d<K>(bd, bi, a0 + a1, r);
        }
#pragma unroll
        for (int p = 0; p < K; ++p) {
            double md = bd[0]; int mj = bi[0];
#pragma unroll
            for (int u = 1; u < K; ++u)
                if (lexd(bd[u], bi[u], md, mj)) { md = bd[u]; mj = bi[u]; }
#pragma unroll
            for (int off = 32; off >= 1; off >>= 1) {
                const double od = __shfl_xor(md, off, 64);
                const int    oj = __shfl_xor(mj, off, 64);
                if (lexd(od, oj, md, mj)) { md = od; mj = oj; }
            }
            if (lane == 0) idx_out[(size_t)q * K + p] = mj;
#pragma unroll
            for (int u = 0; u < K; ++u)
                if (bi[u] == mj) bd[u] = 1e300;
        }
    }
}

// ---------------- T = X @ W^T (bias folded into gather-max) ----------------
template<int D>
__global__ __launch_bounds__(256)
void lin_kernel(const float* __restrict__ X, const float* __restrict__ W,
                float* __restrict__ T, int n) {
    constexpr int PB = 16;
    __shared__ float Wlds[D * HID];
    __shared__ float Xlds[PB * D];
    const int tid = threadIdx.x;
    const int p0 = blockIdx.x * PB;

    {
        const int h = tid & 127;
        const int hf = tid >> 7;
#pragma unroll
        for (int u = 0; u < D / 8; ++u) {
            const int d0 = hf * (D / 2) + u * 4;
            const float4 v = *(const float4*)(W + (size_t)h * D + d0);
            Wlds[(d0 + 0) * HID + h] = v.x;
            Wlds[(d0 + 1) * HID + h] = v.y;
            Wlds[(d0 + 2) * HID + h] = v.z;
            Wlds[(d0 + 3) * HID + h] = v.w;
        }
    }
    {
        const int rr = tid & 15;
        const int g = tid >> 4;
        constexpr int DG = D / 16;
        const int p = p0 + rr;
        const bool ok = p < n;
#pragma unroll
        for (int u = 0; u < DG / 4; ++u) {
            const int d0 = g * DG + u * 4;
            const float4 v = ok ? *(const float4*)(X + (size_t)p * D + d0)
                                : make_float4(0.f, 0.f, 0.f, 0.f);
            *(float4*)(&Xlds[rr * D + d0]) = v;
        }
    }
    __syncthreads();

    const int pp = tid >> 4;
    const int hh = tid & 15;
    float acc[8];
#pragma unroll
    for (int e = 0; e < 8; ++e) acc[e] = 0.f;
#pragma unroll 4
    for (int d = 0; d < D; ++d) {
        const float xa = Xlds[pp * D + d];
#pragma unroll
        for (int e = 0; e < 8; ++e)
            acc[e] = fmaf(xa, Wlds[d * HID + hh + 16 * e], acc[e]);
    }
    const int p = p0 + pp;
    if (p < n) {
#pragma unroll
        for (int e = 0; e < 8; ++e)
            T[(size_t)p * HID + hh + 16 * e] = acc[e];
    }
}

// ---------------- h[i,:] = max_j T[idx_j,:] - T[i,:] + b ----------------
template<int K>
__global__ void gathermax_kernel(const float* __restrict__ T, const int* __restrict__ idx,
                                 const float* __restrict__ b, float* __restrict__ out, int n) {
    const int i = blockIdx.x;
    const int h = threadIdx.x;
    float m = -__builtin_inff();
#pragma unroll
    for (int t = 0; t < K; ++t) {
        const int j = idx[(size_t)i * K + t];
        m = fmaxf(m, T[(size_t)j * HID + h]);
    }
    out[(size_t)i * HID + h] = m - T[(size_t)i * HID + h] + b[h];
}

// ---------------- out = h2 @ Wl^T + bl ----------------
__global__ void final_kernel(const float* __restrict__ h2, const float* __restrict__ Wl,
                             const float* __restrict__ bl, float* __restrict__ out, int n) {
    const int t = blockIdx.x * 256 + threadIdx.x;
    const int i = t >> 4;
    const int c = t & 15;
    if (i >= n || c >= 10) return;
    const float* hr = h2 + (size_t)i * HID;
    const float* wr = Wl + (size_t)c * HID;
    float s = 0.f;
#pragma unroll 4
    for (int d = 0; d < HID; ++d) s = fmaf(hr[d], wr[d], s);
    out[(size_t)i * 10 + c] = s + bl[c];
}

extern "C" void kernel_launch(void* const* d_in, const int* in_sizes, int n_in,
                              void* d_out, int out_size, void* d_ws, size_t ws_size,
                              hipStream_t stream) {
    const float* x  = (const float*)d_in[0];
    const float* W1 = (const float*)d_in[1];
    const float* b1 = (const float*)d_in[2];
    const float* W2 = (const float*)d_in[3];
    const float* b2 = (const float*)d_in[4];
    const float* Wl = (const float*)d_in[5];
    const float* bl = (const float*)d_in[6];
    float* out = (float*)d_out;
    const int n = in_sizes[0] / 64;   // 10000
    constexpr int K1 = 5, K2 = 10;

    char* ws = (char*)d_ws;
    size_t off = 0;
    auto alloc = [&](size_t bytes) -> void* {
        void* p = ws + off;
        off = (off + bytes + 255) & ~(size_t)255;
        return p;
    };
    // union region with disjoint lifetimes:
    //   phase A (knn):      cbuf (NSPLIT strips of BUDS ints/query) + smp
    //   phase B (fallback): fbd/fbi  (aliases cbuf, dead after select)
    //   phase C (lin/gm):   T (lin output)
    const size_t cbufB = (size_t)NSPLIT * n * BUDS * 4;          // 10.24 MB
    const size_t smpB  = (size_t)n * 4 * K2 * 4;                 // 1.6 MB
    const size_t fbdB  = (size_t)MAXF * SEGS * K2 * 8;           // 5.24 MB
    const size_t fbiB  = (size_t)MAXF * SEGS * K2 * 4;           // 2.62 MB
    const size_t TB_   = (size_t)n * HID * 4;                    // 5.12 MB
    size_t regB = cbufB + smpB;
    if (fbdB + fbiB > regB) regB = fbdB + fbiB;
    if (TB_ > regB) regB = TB_;
    char*  region = (char*)alloc(regB);
    float* T1   = (float*)region;
    int*   cbuf = (int*)region;
    float* smp  = (float*)(region + cbufB);
    double* fbd = (double*)region;
    int*   fbi  = (int*)(region + fbdB);
    float* h1b  = (float*)alloc((size_t)n * HID * 4);
    float* sqx  = (float*)alloc((size_t)n * 4);
    float* sqh  = (float*)alloc((size_t)n * 4);
    int*   idx1 = (int*)alloc((size_t)n * K1 * 4);
    int*   idx2 = (int*)alloc((size_t)n * K2 * 4);
    u16*   Xhi  = (u16*)alloc((size_t)n * 64 * 2);
    u16*   Xlo  = (u16*)alloc((size_t)n * 64 * 2);
    u16*   Hhi  = (u16*)alloc((size_t)n * HID * 2);
    u16*   Hlo  = (u16*)alloc((size_t)n * HID * 2);
    float* tau  = (float*)alloc((size_t)n * 4);
    int*   cnt8 = (int*)alloc((size_t)NSPLIT * n * 4);
    double* dkth = (double*)alloc((size_t)n * 8);
    int*   ovf  = (int*)alloc((size_t)n * 4);
    int*   novf = (int*)alloc(256);
    float* sqmax = (float*)alloc(256);
    float* T2  = T1;
    float* h2b = h1b;

    const int cps  = (n + NSPLIT - 1) / NSPLIT;   // 1250
    const int qbs  = (n + 63) / 64;               // 157 (sample pass)
    const int qbs2 = (n + 127) / 128;             // 79  (main pass, QB=128)
    const int sstr = n / SMP;                     // 9
    const int nb   = (n + 255) / 256;

    // ---- layer 1 (D=64, K=5) ----
    zero_misc_kernel<<<1, 64, 0, stream>>>(novf, sqmax);
    sqnorm_kernel<64><<<nb, 256, 0, stream>>>(x, sqx, sqmax, n);
    split_bf16_kernel<<<(n * 64 / 4 + 255) / 256, 256, 0, stream>>>(x, Xhi, Xlo, n * 64 / 4);
    sample_knn_kernel<64, K1><<<qbs, 256, 0, stream>>>(Xhi, Xlo, sqx, smp, n, sstr);
    tau_merge_kernel<K1><<<nb, 256, 0, stream>>>(smp, sqx, sqmax, tau, n);
    knn_main_kernel<64><<<dim3(qbs2, NSPLIT), 256, 0, stream>>>(Xhi, Xlo, sqx, tau, cnt8, cbuf, n, cps);
    select_kernel<64, K1><<<(n + 3) / 4, 256, 0, stream>>>(x, cbuf, cnt8, idx1, dkth, n);
    flag_kernel<K1><<<nb, 256, 0, stream>>>(cnt8, dkth, tau, sqx, sqmax, novf, ovf, n);
    fallback_seg_kernel<64, K1><<<1024, 256, 0, stream>>>(x, ovf, novf, fbd, fbi, n);
    fallback_merge_kernel<K1><<<256, 256, 0, stream>>>(fbd, fbi, ovf, novf, idx1, n);
    fallback_kernel<64, K1><<<256, 256, 0, stream>>>(x, ovf, novf, idx1, n);
    lin_kernel<64><<<(n + 15) / 16, 256, 0, stream>>>(x, W1, T1, n);
    gathermax_kernel<K1><<<n, HID, 0, stream>>>(T1, idx1, b1, h1b, n);

    // ---- layer 2 (D=128, K=10) ----
    zero_misc_kernel<<<1, 64, 0, stream>>>(novf, sqmax);
    sqnorm_kernel<HID><<<nb, 256, 0, stream>>>(h1b, sqh, sqmax, n);
    split_bf16_kernel<<<(n * HID / 4 + 255) / 256, 256, 0, stream>>>(h1b, Hhi, Hlo, n * HID / 4);
    sample_knn_kernel<HID, K2><<<qbs, 256, 0, stream>>>(Hhi, Hlo, sqh, smp, n, sstr);
    tau_merge_kernel<K2><<<nb, 256, 0, stream>>>(smp, sqh, sqmax, tau, n);
    knn_main_kernel<HID><<<dim3(qbs2, NSPLIT), 256, 0, stream>>>(Hhi, Hlo, sqh, tau, cnt8, cbuf, n, cps);
    select_kernel<HID, K2><<<(n + 3) / 4, 256, 0, stream>>>(h1b, cbuf, cnt8, idx2, dkth, n);
    flag_kernel<K2><<<nb, 256, 0, stream>>>(cnt8, dkth, tau, sqh, sqmax, novf, ovf, n);
    fallback_seg_kernel<HID, K2><<<1024, 256, 0, stream>>>(h1b, ovf, novf, fbd, fbi, n);
    fallback_merge_kernel<K2><<<256, 256, 0, stream>>>(fbd, fbi, ovf, novf, idx2, n);
    fallback_kernel<HID, K2><<<256, 256, 0, stream>>>(h1b, ovf, novf, idx2, n);
    lin_kernel<HID><<<(n + 15) / 16, 256, 0, stream>>>(h1b, W2, T2, n);
    gathermax_kernel<K2><<<n, HID, 0, stream>>>(T2, idx2, b2, h2b, n);

    // ---- head ----
    final_kernel<<<(n * 16 + 255) / 256, 256, 0, stream>>>(h2b, Wl, bl, out, n);
}

// Round 10
// 552.277 us; speedup vs baseline: 2.4345x; 1.1210x over previous
//
#include <hip/hip_runtime.h>

#define DEVINLINE __device__ __forceinline__

typedef unsigned short u16;
typedef _Float16 f16;
typedef __attribute__((ext_vector_type(8))) _Float16 half8v;
typedef __attribute__((ext_vector_type(4))) float float4v;

constexpr int HID = 128;
constexpr int NSPLIT = 16;    // main-pass column splits
constexpr int BUDS = 24;      // candidate budget per (split, query)
constexpr int BUD = NSPLIT * BUDS;   // 384 total select capacity
constexpr int SMP = 1024;     // sample size for tau
constexpr int SEGS = 32;      // fallback scan segments per query
constexpr int MAXF = 2048;    // fast-fallback capacity (scratch-sized)

// ---------- small helpers ----------
DEVINLINE void gld16(const void* g, void* l) {
    __builtin_amdgcn_global_load_lds((const __attribute__((address_space(1))) unsigned int*)g,
                                     (__attribute__((address_space(3))) unsigned int*)l, 16, 0, 0);
}
DEVINLINE void gld4(const void* g, void* l) {
    __builtin_amdgcn_global_load_lds((const __attribute__((address_space(1))) unsigned int*)g,
                                     (__attribute__((address_space(3))) unsigned int*)l, 4, 0, 0);
}
// rigorous |d - d~| bound: fp16 RNE per-coord rel err 2^-11 -> ||x-x~|| <=
// 2^-11*||x|| <= 4.9e-4*1.001*sqrt(sq~); x2 vectors + fp32 slop -> E below.
DEVINLINE float err_E(float sqq, float sqm) {
    return 6.2e-4f * (sqrtf(sqq) + sqrtf(sqm)) + 0.02f;
}
// ascending value-only top-K list (static indices)
template<int K>
DEVINLINE void topk_insert_v(float (&bd)[K], float d) {
    if (d >= bd[K - 1]) return;
#pragma unroll
    for (int p = 0; p < K; ++p) {
        const float mn = fminf(d, bd[p]);
        const float mx = fmaxf(d, bd[p]);
        bd[p] = mn; d = mx;
    }
}
DEVINLINE bool lexd(double d1, int i1, double d2, int i2) {
    return (d1 < d2) || ((d1 == d2) && (i1 < i2));
}
template<int K>
DEVINLINE void topk_insert_d(double (&bd)[K], int (&bi)[K], double d, int j) {
    if (!lexd(d, j, bd[K - 1], bi[K - 1])) return;
    double cd = d; int ci = j;
#pragma unroll
    for (int p = 0; p < K; ++p) {
        const bool lt = lexd(cd, ci, bd[p], bi[p]);
        const double sd = bd[p]; const int si = bi[p];
        bd[p] = lt ? cd : sd;  bi[p] = lt ? ci : si;
        cd = lt ? sd : cd;     ci = lt ? si : ci;
    }
}

// ---------------- per-layer init ----------------
__global__ void zero_misc_kernel(int* __restrict__ novf, float* __restrict__ sqmax) {
    if (blockIdx.x == 0 && threadIdx.x == 0) { novf[0] = 0; *(int*)sqmax = 0; }
}

// ---------------- fp32 -> fp16 plane + exact norms of rounded vectors ----------------
template<int D>
__global__ void conv_f16_kernel(const float* __restrict__ X, u16* __restrict__ Xh,
                                float* __restrict__ sqh, float* __restrict__ sqmax, int n) {
    const int i = blockIdx.x * 256 + threadIdx.x;
    float s = 0.f;
    if (i < n) {
        const float4* row = (const float4*)(X + (size_t)i * D);
        ushort4* dst = (ushort4*)(Xh + (size_t)i * D);
#pragma unroll
        for (int u = 0; u < D / 4; ++u) {
            const float4 v = row[u];
            const f16 h0 = (f16)v.x, h1 = (f16)v.y, h2 = (f16)v.z, h3 = (f16)v.w;
            const float f0 = (float)h0, f1 = (float)h1, f2 = (float)h2, f3 = (float)h3;
            s += f0 * f0 + f1 * f1 + f2 * f2 + f3 * f3;
            ushort4 o = {__builtin_bit_cast(u16, h0), __builtin_bit_cast(u16, h1),
                         __builtin_bit_cast(u16, h2), __builtin_bit_cast(u16, h3)};
            dst[u] = o;
        }
        sqh[i] = s;
    }
    float m = (i < n) ? s : 0.f;
#pragma unroll
    for (int off = 32; off >= 1; off >>= 1) m = fmaxf(m, __shfl_xor(m, off, 64));
    if ((threadIdx.x & 63) == 0) atomicMax((int*)sqmax, __float_as_int(m));
}

// ---------------- sample pass: exact-f16-metric top-K (single plane, 1 MFMA) ----------
template<int D, int K>
__global__ __launch_bounds__(256)
void sample_knn_kernel(const u16* __restrict__ Xh, const float* __restrict__ sqh,
                       float* __restrict__ smp, int n, int sstr) {
    constexpr int MB = 64, NMI = 4;
    constexpr int KS = D / 32, SLOTS = D / 8;
    constexpr int TS = MB * SLOTS, TB = TS * 16, SI = TS / 256;
    constexpr int BUFB = TB + 256;
    constexpr int NT = SMP / MB;   // 16
    __shared__ __align__(16) char smem[2 * BUFB];

    const int tid = threadIdx.x, lane = tid & 63, wid = tid >> 6;
    const int lrow = lane & 15, lhalf = lane >> 4;
    const int q0 = blockIdx.x * 64;
    const int q = q0 + wid * 16 + lrow, qc = min(q, n - 1);

    half8v qf[KS];
#pragma unroll
    for (int ks = 0; ks < KS; ++ks)
        qf[ks] = *(const half8v*)(Xh + (size_t)qc * D + (ks * 4 + lhalf) * 8);
    const float sqq = sqh[qc];

    int srow[SI], soff[SI];
#pragma unroll
    for (int it = 0; it < SI; ++it) {
        const int gs = (it * 4 + wid) * 64 + lane;
        const int row = gs / SLOTS, psl = gs % SLOTS;
        const int ksl = (psl & ~7) | ((psl ^ row) & 7);
        srow[it] = row; soff[it] = ksl * 8;
    }

    float bd[K];
#pragma unroll
    for (int p = 0; p < K; ++p) bd[p] = __builtin_inff();

    auto stage = [&](int t, int b) {
        char* buf = smem + b * BUFB;
        const int s0 = t * MB;
#pragma unroll
        for (int it = 0; it < SI; ++it) {
            const size_t phys = (size_t)(s0 + srow[it]) * sstr;
            gld16(Xh + phys * D + soff[it], buf + (it * 4 + wid) * 1024);
        }
        if (wid == 0) gld4(sqh + (size_t)(s0 + lane) * sstr, buf + TB);
    };
    auto compute = [&](int t, int b) {
        const char* buf = smem + b * BUFB;
        const u16* hp = (const u16*)buf;
        const float* sql = (const float*)(buf + TB);
        const int s0 = t * MB;
        float4v acc[NMI];
#pragma unroll
        for (int mi = 0; mi < NMI; ++mi) acc[mi] = (float4v){0.f, 0.f, 0.f, 0.f};
#pragma unroll
        for (int ks = 0; ks < KS; ++ks) {
#pragma unroll
            for (int mi = 0; mi < NMI; ++mi) {
                const int row = mi * 16 + lrow;
                const int ksl = ks * 4 + lhalf;
                const int pk = (ksl & ~7) | ((ksl ^ row) & 7);
                const half8v af = *(const half8v*)(hp + (size_t)row * (SLOTS * 8) + pk * 8);
                acc[mi] = __builtin_amdgcn_mfma_f32_16x16x32_f16(af, qf[ks], acc[mi], 0, 0, 0);
            }
        }
#pragma unroll
        for (int mi = 0; mi < NMI; ++mi) {
            const float4 s4 = *(const float4*)(sql + mi * 16 + lhalf * 4);
            const float ss[4] = {s4.x, s4.y, s4.z, s4.w};
#pragma unroll
            for (int r = 0; r < 4; ++r) {
                const int sidx = s0 + mi * 16 + lhalf * 4 + r;
                const int j = sidx * sstr;
                const float d2 = sqq + ss[r] - 2.f * acc[mi][r];
                if (j != q) topk_insert_v<K>(bd, d2);
            }
        }
    };

    stage(0, 0);
    __syncthreads();
    for (int t = 0; t < NT; ++t) {
        if (t + 1 < NT) stage(t + 1, (t + 1) & 1);
        compute(t, t & 1);
        __syncthreads();
    }

    if (q < n) {
        const size_t base = ((size_t)q * 4 + lhalf) * K;
#pragma unroll
        for (int p = 0; p < K; ++p) smp[base + p] = bd[p];
    }
}

// ---------------- merge sample lists -> raw s~ (kth sample screened d2) ----------------
template<int K>
__global__ void tau_merge_kernel(const float* __restrict__ smp, float* __restrict__ tau, int n) {
    const int q = blockIdx.x * 256 + threadIdx.x;
    if (q >= n) return;
    float bd[K];
#pragma unroll
    for (int p = 0; p < K; ++p) bd[p] = __builtin_inff();
    for (int g = 0; g < 4; ++g) {
        const size_t base = ((size_t)q * 4 + g) * K;
#pragma unroll
        for (int p = 0; p < K; ++p) topk_insert_v<K>(bd, smp[base + p]);
    }
    tau[q] = fmaxf(bd[K - 1], 0.f);
}

// ---------------- main pass: f16 1-MFMA, 2 query sets/wave, LDS compaction ------------
// QB=128 (4 waves x 2 sets of 16). Keep j iff d~2 <= (sqrt(s~)+2E)^2.
template<int D>
__global__ __launch_bounds__(256)
void knn_main_kernel(const u16* __restrict__ Xh, const float* __restrict__ sqh,
                     const float* __restrict__ tau, const float* __restrict__ sqmax,
                     int* __restrict__ cnt8, int* __restrict__ cbuf, int n, int cps) {
    constexpr int QB = 128;
    constexpr int MB = 64, NMI = 4;
    constexpr int KS = D / 32, SLOTS = D / 8;
    constexpr int TS = MB * SLOTS, TB = TS * 16, SI = TS / 256;
    constexpr int BUFB = TB + 256;
    __shared__ __align__(16) char smem[2 * BUFB];
    __shared__ int scnt[QB];

    const int tid = threadIdx.x, lane = tid & 63, wid = tid >> 6;
    const int lrow = lane & 15, lhalf = lane >> 4;
    const int q0 = blockIdx.x * QB, sp = blockIdx.y;
    const int rbeg = sp * cps, rend = min(rbeg + cps, n);
    const int nt = (rend - rbeg + MB - 1) / MB;

    const int qA = q0 + wid * 32 + lrow, qB = qA + 16;
    const int qcA = min(qA, n - 1),     qcB = min(qB, n - 1);
    const bool okA = qA < n,            okB = qB < n;
    const int qlocA = wid * 32 + lrow,  qlocB = qlocA + 16;

    half8v qfA[KS], qfB[KS];
#pragma unroll
    for (int ks = 0; ks < KS; ++ks) {
        const int o = (ks * 4 + lhalf) * 8;
        qfA[ks] = *(const half8v*)(Xh + (size_t)qcA * D + o);
        qfB[ks] = *(const half8v*)(Xh + (size_t)qcB * D + o);
    }
    const float sqqA = sqh[qcA], sqqB = sqh[qcB];
    const float sqm = sqmax[0];
    const float eA = err_E(sqqA, sqm), eB = err_E(sqqB, sqm);
    const float rA = sqrtf(tau[qcA]) + 2.f * eA;
    const float rB = sqrtf(tau[qcB]) + 2.f * eB;
    const float tqA = rA * rA + 0.01f;
    const float tqB = rB * rB + 0.01f;

    int srow[SI], soff[SI];
#pragma unroll
    for (int it = 0; it < SI; ++it) {
        const int gs = (it * 4 + wid) * 64 + lane;
        const int row = gs / SLOTS, psl = gs % SLOTS;
        const int ksl = (psl & ~7) | ((psl ^ row) & 7);
        srow[it] = row; soff[it] = ksl * 8;
    }

    auto stage = [&](int t, int b) {
        char* buf = smem + b * BUFB;
        const int row0 = rbeg + t * MB;
#pragma unroll
        for (int it = 0; it < SI; ++it) {
            const int grow = min(row0 + srow[it], rend - 1);
            gld16(Xh + (size_t)grow * D + soff[it], buf + (it * 4 + wid) * 1024);
        }
        if (tid < MB) gld4(sqh + min(row0 + tid, rend - 1), buf + TB);
    };
    auto compute = [&](int t, int b) {
        const char* buf = smem + b * BUFB;
        const u16* hp = (const u16*)buf;
        const float* sql = (const float*)(buf + TB);
        const int row0 = rbeg + t * MB;
        const int rl = rend - row0;
        float4v accA[NMI], accB[NMI];
#pragma unroll
        for (int mi = 0; mi < NMI; ++mi) {
            accA[mi] = (float4v){0.f, 0.f, 0.f, 0.f};
            accB[mi] = (float4v){0.f, 0.f, 0.f, 0.f};
        }
#pragma unroll
        for (int ks = 0; ks < KS; ++ks) {
#pragma unroll
            for (int mi = 0; mi < NMI; ++mi) {
                const int row = mi * 16 + lrow;
                const int ksl = ks * 4 + lhalf;
                const int pk = (ksl & ~7) | ((ksl ^ row) & 7);
                const half8v af = *(const half8v*)(hp + (size_t)row * (SLOTS * 8) + pk * 8);
                accA[mi] = __builtin_amdgcn_mfma_f32_16x16x32_f16(af, qfA[ks], accA[mi], 0, 0, 0);
                accB[mi] = __builtin_amdgcn_mfma_f32_16x16x32_f16(af, qfB[ks], accB[mi], 0, 0, 0);
            }
        }
#pragma unroll
        for (int mi = 0; mi < NMI; ++mi) {
            const float4 s4 = *(const float4*)(sql + mi * 16 + lhalf * 4);
            const float ss[4] = {s4.x, s4.y, s4.z, s4.w};
#pragma unroll
            for (int r = 0; r < 4; ++r) {
                const int dbr = mi * 16 + lhalf * 4 + r;
                const int j = row0 + dbr;
                const bool jok = dbr < rl;
                const float d2A = sqqA + ss[r] - 2.f * accA[mi][r];
                const float d2B = sqqB + ss[r] - 2.f * accB[mi][r];
                if (okA && jok && d2A <= tqA && j != qA) {
                    const int slot = atomicAdd(&scnt[qlocA], 1);   // LDS atomic
                    if (slot < BUDS) cbuf[((size_t)sp * n + qA) * BUDS + slot] = j;
                }
                if (okB && jok && d2B <= tqB && j != qB) {
                    const int slot = atomicAdd(&scnt[qlocB], 1);
                    if (slot < BUDS) cbuf[((size_t)sp * n + qB) * BUDS + slot] = j;
                }
            }
        }
    };

    if (tid < QB) scnt[tid] = 0;
    stage(0, 0);
    __syncthreads();
    for (int t = 0; t < nt; ++t) {
        if (t + 1 < nt) stage(t + 1, (t + 1) & 1);
        compute(t, t & 1);
        __syncthreads();
    }
    if (tid < QB) {
        const int qq = q0 + tid;
        if (qq < n) cnt8[(size_t)sp * n + qq] = scnt[tid];
    }
}

// ---------------- fp64-exact top-K over the NSPLIT x BUDS candidate strips ------------
template<int D, int K>
__global__ __launch_bounds__(256)
void select_kernel(const float* __restrict__ X, const int* __restrict__ cbuf,
                   const int* __restrict__ cnt8, int* __restrict__ idx_out,
                   double* __restrict__ dkth, int n) {
    constexpr int CH = BUD / 64;   // 6
    __shared__ float xish[4][D];
    const int tid = threadIdx.x, lane = tid & 63, w = tid >> 6;
    const int q = blockIdx.x * 4 + w;
    const int qc = min(q, n - 1);

    if (lane < D / 4)
        *(float4*)(&xish[w][lane * 4]) = *(const float4*)(X + (size_t)qc * D + lane * 4);
    __syncthreads();

    double dv[CH]; int jv[CH];
#pragma unroll
    for (int u = 0; u < CH; ++u) {
        const int c = u * 64 + lane;        // 0..BUD-1
        const int spc = c / BUDS, slot = c % BUDS;
        int j = 0x7fffffff;
        double s = 1e300;
        const int cc = min(cnt8[(size_t)spc * n + qc], BUDS);
        if (slot < cc) {
            j = cbuf[((size_t)spc * n + qc) * BUDS + slot];
            const float4* xj = (const float4*)(X + (size_t)j * D);
            double acc = 0.0;
#pragma unroll 8
            for (int t = 0; t < D / 4; ++t) {
                const float4 b = xj[t];
                const float4 a = *(const float4*)(&xish[w][t * 4]);
                double d;
                d = (double)a.x - (double)b.x; acc = fma(d, d, acc);
                d = (double)a.y - (double)b.y; acc = fma(d, d, acc);
                d = (double)a.z - (double)b.z; acc = fma(d, d, acc);
                d = (double)a.w - (double)b.w; acc = fma(d, d, acc);
            }
            s = acc;
        }
        dv[u] = s; jv[u] = j;
    }

#pragma unroll
    for (int p = 0; p < K; ++p) {
        double md = dv[0]; int mj = jv[0];
#pragma unroll
        for (int u = 1; u < CH; ++u)
            if (lexd(dv[u], jv[u], md, mj)) { md = dv[u]; mj = jv[u]; }
#pragma unroll
        for (int off = 32; off >= 1; off >>= 1) {
            const double od = __shfl_xor(md, off, 64);
            const int    oj = __shfl_xor(mj, off, 64);
            if (lexd(od, oj, md, mj)) { md = od; mj = oj; }
        }
        if (lane == 0 && q < n) {
            idx_out[(size_t)q * K + p] = mj;
            if (p == K - 1) dkth[q] = md;
        }
#pragma unroll
        for (int u = 0; u < CH; ++u)
            if (jv[u] == mj) dv[u] = 1e300;
    }
}

// ---------------- certificate check -> flagged-query list ----------------
template<int K>
__global__ void flag_kernel(const int* __restrict__ cnt8, const double* __restrict__ dkth,
                            const float* __restrict__ tau, const float* __restrict__ sqh,
                            const float* __restrict__ sqmax, int* __restrict__ novf,
                            int* __restrict__ ovf, int n) {
    const int q = blockIdx.x * 256 + threadIdx.x;
    if (q >= n) return;
    const float E = err_E(sqh[q], sqmax[0]);
    const float cv = sqrtf(tau[q]) + E;
    const double certv = (double)cv * (double)cv - 0.01;
    int tot = 0; bool ov = false;
#pragma unroll
    for (int spc = 0; spc < NSPLIT; ++spc) {
        const int c = cnt8[(size_t)spc * n + q];
        tot += c; ov |= (c > BUDS);
    }
    const bool bad = ov || (tot < K) || (dkth[q] > certv);
    if (bad) { const int s = atomicAdd(novf, 1); ovf[s] = q; }
}

// ---------------- parallel exact fallback: per-(query,segment) wave scan --------------
template<int D, int K>
__global__ __launch_bounds__(256)
void fallback_seg_kernel(const float* __restrict__ X, const int* __restrict__ ovf,
                         const int* __restrict__ novf, double* __restrict__ fbd,
                         int* __restrict__ fbi, int n) {
    __shared__ float xq[4][D];
    const int tid = threadIdx.x, lane = tid & 63, w = tid >> 6;
    const int nwave = gridDim.x * 4;
    const int total = min(novf[0], MAXF);
    const int items = total * SEGS;
    const int segsz = (n + SEGS - 1) / SEGS;
    for (int item = blockIdx.x * 4 + w; item < items; item += nwave) {
        const int e = item / SEGS, s = item % SEGS;
        const int q = ovf[e];
        if (lane < D / 4)
            *(float4*)(&xq[w][lane * 4]) = *(const float4*)(X + (size_t)q * D + lane * 4);
        double bd[K]; int bi[K];
#pragma unroll
        for (int p = 0; p < K; ++p) { bd[p] = 1e300; bi[p] = 0x7fffffff; }
        const int rs = s * segsz, re = min(rs + segsz, n);
        for (int r = rs + lane; r < re; r += 64) {
            if (r == q) continue;
            const float4* xr = (const float4*)(X + (size_t)r * D);
            double a0 = 0.0, a1 = 0.0;
#pragma unroll
            for (int t = 0; t < D / 8; ++t) {
                const float4 b0 = xr[2 * t], b1 = xr[2 * t + 1];
                const float4 c0 = *(const float4*)(&xq[w][8 * t]);
                const float4 c1 = *(const float4*)(&xq[w][8 * t + 4]);
                double d;
                d = (double)c0.x - (double)b0.x; a0 = fma(d, d, a0);
                d = (double)c0.y - (double)b0.y; a0 = fma(d, d, a0);
                d = (double)c0.z - (double)b0.z; a0 = fma(d, d, a0);
                d = (double)c0.w - (double)b0.w; a0 = fma(d, d, a0);
                d = (double)c1.x - (double)b1.x; a1 = fma(d, d, a1);
                d = (double)c1.y - (double)b1.y; a1 = fma(d, d, a1);
                d = (double)c1.z - (double)b1.z; a1 = fma(d, d, a1);
                d = (double)c1.w - (double)b1.w; a1 = fma(d, d, a1);
            }
            topk_insert_d<K>(bd, bi, a0 + a1, r);
        }
#pragma unroll
        for (int p = 0; p < K; ++p) {
            double md = bd[0]; int mj = bi[0];
#pragma unroll
            for (int u = 1; u < K; ++u)
                if (lexd(bd[u], bi[u], md, mj)) { md = bd[u]; mj = bi[u]; }
#pragma unroll
            for (int off = 32; off >= 1; off >>= 1) {
                const double od = __shfl_xor(md, off, 64);
                const int    oj = __shfl_xor(mj, off, 64);
                if (lexd(od, oj, md, mj)) { md = od; mj = oj; }
            }
            if (lane == 0) {
                fbd[(size_t)item * K + p] = md;
                fbi[(size_t)item * K + p] = mj;
            }
#pragma unroll
            for (int u = 0; u < K; ++u)
                if (bi[u] == mj) bd[u] = 1e300;
        }
    }
}

// ---------------- merge per-segment partial top-Ks -> final indices ----------------
template<int K>
__global__ __launch_bounds__(256)
void fallback_merge_kernel(const double* __restrict__ fbd, const int* __restrict__ fbi,
                           const int* __restrict__ ovf, const int* __restrict__ novf,
                           int* __restrict__ idx_out, int n) {
    const int tid = threadIdx.x, lane = tid & 63, w = tid >> 6;
    const int nwave = gridDim.x * 4;
    const int total = min(novf[0], MAXF);
    constexpr int E = SEGS * K;
    constexpr int PL = (E + 63) / 64;
    for (int e = blockIdx.x * 4 + w; e < total; e += nwave) {
        const int q = ovf[e];
        double dv[PL]; int jv[PL];
#pragma unroll
        for (int u = 0; u < PL; ++u) {
            const int c = u * 64 + lane;
            if (c < E) { dv[u] = fbd[(size_t)e * E + c]; jv[u] = fbi[(size_t)e * E + c]; }
            else       { dv[u] = 1e300;                  jv[u] = 0x7fffffff; }
        }
#pragma unroll
        for (int p = 0; p < K; ++p) {
            double md = dv[0]; int mj = jv[0];
#pragma unroll
            for (int u = 1; u < PL; ++u)
                if (lexd(dv[u], jv[u], md, mj)) { md = dv[u]; mj = jv[u]; }
#pragma unroll
            for (int off = 32; off >= 1; off >>= 1) {
                const double od = __shfl_xor(md, off, 64);
                const int    oj = __shfl_xor(mj, off, 64);
                if (lexd(od, oj, md, mj)) { md = od; mj = oj; }
            }
            if (lane == 0) idx_out[(size_t)q * K + p] = mj;
#pragma unroll
            for (int u = 0; u < PL; ++u)
                if (jv[u] == mj) dv[u] = 1e300;
        }
    }
}

// ---------------- serial fallback (only for e >= MAXF; never expected) ----------------
template<int D, int K>
__global__ __launch_bounds__(256)
void fallback_kernel(const float* __restrict__ X, const int* __restrict__ ovf,
                     const int* __restrict__ novf, int* __restrict__ idx_out, int n) {
    __shared__ float xq[4][D];
    const int tid = threadIdx.x, lane = tid & 63, w = tid >> 6;
    const int gw = blockIdx.x * 4 + w;
    const int total = novf[0];
    for (int e = MAXF + gw; e < total; e += gridDim.x * 4) {
        const int q = ovf[e];
        if (lane < D / 4)
            *(float4*)(&xq[w][lane * 4]) = *(const float4*)(X + (size_t)q * D + lane * 4);
        double bd[K]; int bi[K];
#pragma unroll
        for (int p = 0; p < K; ++p) { bd[p] = 1e300; bi[p] = 0x7fffffff; }
        for (int r = lane; r < n; r += 64) {
            if (r == q) continue;
            const float4* xr = (const float4*)(X + (size_t)r * D);
            double a0 = 0.0, a1 = 0.0;
#pragma unroll
            for (int t = 0; t < D / 8; ++t) {
                const float4 b0 = xr[2 * t], b1 = xr[2 * t + 1];
                const float4 c0 = *(const float4*)(&xq[w][8 * t]);
                const float4 c1 = *(const float4*)(&xq[w][8 * t + 4]);
                double d;
                d = (double)c0.x - (double)b0.x; a0 = fma(d, d, a0);
                d = (double)c0.y - (double)b0.y; a0 = fma(d, d, a0);
                d = (double)c0.z - (double)b0.z; a0 = fma(d, d, a0);
                d = (double)c0.w - (double)b0.w; a0 = fma(d, d, a0);
                d = (double)c1.x - (double)b1.x; a1 = fma(d, d, a1);
                d = (double)c1.y - (double)b1.y; a1 = fma(d, d, a1);
                d = (double)c1.z - (double)b1.z; a1 = fma(d, d, a1);
                d = (double)c1.w - (double)b1.w; a1 = fma(d, d, a1);
            }
            topk_insert_d<K>(bd, bi, a0 + a1, r);
        }
#pragma unroll
        for (int p = 0; p < K; ++p) {
            double md = bd[0]; int mj = bi[0];
#pragma unroll
            for (int u = 1; u < K; ++u)
                if (lexd(bd[u], bi[u], md, mj)) { md = bd[u]; mj = bi[u]; }
#pragma unroll
            for (int off = 32; off >= 1; off >>= 1) {
                const double od = __shfl_xor(md, off, 64);
                const int    oj = __shfl_xor(mj, off, 64);
                if (lexd(od, oj, md, mj)) { md = od; mj = oj; }
            }
            if (lane == 0) idx_out[(size_t)q * K + p] = mj;
#pragma unroll
            for (int u = 0; u < K; ++u)
                if (bi[u] == mj) bd[u] = 1e300;
        }
    }
}

// ---------------- T = X @ W^T (bias folded into gather-max) ----------------
template<int D>
__global__ __launch_bounds__(256)
void lin_kernel(const float* __restrict__ X, const float* __restrict__ W,
                float* __restrict__ T, int n) {
    constexpr int PB = 16;
    __shared__ float Wlds[D * HID];
    __shared__ float Xlds[PB * D];
    const int tid = threadIdx.x;
    const int p0 = blockIdx.x * PB;

    {
        const int h = tid & 127;
        const int hf = tid >> 7;
#pragma unroll
        for (int u = 0; u < D / 8; ++u) {
            const int d0 = hf * (D / 2) + u * 4;
            const float4 v = *(const float4*)(W + (size_t)h * D + d0);
            Wlds[(d0 + 0) * HID + h] = v.x;
            Wlds[(d0 + 1) * HID + h] = v.y;
            Wlds[(d0 + 2) * HID + h] = v.z;
            Wlds[(d0 + 3) * HID + h] = v.w;
        }
    }
    {
        const int rr = tid & 15;
        const int g = tid >> 4;
        constexpr int DG = D / 16;
        const int p = p0 + rr;
        const bool ok = p < n;
#pragma unroll
        for (int u = 0; u < DG / 4; ++u) {
            const int d0 = g * DG + u * 4;
            const float4 v = ok ? *(const float4*)(X + (size_t)p * D + d0)
                                : make_float4(0.f, 0.f, 0.f, 0.f);
            *(float4*)(&Xlds[rr * D + d0]) = v;
        }
    }
    __syncthreads();

    const int pp = tid >> 4;
    const int hh = tid & 15;
    float acc[8];
#pragma unroll
    for (int e = 0; e < 8; ++e) acc[e] = 0.f;
#pragma unroll 4
    for (int d = 0; d < D; ++d) {
        const float xa = Xlds[pp * D + d];
#pragma unroll
        for (int e = 0; e < 8; ++e)
            acc[e] = fmaf(xa, Wlds[d * HID + hh + 16 * e], acc[e]);
    }
    const int p = p0 + pp;
    if (p < n) {
#pragma unroll
        for (int e = 0; e < 8; ++e)
            T[(size_t)p * HID + hh + 16 * e] = acc[e];
    }
}

// ---------------- h[i,:] = max_j T[idx_j,:] - T[i,:] + b ----------------
template<int K>
__global__ void gathermax_kernel(const float* __restrict__ T, const int* __restrict__ idx,
                                 const float* __restrict__ b, float* __restrict__ out, int n) {
    const int i = blockIdx.x;
    const int h = threadIdx.x;
    float m = -__builtin_inff();
#pragma unroll
    for (int t = 0; t < K; ++t) {
        const int j = idx[(size_t)i * K + t];
        m = fmaxf(m, T[(size_t)j * HID + h]);
    }
    out[(size_t)i * HID + h] = m - T[(size_t)i * HID + h] + b[h];
}

// ---------------- out = h2 @ Wl^T + bl ----------------
__global__ void final_kernel(const float* __restrict__ h2, const float* __restrict__ Wl,
                             const float* __restrict__ bl, float* __restrict__ out, int n) {
    const int t = blockIdx.x * 256 + threadIdx.x;
    const int i = t >> 4;
    const int c = t & 15;
    if (i >= n || c >= 10) return;
    const float* hr = h2 + (size_t)i * HID;
    const float* wr = Wl + (size_t)c * HID;
    float s = 0.f;
#pragma unroll 4
    for (int d = 0; d < HID; ++d) s = fmaf(hr[d], wr[d], s);
    out[(size_t)i * 10 + c] = s + bl[c];
}

extern "C" void kernel_launch(void* const* d_in, const int* in_sizes, int n_in,
                              void* d_out, int out_size, void* d_ws, size_t ws_size,
                              hipStream_t stream) {
    const float* x  = (const float*)d_in[0];
    const float* W1 = (const float*)d_in[1];
    const float* b1 = (const float*)d_in[2];
    const float* W2 = (const float*)d_in[3];
    const float* b2 = (const float*)d_in[4];
    const float* Wl = (const float*)d_in[5];
    const float* bl = (const float*)d_in[6];
    float* out = (float*)d_out;
    const int n = in_sizes[0] / 64;   // 10000
    constexpr int K1 = 5, K2 = 10;

    char* ws = (char*)d_ws;
    size_t off = 0;
    auto alloc = [&](size_t bytes) -> void* {
        void* p = ws + off;
        off = (off + bytes + 255) & ~(size_t)255;
        return p;
    };
    // union region with disjoint lifetimes:
    //   phase A (knn):      cbuf (NSPLIT strips of BUDS ints/query) + smp
    //   phase B (fallback): fbd/fbi  (aliases cbuf, dead after select)
    //   phase C (lin/gm):   T (lin output)
    const size_t cbufB = (size_t)NSPLIT * n * BUDS * 4;          // 15.36 MB
    const size_t smpB  = (size_t)n * 4 * K2 * 4;                 // 1.6 MB
    const size_t fbdB  = (size_t)MAXF * SEGS * K2 * 8;           // 5.24 MB
    const size_t fbiB  = (size_t)MAXF * SEGS * K2 * 4;           // 2.62 MB
    const size_t TB_   = (size_t)n * HID * 4;                    // 5.12 MB
    size_t regB = cbufB + smpB;
    if (fbdB + fbiB > regB) regB = fbdB + fbiB;
    if (TB_ > regB) regB = TB_;
    char*  region = (char*)alloc(regB);
    float* T1   = (float*)region;
    int*   cbuf = (int*)region;
    float* smp  = (float*)(region + cbufB);
    double* fbd = (double*)region;
    int*   fbi  = (int*)(region + fbdB);
    float* h1b  = (float*)alloc((size_t)n * HID * 4);
    float* sqh  = (float*)alloc((size_t)n * 4);
    int*   idx1 = (int*)alloc((size_t)n * K1 * 4);
    int*   idx2 = (int*)alloc((size_t)n * K2 * 4);
    u16*   Xh   = (u16*)alloc((size_t)n * 64 * 2);
    u16*   Hh   = (u16*)alloc((size_t)n * HID * 2);
    float* tau  = (float*)alloc((size_t)n * 4);
    int*   cnt8 = (int*)alloc((size_t)NSPLIT * n * 4);
    double* dkth = (double*)alloc((size_t)n * 8);
    int*   ovf  = (int*)alloc((size_t)n * 4);
    int*   novf = (int*)alloc(256);
    float* sqmax = (float*)alloc(256);
    float* T2  = T1;
    float* h2b = h1b;

    const int cps  = (n + NSPLIT - 1) / NSPLIT;   // 625
    const int qbs  = (n + 63) / 64;               // 157 (sample pass)
    const int qbs2 = (n + 127) / 128;             // 79  (main pass, QB=128)
    const int sstr = n / SMP;                     // 9
    const int nb   = (n + 255) / 256;

    // ---- layer 1 (D=64, K=5) ----
    zero_misc_kernel<<<1, 64, 0, stream>>>(novf, sqmax);
    conv_f16_kernel<64><<<nb, 256, 0, stream>>>(x, Xh, sqh, sqmax, n);
    sample_knn_kernel<64, K1><<<qbs, 256, 0, stream>>>(Xh, sqh, smp, n, sstr);
    tau_merge_kernel<K1><<<nb, 256, 0, stream>>>(smp, tau, n);
    knn_main_kernel<64><<<dim3(qbs2, NSPLIT), 256, 0, stream>>>(Xh, sqh, tau, sqmax, cnt8, cbuf, n, cps);
    select_kernel<64, K1><<<(n + 3) / 4, 256, 0, stream>>>(x, cbuf, cnt8, idx1, dkth, n);
    flag_kernel<K1><<<nb, 256, 0, stream>>>(cnt8, dkth, tau, sqh, sqmax, novf, ovf, n);
    fallback_seg_kernel<64, K1><<<1024, 256, 0, stream>>>(x, ovf, novf, fbd, fbi, n);
    fallback_merge_kernel<K1><<<256, 256, 0, stream>>>(fbd, fbi, ovf, novf, idx1, n);
    fallback_kernel<64, K1><<<256, 256, 0, stream>>>(x, ovf, novf, idx1, n);
    lin_kernel<64><<<(n + 15) / 16, 256, 0, stream>>>(x, W1, T1, n);
    gathermax_kernel<K1><<<n, HID, 0, stream>>>(T1, idx1, b1, h1b, n);

    // ---- layer 2 (D=128, K=10) ----
    zero_misc_kernel<<<1, 64, 0, stream>>>(novf, sqmax);
    conv_f16_kernel<HID><<<nb, 256, 0, stream>>>(h1b, Hh, sqh, sqmax, n);
    sample_knn_kernel<HID, K2><<<qbs, 256, 0, stream>>>(Hh, sqh, smp, n, sstr);
    tau_merge_kernel<K2><<<nb, 256, 0, stream>>>(smp, tau, n);
    knn_main_kernel<HID><<<dim3(qbs2, NSPLIT), 256, 0, stream>>>(Hh, sqh, tau, sqmax, cnt8, cbuf, n, cps);
    select_kernel<HID, K2><<<(n + 3) / 4, 256, 0, stream>>>(h1b, cbuf, cnt8, idx2, dkth, n);
    flag_kernel<K2><<<nb, 256, 0, stream>>>(cnt8, dkth, tau, sqh, sqmax, novf, ovf, n);
    fallback_seg_kernel<HID, K2><<<1024, 256, 0, stream>>>(h1b, ovf, novf, fbd, fbi, n);
    fallback_merge_kernel<K2><<<256, 256, 0, stream>>>(fbd, fbi, ovf, novf, idx2, n);
    fallback_kernel<HID, K2><<<256, 256, 0, stream>>>(h1b, ovf, novf, idx2, n);
    lin_kernel<HID><<<(n + 15) / 16, 256, 0, stream>>>(h1b, W2, T2, n);
    gathermax_kernel<K2><<<n, HID, 0, stream>>>(T2, idx2, b2, h2b, n);

    // ---- head ----
    final_kernel<<<(n * 16 + 255) / 256, 256, 0, stream>>>(h2b, Wl, bl, out, n);
}